// Round 2
// baseline (37069.131 us; speedup 1.0000x reference)
//
#include <hip/hip_runtime.h>

#define LRELU(v) ((v) >= 0.f ? (v) : 0.2f * (v))

// ---------------- direct 3x3 conv, shared weights (guide net), one sample ----------------
// in [C,Hin,Win], w [O,C,3,3], b [O], out [O,Hout,Wout], pad=1
__global__ void conv3x3_guide(const float* __restrict__ in, const float* __restrict__ w,
                              const float* __restrict__ b, float* __restrict__ out,
                              int C, int O, int Hin, int Win, int Hout, int Wout,
                              int stride, int act, int tilesX, int tilesY)
{
    int bid = blockIdx.x;
    int tx = bid % tilesX; bid /= tilesX;
    int ty = bid % tilesY; bid /= tilesY;
    int o  = bid;
    extern __shared__ float wls[];
    int nw = C * 9;
    for (int i = threadIdx.x; i < nw; i += blockDim.x) wls[i] = w[o * nw + i];
    __syncthreads();
    int x = tx * 16 + (threadIdx.x & 15);
    int y = ty * 16 + (threadIdx.x >> 4);
    if (x >= Wout || y >= Hout) return;
    float acc = b[o];
    size_t plane = (size_t)Hin * Win;
    int iy0 = y * stride - 1, ix0 = x * stride - 1;
    for (int c = 0; c < C; ++c) {
        const float* ip = in + c * plane;
        const float* wc = wls + c * 9;
        #pragma unroll
        for (int ky = 0; ky < 3; ++ky) {
            int iy = iy0 + ky;
            if ((unsigned)iy >= (unsigned)Hin) continue;
            #pragma unroll
            for (int kx = 0; kx < 3; ++kx) {
                int ix = ix0 + kx;
                if ((unsigned)ix >= (unsigned)Win) continue;
                acc += ip[(size_t)iy * Win + ix] * wc[ky * 3 + kx];
            }
        }
    }
    if (act) acc = LRELU(acc);
    out[((size_t)o * Hout + y) * Wout + x] = acc;
}

// ---------------- direct 3x3 conv, per-sample modulated weights, one sample ----------------
// in [C,Hin,Win] (+optional in2 added), W [O,C,3,3] (this sample), sb [O]
__global__ void conv3x3_mod(const float* __restrict__ in, const float* __restrict__ in2,
                            const float* __restrict__ W, const float* __restrict__ sb,
                            float* __restrict__ out,
                            int C, int O, int Hin, int Win, int Hout, int Wout,
                            int stride, int pad, int act, int tilesX, int tilesY)
{
    int bid = blockIdx.x;
    int tx = bid % tilesX; bid /= tilesX;
    int ty = bid % tilesY; bid /= tilesY;
    int o  = bid;
    extern __shared__ float wls[];
    int nw = C * 9;
    const float* wp = W + (size_t)o * nw;
    for (int i = threadIdx.x; i < nw; i += blockDim.x) wls[i] = wp[i];
    __syncthreads();
    int x = tx * 16 + (threadIdx.x & 15);
    int y = ty * 16 + (threadIdx.x >> 4);
    if (x >= Wout || y >= Hout) return;
    float acc = sb[o];
    size_t plane = (size_t)Hin * Win;
    int iy0 = y * stride - pad, ix0 = x * stride - pad;
    for (int c = 0; c < C; ++c) {
        const float* ip  = in + c * plane;
        const float* ip2 = in2 ? in2 + c * plane : nullptr;
        const float* wc  = wls + c * 9;
        #pragma unroll
        for (int ky = 0; ky < 3; ++ky) {
            int iy = iy0 + ky;
            if ((unsigned)iy >= (unsigned)Hin) continue;
            #pragma unroll
            for (int kx = 0; kx < 3; ++kx) {
                int ix = ix0 + kx;
                if ((unsigned)ix >= (unsigned)Win) continue;
                float xv = ip[(size_t)iy * Win + ix];
                if (ip2) xv += ip2[(size_t)iy * Win + ix];
                acc += xv * wc[ky * 3 + kx];
            }
        }
    }
    if (act) acc = LRELU(acc);
    out[((size_t)o * Hout + y) * Wout + x] = acc;
}

// ---------------- direct transposed 3x3 conv (stride-2 up), in1+in2 summed, one sample ----------------
// out[o,y,x] = sum_{c,a,b: (y-a),(x-b) even>=0, in range} (in+in2)[c,(y-a)/2,(x-b)/2] * W[o,c,a,b]
// out size (2*Hin+1)^2. No bias/act (applied in following blur).
__global__ void tconv3x3_mod(const float* __restrict__ in, const float* __restrict__ in2,
                             const float* __restrict__ W, float* __restrict__ out,
                             int C, int O, int Hin, int Win, int tilesX, int tilesY)
{
    int Hout = 2 * Hin + 1, Wout = 2 * Win + 1;
    int bid = blockIdx.x;
    int tx = bid % tilesX; bid /= tilesX;
    int ty = bid % tilesY; bid /= tilesY;
    int o  = bid;
    extern __shared__ float wls[];
    int nw = C * 9;
    const float* wp = W + (size_t)o * nw;
    for (int i = threadIdx.x; i < nw; i += blockDim.x) wls[i] = wp[i];
    __syncthreads();
    int x = tx * 16 + (threadIdx.x & 15);
    int y = ty * 16 + (threadIdx.x >> 4);
    if (x >= Wout || y >= Hout) return;
    float acc = 0.f;
    size_t plane = (size_t)Hin * Win;
    for (int c = 0; c < C; ++c) {
        const float* ip  = in  + c * plane;
        const float* ip2 = in2 + c * plane;
        const float* wc  = wls + c * 9;
        #pragma unroll
        for (int a = 0; a < 3; ++a) {
            int u = y - a;
            if (u < 0 || (u & 1)) continue;
            int iy = u >> 1;
            if (iy >= Hin) continue;
            #pragma unroll
            for (int b = 0; b < 3; ++b) {
                int v = x - b;
                if (v < 0 || (v & 1)) continue;
                int ix = v >> 1;
                if (ix >= Win) continue;
                acc += (ip[(size_t)iy * Win + ix] + ip2[(size_t)iy * Win + ix]) * wc[a * 3 + b];
            }
        }
    }
    out[((size_t)o * Hout + y) * Wout + x] = acc;
}

// ---------------- 4x4 blur, pad=2 (pre-down): 64 planes, out [64, H+1, W+1], scale 1/64 ----------------
__global__ void blur_down(const float* __restrict__ in, float* __restrict__ out,
                          int H, int W, int tilesX, int tilesY)
{
    int Ho = H + 1, Wo = W + 1;
    int bid = blockIdx.x;
    int tx = bid % tilesX; bid /= tilesX;
    int ty = bid % tilesY; bid /= tilesY;
    int p  = bid;
    int x = tx * 16 + (threadIdx.x & 15);
    int y = ty * 16 + (threadIdx.x >> 4);
    if (x >= Wo || y >= Ho) return;
    const float k[4] = {1.f, 3.f, 3.f, 1.f};
    const float* ip = in + (size_t)p * H * W;
    float acc = 0.f;
    #pragma unroll
    for (int ky = 0; ky < 4; ++ky) {
        int iy = y - 2 + ky;
        if ((unsigned)iy >= (unsigned)H) continue;
        float row = 0.f;
        #pragma unroll
        for (int kx = 0; kx < 4; ++kx) {
            int ix = x - 2 + kx;
            if ((unsigned)ix >= (unsigned)W) continue;
            row += ip[(size_t)iy * W + ix] * k[kx];
        }
        acc += row * k[ky];
    }
    out[((size_t)p * Ho + y) * Wo + x] = acc * (1.f / 64.f);
}

// ------- 4x4 blur, pad=1, x4 scale (post-up) + bias + lrelu: [64,Hi,Wi] -> [64,Hi-1,Wi-1] -------
__global__ void blur_up_act(const float* __restrict__ in, const float* __restrict__ sb,
                            float* __restrict__ out, int Hi, int Wi, int tilesX, int tilesY)
{
    int Ho = Hi - 1, Wo = Wi - 1;
    int bid = blockIdx.x;
    int tx = bid % tilesX; bid /= tilesX;
    int ty = bid % tilesY; bid /= tilesY;
    int p  = bid;
    int x = tx * 16 + (threadIdx.x & 15);
    int y = ty * 16 + (threadIdx.x >> 4);
    if (x >= Wo || y >= Ho) return;
    const float k[4] = {1.f, 3.f, 3.f, 1.f};
    const float* ip = in + (size_t)p * Hi * Wi;
    float acc = 0.f;
    #pragma unroll
    for (int ky = 0; ky < 4; ++ky) {
        int iy = y - 1 + ky;
        if ((unsigned)iy >= (unsigned)Hi) continue;
        float row = 0.f;
        #pragma unroll
        for (int kx = 0; kx < 4; ++kx) {
            int ix = x - 1 + kx;
            if ((unsigned)ix >= (unsigned)Wi) continue;
            row += ip[(size_t)iy * Wi + ix] * k[kx];
        }
        acc += row * k[ky];
    }
    acc = acc * (4.f / 64.f) + sb[p];
    out[((size_t)p * Ho + y) * Wo + x] = LRELU(acc);
}

// ---------------- avg pool to 1x1: mean over HW per plane (64 planes, one sample) ----------------
__global__ void avgpool_hw(const float* __restrict__ in, float* __restrict__ out, int HW)
{
    int p = blockIdx.x;
    const float* ip = in + (size_t)p * HW;
    float s = 0.f;
    for (int i = threadIdx.x; i < HW; i += blockDim.x) s += ip[i];
    __shared__ float red[256];
    red[threadIdx.x] = s;
    __syncthreads();
    for (int off = 128; off; off >>= 1) {
        if ((int)threadIdx.x < off) red[threadIdx.x] += red[threadIdx.x + off];
        __syncthreads();
    }
    if (threadIdx.x == 0) out[p] = red[0] / (float)HW;
}

// ---------------- style FC (batched): out[n*64+i] = lrelu(dot(s[n,:64], W[i,:64]) + b[i]) ----------------
__global__ void style_fc(const float* __restrict__ s, const float* __restrict__ W,
                         const float* __restrict__ b, float* __restrict__ out, int outdim)
{
    int n = blockIdx.x;
    int i = threadIdx.x;
    if (i >= outdim) return;
    float acc = b[i];
    const float* sn = s + n * 64;
    const float* wi = W + i * 64;
    for (int f = 0; f < 64; ++f) acc += sn[f] * wi[f];
    out[n * 64 + i] = LRELU(acc);
}

// ------- weight modulate+demodulate (batched): Wout[n,o,c,k] = w[o,c,k]*sw[n,c]*rsqrt(sum+eps) -------
__global__ void modulate(const float* __restrict__ w, const float* __restrict__ sw,
                         float* __restrict__ wout, int O, int C)
{
    int no = blockIdx.x;
    int o = no % O, n = no / O;
    int nw = C * 9;
    int t = threadIdx.x;
    float v[9];
    int cnt = 0;
    float ss = 0.f;
    for (int idx = t; idx < nw; idx += 64) {
        int c = idx / 9;
        float val = w[o * nw + idx] * sw[n * 64 + c];
        v[cnt++] = val;
        ss += val * val;
    }
    #pragma unroll
    for (int off = 32; off; off >>= 1) ss += __shfl_xor(ss, off);
    float d = rsqrtf(ss + 1e-8f);
    cnt = 0;
    for (int idx = t; idx < nw; idx += 64)
        wout[(size_t)no * nw + idx] = v[cnt++] * d;
}

// ---------------- sentinel fill (ws too small -> distinguishable failure) ----------------
__global__ void fill_sentinel(float* __restrict__ out, int n)
{
    int i = blockIdx.x * 256 + threadIdx.x;
    if (i < n) out[i] = 1.0e9f;
}

extern "C" void kernel_launch(void* const* d_in, const int* in_sizes, int n_in,
                              void* d_out, int out_size, void* d_ws, size_t ws_size,
                              hipStream_t stream)
{
    const float* x     = (const float*)d_in[0];
    const float* ref   = (const float*)d_in[1];
    const float* g0w   = (const float*)d_in[2];
    const float* g0b   = (const float*)d_in[3];
    const float* grw   = (const float*)d_in[4];
    const float* grb   = (const float*)d_in[5];
    const float* c0w   = (const float*)d_in[6];
    const float* c0swW = (const float*)d_in[7];
    const float* c0swb = (const float*)d_in[8];
    const float* c0sbW = (const float*)d_in[9];
    const float* c0sbb = (const float*)d_in[10];
    const float* midw  = (const float*)d_in[11];
    const float* midswW= (const float*)d_in[12];
    const float* midswb= (const float*)d_in[13];
    const float* midsbW= (const float*)d_in[14];
    const float* midsbb= (const float*)d_in[15];
    const float* c6w   = (const float*)d_in[16];
    const float* c6swW = (const float*)d_in[17];
    const float* c6swb = (const float*)d_in[18];
    const float* c6sbW = (const float*)d_in[19];
    const float* c6sbb = (const float*)d_in[20];
    float* out = (float*)d_out;
    float* ws  = (float*)d_ws;

    // -------- per-sample workspace layout (floats), reused across the n=0..7 loop --------
    const size_t F0s = 0;                          // f0      [64,256,256]
    const size_t T1s = F0s + 4194304ull;           // 257^2-class temp [64,257,257]
    const size_t T2s = T1s + 4227136ull;           // 256^2 temp
    const size_t D1  = T2s + 4194304ull;           // [64,128,128]
    const size_t D2  = D1  + 1048576ull;           // f1 final
    const size_t D3  = D2  + 1048576ull;           // [64,129,129]-class
    const size_t E1  = D3  + 1065024ull;           // [64,64,64]
    const size_t E2  = E1  + 262144ull;
    const size_t E3  = E2  + 262144ull;
    const size_t SV  = E3  + 262144ull;            // s [8,64]
    const size_t STY = SV  + 512ull;               // 12 x (sw 512 + sb 512)
    const size_t WM  = STY + 12288ull;             // modulated weights (all samples)
    const size_t TOTAL = WM + 2976768ull;          // ~19.55M floats ~ 78.2 MB
    if (ws_size < TOTAL * sizeof(float)) {
        fill_sentinel<<<dim3((out_size + 255) / 256), dim3(256), 0, stream>>>(out, out_size);
        return;
    }

    dim3 blk(256);

    // ==================== guide net (per sample) -> s ====================
    for (int n = 0; n < 8; ++n) {
        const float* refn = ref + (size_t)n * 3 * 65536;
        conv3x3_guide<<<dim3(16 * 16 * 64), blk, 27 * 4, stream>>>(
            refn, g0w, g0b, ws + T1s, 3, 64, 256, 256, 256, 256, 1, 1, 16, 16);
        conv3x3_guide<<<dim3(8 * 8 * 64), blk, 2304, stream>>>(
            ws + T1s, grw + 0 * 36864, grb + 0 * 64, ws + D1, 64, 64, 256, 256, 128, 128, 2, 1, 8, 8);
        conv3x3_guide<<<dim3(8 * 8 * 64), blk, 2304, stream>>>(
            ws + D1, grw + 1 * 36864, grb + 1 * 64, ws + D2, 64, 64, 128, 128, 128, 128, 1, 1, 8, 8);
        conv3x3_guide<<<dim3(4 * 4 * 64), blk, 2304, stream>>>(
            ws + D2, grw + 2 * 36864, grb + 2 * 64, ws + E1, 64, 64, 128, 128, 64, 64, 2, 1, 4, 4);
        conv3x3_guide<<<dim3(4 * 4 * 64), blk, 2304, stream>>>(
            ws + E1, grw + 3 * 36864, grb + 3 * 64, ws + E2, 64, 64, 64, 64, 64, 64, 1, 0, 4, 4);
        avgpool_hw<<<dim3(64), blk, 0, stream>>>(ws + E2, ws + SV + n * 64, 4096);
    }

    // ==================== styles + modulated weights (batched) ====================
    // conv list: 0=c0, 1..10=mid0..9, 11=c6
    const float* Wt[12];  const float* swWp[12]; const float* swbp[12];
    const float* sbWp[12]; const float* sbbp[12];
    int Ci[12], Oi[12];
    size_t wmo[12];
    Wt[0] = c0w; swWp[0] = c0swW; swbp[0] = c0swb; sbWp[0] = c0sbW; sbbp[0] = c0sbb;
    Ci[0] = 3; Oi[0] = 64; wmo[0] = WM;
    for (int i = 0; i < 10; ++i) {
        Wt[1 + i]   = midw   + (size_t)i * 36864;
        swWp[1 + i] = midswW + (size_t)i * 4096;
        swbp[1 + i] = midswb + (size_t)i * 64;
        sbWp[1 + i] = midsbW + (size_t)i * 4096;
        sbbp[1 + i] = midsbb + (size_t)i * 64;
        Ci[1 + i] = 64; Oi[1 + i] = 64;
        wmo[1 + i] = WM + 13824ull + (size_t)i * 294912ull;
    }
    Wt[11] = c6w; swWp[11] = c6swW; swbp[11] = c6swb; sbWp[11] = c6sbW; sbbp[11] = c6sbb;
    Ci[11] = 64; Oi[11] = 3; wmo[11] = WM + 13824ull + 2949120ull;

    for (int i = 0; i < 12; ++i) {
        style_fc<<<dim3(8), dim3(64), 0, stream>>>(ws + SV, swWp[i], swbp[i], ws + STY + i * 1024, Ci[i]);
        style_fc<<<dim3(8), dim3(64), 0, stream>>>(ws + SV, sbWp[i], sbbp[i], ws + STY + i * 1024 + 512, Oi[i]);
        modulate<<<dim3(8 * Oi[i]), dim3(64), 0, stream>>>(Wt[i], ws + STY + i * 1024, ws + wmo[i], Oi[i], Ci[i]);
    }

    // ==================== main path (per sample) ====================
    for (int n = 0; n < 8; ++n) {
        const float* xn = x + (size_t)n * 3 * 65536;
        float* outn = out + (size_t)n * 3 * 65536;
        #define WN(i) (ws + wmo[i] + (size_t)n * Oi[i] * Ci[i] * 9)
        #define SBN(i) (ws + STY + (i) * 1024 + 512 + n * 64)
        // f0 = modconv(x, c0, none, act) -> F0s
        conv3x3_mod<<<dim3(16 * 16 * 64), blk, 27 * 4, stream>>>(
            xn, nullptr, WN(0), SBN(0), ws + F0s, 3, 64, 256, 256, 256, 256, 1, 1, 1, 16, 16);
        // f1 down: blur(f0) -> T1s (257^2); conv s2 p0 -> D1; then none-conv -> D2
        blur_down<<<dim3(64 * 17 * 17), blk, 0, stream>>>(ws + F0s, ws + T1s, 256, 256, 17, 17);
        conv3x3_mod<<<dim3(8 * 8 * 64), blk, 2304, stream>>>(
            ws + T1s, nullptr, WN(1), SBN(1), ws + D1, 64, 64, 257, 257, 128, 128, 2, 0, 1, 8, 8);
        conv3x3_mod<<<dim3(8 * 8 * 64), blk, 2304, stream>>>(
            ws + D1, nullptr, WN(2), SBN(2), ws + D2, 64, 64, 128, 128, 128, 128, 1, 1, 1, 8, 8);
        // f2 down: blur(f1) -> D3 (129^2); conv s2 p0 -> E1; none-conv -> E2
        blur_down<<<dim3(64 * 9 * 9), blk, 0, stream>>>(ws + D2, ws + D3, 128, 128, 9, 9);
        conv3x3_mod<<<dim3(4 * 4 * 64), blk, 2304, stream>>>(
            ws + D3, nullptr, WN(3), SBN(3), ws + E1, 64, 64, 129, 129, 64, 64, 2, 0, 1, 4, 4);
        conv3x3_mod<<<dim3(4 * 4 * 64), blk, 2304, stream>>>(
            ws + E1, nullptr, WN(4), SBN(4), ws + E2, 64, 64, 64, 64, 64, 64, 1, 1, 1, 4, 4);
        // f3 = conv(f2) -> E3; f3 = conv(f3) -> E1
        conv3x3_mod<<<dim3(4 * 4 * 64), blk, 2304, stream>>>(
            ws + E2, nullptr, WN(5), SBN(5), ws + E3, 64, 64, 64, 64, 64, 64, 1, 1, 1, 4, 4);
        conv3x3_mod<<<dim3(4 * 4 * 64), blk, 2304, stream>>>(
            ws + E3, nullptr, WN(6), SBN(6), ws + E1, 64, 64, 64, 64, 64, 64, 1, 1, 1, 4, 4);
        // f4 up: tconv(f3+f2) -> D3 (129^2); blur*4+bias+lrelu -> D1 (128^2); none-conv -> D3
        tconv3x3_mod<<<dim3(9 * 9 * 64), blk, 2304, stream>>>(
            ws + E1, ws + E2, WN(7), ws + D3, 64, 64, 64, 64, 9, 9);
        blur_up_act<<<dim3(64 * 8 * 8), blk, 0, stream>>>(ws + D3, SBN(7), ws + D1, 129, 129, 8, 8);
        conv3x3_mod<<<dim3(8 * 8 * 64), blk, 2304, stream>>>(
            ws + D1, nullptr, WN(8), SBN(8), ws + D3, 64, 64, 128, 128, 128, 128, 1, 1, 1, 8, 8);
        // f5 up: tconv(f4+f1) -> T1s (257^2); blur*4+bias+lrelu -> T2s (256^2); none-conv -> T1s
        tconv3x3_mod<<<dim3(17 * 17 * 64), blk, 2304, stream>>>(
            ws + D3, ws + D2, WN(9), ws + T1s, 64, 64, 128, 128, 17, 17);
        blur_up_act<<<dim3(64 * 16 * 16), blk, 0, stream>>>(ws + T1s, SBN(9), ws + T2s, 257, 257, 16, 16);
        conv3x3_mod<<<dim3(16 * 16 * 64), blk, 2304, stream>>>(
            ws + T2s, nullptr, WN(10), SBN(10), ws + T1s, 64, 64, 256, 256, 256, 256, 1, 1, 1, 16, 16);
        // out = modconv(f5+f0, c6, none, no act) -> out
        conv3x3_mod<<<dim3(16 * 16 * 3), blk, 2304, stream>>>(
            ws + T1s, ws + F0s, WN(11), SBN(11), outn, 64, 3, 256, 256, 256, 256, 1, 1, 0, 16, 16);
        #undef WN
        #undef SBN
    }
}

// Round 4
// 24164.835 us; speedup vs baseline: 1.5340x; 1.5340x over previous
//
#include <hip/hip_runtime.h>

#define LRELU(v) ((v) >= 0.f ? (v) : 0.2f * (v))

// ================= implicit-GEMM 3x3 conv, C=64 -> O=64, one sample =================
// in [64,Hin,Win]; Wt transposed [c][k][o] = [64][9][64]; bias[64]; out [64,Hout,Wout]
// Block: 256 thr -> 16x16 output px x 64 och. Micro-tile: 8 och x 8 px per thread.
template<int S>
__global__ void conv64_gemm(const float* __restrict__ in, const float* __restrict__ Wt,
                            const float* __restrict__ bias, float* __restrict__ out,
                            int Hin, int Win, int Hout, int Wout, int pad, int act, int tilesX)
{
    constexpr int CC  = (S == 1) ? 8 : 4;    // c-chunk
    constexpr int TIN = (S == 1) ? 18 : 33;  // staged input tile dim
    constexpr int RS  = (S == 1) ? 20 : 36;  // padded row stride
    constexpr int NF4 = (S == 1) ? 3 : 5;    // float4 row reads
    constexpr int PW  = NF4 * 4;             // row window regs
    extern __shared__ float lds[];
    float* it = lds;                         // [CC][TIN][RS]
    float* wl = lds + CC * TIN * RS;         // [CC*9*64]

    int b  = blockIdx.x;
    int tx = b % tilesX, ty = b / tilesX;
    int t  = threadIdx.x;
    int og = t >> 5;                         // 0..7  (och group)
    int pg = t & 31;                         // 0..31 (pixel group)
    int r  = pg >> 1, ch = pg & 1;           // out row 0..15, col half 0..1

    float acc[8][8];
    #pragma unroll
    for (int i = 0; i < 8; ++i)
        #pragma unroll
        for (int j = 0; j < 8; ++j) acc[i][j] = 0.f;

    const int y0 = ty * 16 * S - pad;
    const int x0 = tx * 16 * S - pad;
    const size_t plane = (size_t)Hin * Win;

    for (int c0 = 0; c0 < 64; c0 += CC) {
        __syncthreads();
        for (int i = t; i < CC * 9 * 64; i += 256) wl[i] = Wt[c0 * 9 * 64 + i];
        for (int i = t; i < CC * TIN * TIN; i += 256) {
            int cc  = i / (TIN * TIN);
            int rem = i - cc * (TIN * TIN);
            int rr  = rem / TIN, cl = rem - rr * TIN;
            int iy = y0 + rr, ix = x0 + cl;
            float v = 0.f;
            if ((unsigned)iy < (unsigned)Hin && (unsigned)ix < (unsigned)Win)
                v = in[(size_t)(c0 + cc) * plane + (size_t)iy * Win + ix];
            it[(cc * TIN + rr) * RS + cl] = v;
        }
        __syncthreads();
        for (int cc = 0; cc < CC; ++cc) {
            const float* base = it + cc * TIN * RS;
            #pragma unroll
            for (int ky = 0; ky < 3; ++ky) {
                float p[PW];
                const float* rowp = base + (r * S + ky) * RS + ch * 8 * S;
                #pragma unroll
                for (int q = 0; q < NF4; ++q) {
                    float4 f = *(const float4*)(rowp + q * 4);
                    p[q*4+0] = f.x; p[q*4+1] = f.y; p[q*4+2] = f.z; p[q*4+3] = f.w;
                }
                #pragma unroll
                for (int kx = 0; kx < 3; ++kx) {
                    const float* wp = wl + ((cc * 9) + ky * 3 + kx) * 64 + og * 8;
                    float4 wa = *(const float4*)wp;
                    float4 wb = *(const float4*)(wp + 4);
                    float w8[8] = {wa.x, wa.y, wa.z, wa.w, wb.x, wb.y, wb.z, wb.w};
                    #pragma unroll
                    for (int oi = 0; oi < 8; ++oi)
                        #pragma unroll
                        for (int j = 0; j < 8; ++j)
                            acc[oi][j] += w8[oi] * p[j * S + kx];
                }
            }
        }
    }

    int y  = ty * 16 + r;
    int xb = tx * 16 + ch * 8;
    #pragma unroll
    for (int oi = 0; oi < 8; ++oi) {
        int o = og * 8 + oi;
        float bo = bias[o];
        float v[8];
        #pragma unroll
        for (int j = 0; j < 8; ++j) {
            float a = acc[oi][j] + bo;
            v[j] = act ? LRELU(a) : a;
        }
        float* op = out + ((size_t)o * Hout + y) * Wout + xb;
        *(float4*)op       = make_float4(v[0], v[1], v[2], v[3]);
        *(float4*)(op + 4) = make_float4(v[4], v[5], v[6], v[7]);
    }
}

// ---------------- direct 3x3 conv, shared weights (guide g0 only), o-innermost ----------------
__global__ void conv3x3_guide(const float* __restrict__ in, const float* __restrict__ w,
                              const float* __restrict__ b, float* __restrict__ out,
                              int C, int O, int Hin, int Win, int Hout, int Wout,
                              int stride, int act, int tilesX, int tilesY)
{
    int bid = blockIdx.x;
    int o  = bid % O; bid /= O;
    int tx = bid % tilesX;
    int ty = bid / tilesX;
    extern __shared__ float wls[];
    int nw = C * 9;
    for (int i = threadIdx.x; i < nw; i += blockDim.x) wls[i] = w[o * nw + i];
    __syncthreads();
    int x = tx * 16 + (threadIdx.x & 15);
    int y = ty * 16 + (threadIdx.x >> 4);
    if (x >= Wout || y >= Hout) return;
    float acc = b[o];
    size_t plane = (size_t)Hin * Win;
    int iy0 = y * stride - 1, ix0 = x * stride - 1;
    for (int c = 0; c < C; ++c) {
        const float* ip = in + c * plane;
        const float* wc = wls + c * 9;
        #pragma unroll
        for (int ky = 0; ky < 3; ++ky) {
            int iy = iy0 + ky;
            if ((unsigned)iy >= (unsigned)Hin) continue;
            #pragma unroll
            for (int kx = 0; kx < 3; ++kx) {
                int ix = ix0 + kx;
                if ((unsigned)ix >= (unsigned)Win) continue;
                acc += ip[(size_t)iy * Win + ix] * wc[ky * 3 + kx];
            }
        }
    }
    if (act) acc = LRELU(acc);
    out[((size_t)o * Hout + y) * Wout + x] = acc;
}

// ---------------- direct 3x3 conv, per-sample weights [o][c][k] (f0: C=3, c6: O=3) ----------------
__global__ void conv3x3_mod(const float* __restrict__ in, const float* __restrict__ in2,
                            const float* __restrict__ W, const float* __restrict__ sb,
                            float* __restrict__ out,
                            int C, int O, int Hin, int Win, int Hout, int Wout,
                            int stride, int pad, int act, int tilesX, int tilesY)
{
    int bid = blockIdx.x;
    int o  = bid % O; bid /= O;
    int tx = bid % tilesX;
    int ty = bid / tilesX;
    extern __shared__ float wls[];
    int nw = C * 9;
    const float* wp = W + (size_t)o * nw;
    for (int i = threadIdx.x; i < nw; i += blockDim.x) wls[i] = wp[i];
    __syncthreads();
    int x = tx * 16 + (threadIdx.x & 15);
    int y = ty * 16 + (threadIdx.x >> 4);
    if (x >= Wout || y >= Hout) return;
    float acc = sb[o];
    size_t plane = (size_t)Hin * Win;
    int iy0 = y * stride - pad, ix0 = x * stride - pad;
    for (int c = 0; c < C; ++c) {
        const float* ip  = in + c * plane;
        const float* ip2 = in2 ? in2 + c * plane : nullptr;
        const float* wc  = wls + c * 9;
        #pragma unroll
        for (int ky = 0; ky < 3; ++ky) {
            int iy = iy0 + ky;
            if ((unsigned)iy >= (unsigned)Hin) continue;
            #pragma unroll
            for (int kx = 0; kx < 3; ++kx) {
                int ix = ix0 + kx;
                if ((unsigned)ix >= (unsigned)Win) continue;
                float xv = ip[(size_t)iy * Win + ix];
                if (ip2) xv += ip2[(size_t)iy * Win + ix];
                acc += xv * wc[ky * 3 + kx];
            }
        }
    }
    if (act) acc = LRELU(acc);
    out[((size_t)o * Hout + y) * Wout + x] = acc;
}

// ------- direct transposed 3x3 conv (stride-2 up), in1+in2, weights [o][c][k], o-innermost -------
__global__ void tconv3x3_mod(const float* __restrict__ in, const float* __restrict__ in2,
                             const float* __restrict__ W, float* __restrict__ out,
                             int C, int Hin, int Win, int tilesX, int tilesY)
{
    int Hout = 2 * Hin + 1, Wout = 2 * Win + 1;
    int bid = blockIdx.x;
    int o  = bid & 63; bid >>= 6;
    int tx = bid % tilesX;
    int ty = bid / tilesX;
    extern __shared__ float wls[];
    int nw = C * 9;
    const float* wp = W + (size_t)o * nw;
    for (int i = threadIdx.x; i < nw; i += blockDim.x) wls[i] = wp[i];
    __syncthreads();
    int x = tx * 16 + (threadIdx.x & 15);
    int y = ty * 16 + (threadIdx.x >> 4);
    if (x >= Wout || y >= Hout) return;
    float acc = 0.f;
    size_t plane = (size_t)Hin * Win;
    for (int c = 0; c < C; ++c) {
        const float* ip  = in  + c * plane;
        const float* ip2 = in2 + c * plane;
        const float* wc  = wls + c * 9;
        #pragma unroll
        for (int a = 0; a < 3; ++a) {
            int u = y - a;
            if (u < 0 || (u & 1)) continue;
            int iy = u >> 1;
            if (iy >= Hin) continue;
            #pragma unroll
            for (int b2 = 0; b2 < 3; ++b2) {
                int v = x - b2;
                if (v < 0 || (v & 1)) continue;
                int ix = v >> 1;
                if (ix >= Win) continue;
                acc += (ip[(size_t)iy * Win + ix] + ip2[(size_t)iy * Win + ix]) * wc[a * 3 + b2];
            }
        }
    }
    out[((size_t)o * Hout + y) * Wout + x] = acc;
}

// ---------------- 4x4 blur pad=2 (pre-down): out [64, H+1, W+1], /64 ----------------
__global__ void blur_down(const float* __restrict__ in, float* __restrict__ out,
                          int H, int W, int tilesX, int tilesY)
{
    int Ho = H + 1, Wo = W + 1;
    int bid = blockIdx.x;
    int tx = bid % tilesX; bid /= tilesX;
    int ty = bid % tilesY; bid /= tilesY;
    int p  = bid;
    int x = tx * 16 + (threadIdx.x & 15);
    int y = ty * 16 + (threadIdx.x >> 4);
    if (x >= Wo || y >= Ho) return;
    const float k[4] = {1.f, 3.f, 3.f, 1.f};
    const float* ip = in + (size_t)p * H * W;
    float acc = 0.f;
    #pragma unroll
    for (int ky = 0; ky < 4; ++ky) {
        int iy = y - 2 + ky;
        if ((unsigned)iy >= (unsigned)H) continue;
        float row = 0.f;
        #pragma unroll
        for (int kx = 0; kx < 4; ++kx) {
            int ix = x - 2 + kx;
            if ((unsigned)ix >= (unsigned)W) continue;
            row += ip[(size_t)iy * W + ix] * k[kx];
        }
        acc += row * k[ky];
    }
    out[((size_t)p * Ho + y) * Wo + x] = acc * (1.f / 64.f);
}

// ------- 4x4 blur pad=1 x4 (post-up) + bias + lrelu: [64,Hi,Wi] -> [64,Hi-1,Wi-1] -------
__global__ void blur_up_act(const float* __restrict__ in, const float* __restrict__ sb,
                            float* __restrict__ out, int Hi, int Wi, int tilesX, int tilesY)
{
    int Ho = Hi - 1, Wo = Wi - 1;
    int bid = blockIdx.x;
    int tx = bid % tilesX; bid /= tilesX;
    int ty = bid % tilesY; bid /= tilesY;
    int p  = bid;
    int x = tx * 16 + (threadIdx.x & 15);
    int y = ty * 16 + (threadIdx.x >> 4);
    if (x >= Wo || y >= Ho) return;
    const float k[4] = {1.f, 3.f, 3.f, 1.f};
    const float* ip = in + (size_t)p * Hi * Wi;
    float acc = 0.f;
    #pragma unroll
    for (int ky = 0; ky < 4; ++ky) {
        int iy = y - 1 + ky;
        if ((unsigned)iy >= (unsigned)Hi) continue;
        float row = 0.f;
        #pragma unroll
        for (int kx = 0; kx < 4; ++kx) {
            int ix = x - 1 + kx;
            if ((unsigned)ix >= (unsigned)Wi) continue;
            row += ip[(size_t)iy * Wi + ix] * k[kx];
        }
        acc += row * k[ky];
    }
    acc = acc * (4.f / 64.f) + sb[p];
    out[((size_t)p * Ho + y) * Wo + x] = LRELU(acc);
}

// ---------------- avg pool to 1x1 (64 planes, one sample) ----------------
__global__ void avgpool_hw(const float* __restrict__ in, float* __restrict__ out, int HW)
{
    int p = blockIdx.x;
    const float* ip = in + (size_t)p * HW;
    float s = 0.f;
    for (int i = threadIdx.x; i < HW; i += blockDim.x) s += ip[i];
    __shared__ float red[256];
    red[threadIdx.x] = s;
    __syncthreads();
    for (int off = 128; off; off >>= 1) {
        if ((int)threadIdx.x < off) red[threadIdx.x] += red[threadIdx.x + off];
        __syncthreads();
    }
    if (threadIdx.x == 0) out[p] = red[0] / (float)HW;
}

// ---------------- style FC (batched) ----------------
__global__ void style_fc(const float* __restrict__ s, const float* __restrict__ W,
                         const float* __restrict__ b, float* __restrict__ out, int outdim)
{
    int n = blockIdx.x;
    int i = threadIdx.x;
    if (i >= outdim) return;
    float acc = b[i];
    const float* sn = s + n * 64;
    const float* wi = W + i * 64;
    for (int f = 0; f < 64; ++f) acc += sn[f] * wi[f];
    out[n * 64 + i] = LRELU(acc);
}

// ------- modulate+demodulate; transpose=1 writes [c][k][o] layout for conv64_gemm -------
__global__ void modulate(const float* __restrict__ w, const float* __restrict__ sw,
                         float* __restrict__ wout, int O, int C, int transpose)
{
    int no = blockIdx.x;
    int o = no % O, n = no / O;
    int nw = C * 9;
    int t = threadIdx.x;
    float v[9];
    int cnt = 0;
    float ss = 0.f;
    for (int idx = t; idx < nw; idx += 64) {
        int c = idx / 9;
        float val = w[o * nw + idx] * sw[n * 64 + c];
        v[cnt++] = val;
        ss += val * val;
    }
    #pragma unroll
    for (int off = 32; off; off >>= 1) ss += __shfl_xor(ss, off);
    float d = rsqrtf(ss + 1e-8f);
    cnt = 0;
    for (int idx = t; idx < nw; idx += 64) {
        float val = v[cnt++] * d;
        if (transpose)
            wout[(size_t)n * nw * O + (size_t)idx * O + o] = val;
        else
            wout[(size_t)no * nw + idx] = val;
    }
}

// ------- guide weight transpose: gt[l][(c*9+k)*64+o] = grw[((l*64+o)*64+c)*9+k] -------
__global__ void guide_transpose(const float* __restrict__ grw, float* __restrict__ gt, int total)
{
    int i = blockIdx.x * 256 + threadIdx.x;
    if (i >= total) return;
    int l = i / 36864, rem = i % 36864;
    int idx = rem / 64, o = rem % 64;
    int c = idx / 9, k = idx % 9;
    gt[i] = grw[(((size_t)l * 64 + o) * 64 + c) * 9 + k];
}

__global__ void fill_sentinel(float* __restrict__ out, int n)
{
    int i = blockIdx.x * 256 + threadIdx.x;
    if (i < n) out[i] = 1.0e9f;
}

extern "C" void kernel_launch(void* const* d_in, const int* in_sizes, int n_in,
                              void* d_out, int out_size, void* d_ws, size_t ws_size,
                              hipStream_t stream)
{
    const float* x     = (const float*)d_in[0];
    const float* ref   = (const float*)d_in[1];
    const float* g0w   = (const float*)d_in[2];
    const float* g0b   = (const float*)d_in[3];
    const float* grw   = (const float*)d_in[4];
    const float* grb   = (const float*)d_in[5];
    const float* c0w   = (const float*)d_in[6];
    const float* c0swW = (const float*)d_in[7];
    const float* c0swb = (const float*)d_in[8];
    const float* c0sbW = (const float*)d_in[9];
    const float* c0sbb = (const float*)d_in[10];
    const float* midw  = (const float*)d_in[11];
    const float* midswW= (const float*)d_in[12];
    const float* midswb= (const float*)d_in[13];
    const float* midsbW= (const float*)d_in[14];
    const float* midsbb= (const float*)d_in[15];
    const float* c6w   = (const float*)d_in[16];
    const float* c6swW = (const float*)d_in[17];
    const float* c6swb = (const float*)d_in[18];
    const float* c6sbW = (const float*)d_in[19];
    const float* c6sbb = (const float*)d_in[20];
    float* out = (float*)d_out;
    float* ws  = (float*)d_ws;

    // -------- per-sample workspace layout (floats) --------
    const size_t F0s = 0;                    // f0 [64,256,256]
    const size_t T1s = 4194304ull;           // [64,257,257]-class
    const size_t T2s = 8421440ull;           // [64,256,256]
    const size_t D1  = 12615744ull;          // [64,128,128]
    const size_t D2  = 13664320ull;          // [64,128,128]
    const size_t D3  = 14712896ull;          // [64,129,129]-class
    const size_t E1  = 15777920ull;          // [64,64,64]
    const size_t E2  = 16040064ull;
    const size_t E3  = 16302208ull;
    const size_t SV  = 16564352ull;          // s [8,64]
    const size_t STY = 16564864ull;          // 12 x (sw 512 + sb 512)
    const size_t WM  = 16577152ull;          // modulated weights (all samples)
    const size_t GT  = 19553920ull;          // transposed guide weights [4][576][64]
    const size_t TOTAL = 19701376ull;        // ~78.8 MB
    if (ws_size < TOTAL * sizeof(float)) {
        fill_sentinel<<<dim3((out_size + 255) / 256), dim3(256), 0, stream>>>(out, out_size);
        return;
    }

    dim3 blk(256);
    const int LDS1 = 29952;   // conv64_gemm<1>
    const int LDS2 = 28224;   // conv64_gemm<2>

    // guide weights -> [c][k][o]
    guide_transpose<<<dim3(147456 / 256), blk, 0, stream>>>(grw, ws + GT, 147456);

    // ==================== guide net (per sample) -> s ====================
    for (int n = 0; n < 8; ++n) {
        const float* refn = ref + (size_t)n * 3 * 65536;
        conv3x3_guide<<<dim3(64 * 16 * 16), blk, 27 * 4, stream>>>(
            refn, g0w, g0b, ws + T1s, 3, 64, 256, 256, 256, 256, 1, 1, 16, 16);
        conv64_gemm<2><<<dim3(8 * 8), blk, LDS2, stream>>>(
            ws + T1s, ws + GT, grb, ws + D1, 256, 256, 128, 128, 1, 1, 8);
        conv64_gemm<1><<<dim3(8 * 8), blk, LDS1, stream>>>(
            ws + D1, ws + GT + 36864, grb + 64, ws + D2, 128, 128, 128, 128, 1, 1, 8);
        conv64_gemm<2><<<dim3(4 * 4), blk, LDS2, stream>>>(
            ws + D2, ws + GT + 73728, grb + 128, ws + E1, 128, 128, 64, 64, 1, 1, 4);
        conv64_gemm<1><<<dim3(4 * 4), blk, LDS1, stream>>>(
            ws + E1, ws + GT + 110592, grb + 192, ws + E2, 64, 64, 64, 64, 1, 0, 4);
        avgpool_hw<<<dim3(64), blk, 0, stream>>>(ws + E2, ws + SV + n * 64, 4096);
    }

    // ==================== styles + modulated weights (batched) ====================
    const float* Wt[12];  const float* swWp[12]; const float* swbp[12];
    const float* sbWp[12]; const float* sbbp[12];
    int Ci[12], Oi[12];
    size_t wmo[12];
    Wt[0] = c0w; swWp[0] = c0swW; swbp[0] = c0swb; sbWp[0] = c0sbW; sbbp[0] = c0sbb;
    Ci[0] = 3; Oi[0] = 64; wmo[0] = WM;
    for (int i = 0; i < 10; ++i) {
        Wt[1 + i]   = midw   + (size_t)i * 36864;
        swWp[1 + i] = midswW + (size_t)i * 4096;
        swbp[1 + i] = midswb + (size_t)i * 64;
        sbWp[1 + i] = midsbW + (size_t)i * 4096;
        sbbp[1 + i] = midsbb + (size_t)i * 64;
        Ci[1 + i] = 64; Oi[1 + i] = 64;
        wmo[1 + i] = WM + 13824ull + (size_t)i * 294912ull;
    }
    Wt[11] = c6w; swWp[11] = c6swW; swbp[11] = c6swb; sbWp[11] = c6sbW; sbbp[11] = c6sbb;
    Ci[11] = 64; Oi[11] = 3; wmo[11] = WM + 13824ull + 2949120ull;

    // transpose flags per CONSUMER:
    //  i=0 (c0 -> conv3x3_mod): 0
    //  i=1..10 (mids): conv64_gemm consumers -> 1, EXCEPT i=7 (mid6) and i=9 (mid8)
    //                  which feed tconv3x3_mod ([o][c][k]) -> 0
    //  i=11 (c6 -> conv3x3_mod): 0
    const int trf[12] = {0, 1, 1, 1, 1, 1, 1, 0, 1, 0, 1, 0};

    for (int i = 0; i < 12; ++i) {
        style_fc<<<dim3(8), dim3(64), 0, stream>>>(ws + SV, swWp[i], swbp[i], ws + STY + i * 1024, Ci[i]);
        style_fc<<<dim3(8), dim3(64), 0, stream>>>(ws + SV, sbWp[i], sbbp[i], ws + STY + i * 1024 + 512, Oi[i]);
        modulate<<<dim3(8 * Oi[i]), dim3(64), 0, stream>>>(Wt[i], ws + STY + i * 1024, ws + wmo[i], Oi[i], Ci[i], trf[i]);
    }

    // ==================== main path (per sample) ====================
    for (int n = 0; n < 8; ++n) {
        const float* xn = x + (size_t)n * 3 * 65536;
        float* outn = out + (size_t)n * 3 * 65536;
        #define WN(i)  (ws + wmo[i] + (size_t)n * Oi[i] * Ci[i] * 9)
        #define SBN(i) (ws + STY + (i) * 1024 + 512 + n * 64)
        // f0 = modconv(x, c0)
        conv3x3_mod<<<dim3(64 * 16 * 16), blk, 27 * 4, stream>>>(
            xn, nullptr, WN(0), SBN(0), ws + F0s, 3, 64, 256, 256, 256, 256, 1, 1, 1, 16, 16);
        // f1 down
        blur_down<<<dim3(64 * 17 * 17), blk, 0, stream>>>(ws + F0s, ws + T1s, 256, 256, 17, 17);
        conv64_gemm<2><<<dim3(8 * 8), blk, LDS2, stream>>>(
            ws + T1s, WN(1), SBN(1), ws + D1, 257, 257, 128, 128, 0, 1, 8);
        conv64_gemm<1><<<dim3(8 * 8), blk, LDS1, stream>>>(
            ws + D1, WN(2), SBN(2), ws + D2, 128, 128, 128, 128, 1, 1, 8);
        // f2 down
        blur_down<<<dim3(64 * 9 * 9), blk, 0, stream>>>(ws + D2, ws + D3, 128, 128, 9, 9);
        conv64_gemm<2><<<dim3(4 * 4), blk, LDS2, stream>>>(
            ws + D3, WN(3), SBN(3), ws + E1, 129, 129, 64, 64, 0, 1, 4);
        conv64_gemm<1><<<dim3(4 * 4), blk, LDS1, stream>>>(
            ws + E1, WN(4), SBN(4), ws + E2, 64, 64, 64, 64, 1, 1, 4);
        // f3 x2
        conv64_gemm<1><<<dim3(4 * 4), blk, LDS1, stream>>>(
            ws + E2, WN(5), SBN(5), ws + E3, 64, 64, 64, 64, 1, 1, 4);
        conv64_gemm<1><<<dim3(4 * 4), blk, LDS1, stream>>>(
            ws + E3, WN(6), SBN(6), ws + E1, 64, 64, 64, 64, 1, 1, 4);
        // f4 up: tconv(f3+f2) -> 129^2; blur+bias+lrelu -> 128^2; conv
        tconv3x3_mod<<<dim3(64 * 9 * 9), blk, 2304, stream>>>(
            ws + E1, ws + E2, WN(7), ws + D3, 64, 64, 64, 9, 9);
        blur_up_act<<<dim3(64 * 8 * 8), blk, 0, stream>>>(ws + D3, SBN(7), ws + D1, 129, 129, 8, 8);
        conv64_gemm<1><<<dim3(8 * 8), blk, LDS1, stream>>>(
            ws + D1, WN(8), SBN(8), ws + D3, 128, 128, 128, 128, 1, 1, 8);
        // f5 up: tconv(f4+f1) -> 257^2; blur+bias+lrelu -> 256^2; conv
        tconv3x3_mod<<<dim3(64 * 17 * 17), blk, 2304, stream>>>(
            ws + D3, ws + D2, WN(9), ws + T1s, 64, 128, 128, 17, 17);
        blur_up_act<<<dim3(64 * 16 * 16), blk, 0, stream>>>(ws + T1s, SBN(9), ws + T2s, 257, 257, 16, 16);
        conv64_gemm<1><<<dim3(16 * 16), blk, LDS1, stream>>>(
            ws + T2s, WN(10), SBN(10), ws + T1s, 256, 256, 256, 256, 1, 1, 16);
        // out = modconv(f5+f0, c6, no act)
        conv3x3_mod<<<dim3(3 * 16 * 16), blk, 2304, stream>>>(
            ws + T1s, ws + F0s, WN(11), SBN(11), outn, 64, 3, 256, 256, 256, 256, 1, 1, 0, 16, 16);
        #undef WN
        #undef SBN
    }
}

// Round 5
// 18254.813 us; speedup vs baseline: 2.0306x; 1.3238x over previous
//
#include <hip/hip_runtime.h>

#define LRELU(v) ((v) >= 0.f ? (v) : 0.2f * (v))

// ================= implicit-GEMM 3x3 conv, C=64 -> O=64, one sample =================
// in [64,Hin,Win]; Wt transposed [c][k][o] = [64][9][64]; bias[64]; out [64,Hout,Wout]
// Block: 256 thr -> 16x16 output px x 64 och. Micro-tile: 8 och x 8 px per thread.
template<int S>
__global__ void conv64_gemm(const float* __restrict__ in, const float* __restrict__ Wt,
                            const float* __restrict__ bias, float* __restrict__ out,
                            int Hin, int Win, int Hout, int Wout, int pad, int act, int tilesX)
{
    constexpr int CC  = (S == 1) ? 8 : 4;    // c-chunk
    constexpr int TIN = (S == 1) ? 18 : 33;  // staged input tile dim
    constexpr int RS  = (S == 1) ? 20 : 36;  // padded row stride
    constexpr int NF4 = (S == 1) ? 3 : 5;    // float4 row reads
    constexpr int PW  = NF4 * 4;             // row window regs
    extern __shared__ float lds[];
    float* it = lds;                         // [CC][TIN][RS]
    float* wl = lds + CC * TIN * RS;         // [CC*9*64]

    int b  = blockIdx.x;
    int tx = b % tilesX, ty = b / tilesX;
    int t  = threadIdx.x;
    int og = t >> 5;                         // 0..7  (och group)
    int pg = t & 31;                         // 0..31 (pixel group)
    int r  = pg >> 1, ch = pg & 1;           // out row 0..15, col half 0..1

    float acc[8][8];
    #pragma unroll
    for (int i = 0; i < 8; ++i)
        #pragma unroll
        for (int j = 0; j < 8; ++j) acc[i][j] = 0.f;

    const int y0 = ty * 16 * S - pad;
    const int x0 = tx * 16 * S - pad;
    const size_t plane = (size_t)Hin * Win;

    for (int c0 = 0; c0 < 64; c0 += CC) {
        __syncthreads();
        for (int i = t; i < CC * 9 * 64; i += 256) wl[i] = Wt[c0 * 9 * 64 + i];
        for (int i = t; i < CC * TIN * TIN; i += 256) {
            int cc  = i / (TIN * TIN);
            int rem = i - cc * (TIN * TIN);
            int rr  = rem / TIN, cl = rem - rr * TIN;
            int iy = y0 + rr, ix = x0 + cl;
            float v = 0.f;
            if ((unsigned)iy < (unsigned)Hin && (unsigned)ix < (unsigned)Win)
                v = in[(size_t)(c0 + cc) * plane + (size_t)iy * Win + ix];
            it[(cc * TIN + rr) * RS + cl] = v;
        }
        __syncthreads();
        for (int cc = 0; cc < CC; ++cc) {
            const float* base = it + cc * TIN * RS;
            #pragma unroll
            for (int ky = 0; ky < 3; ++ky) {
                float p[PW];
                const float* rowp = base + (r * S + ky) * RS + ch * 8 * S;
                #pragma unroll
                for (int q = 0; q < NF4; ++q) {
                    float4 f = *(const float4*)(rowp + q * 4);
                    p[q*4+0] = f.x; p[q*4+1] = f.y; p[q*4+2] = f.z; p[q*4+3] = f.w;
                }
                #pragma unroll
                for (int kx = 0; kx < 3; ++kx) {
                    const float* wp = wl + ((cc * 9) + ky * 3 + kx) * 64 + og * 8;
                    float4 wa = *(const float4*)wp;
                    float4 wb = *(const float4*)(wp + 4);
                    float w8[8] = {wa.x, wa.y, wa.z, wa.w, wb.x, wb.y, wb.z, wb.w};
                    #pragma unroll
                    for (int oi = 0; oi < 8; ++oi)
                        #pragma unroll
                        for (int j = 0; j < 8; ++j)
                            acc[oi][j] += w8[oi] * p[j * S + kx];
                }
            }
        }
    }

    int y  = ty * 16 + r;
    int xb = tx * 16 + ch * 8;
    #pragma unroll
    for (int oi = 0; oi < 8; ++oi) {
        int o = og * 8 + oi;
        float bo = bias[o];
        float v[8];
        #pragma unroll
        for (int j = 0; j < 8; ++j) {
            float a = acc[oi][j] + bo;
            v[j] = act ? LRELU(a) : a;
        }
        float* op = out + ((size_t)o * Hout + y) * Wout + xb;
        *(float4*)op       = make_float4(v[0], v[1], v[2], v[3]);
        *(float4*)(op + 4) = make_float4(v[4], v[5], v[6], v[7]);
    }
}

// ===== fused up-conv: tconv(s2,3x3) + blur(4x4,x4/64) + bias + lrelu, C=64 -> O=64 =====
// Equivalent to, for each output parity (py,px), a 3x3 conv over the (non-upsampled) input
// with combined weights G2[c][py][px][ty][tx][o]. in/in2 summed (residual). out [64,2Hin,2Win].
// Block: 256 thr -> 16x16 out px x 64 och; parity is wave-uniform (q remap).
__global__ void upconv64_gemm(const float* __restrict__ in, const float* __restrict__ in2,
                              const float* __restrict__ G2, const float* __restrict__ sb,
                              float* __restrict__ out, int Hin, int Win, int tilesX)
{
    constexpr int CC = 4;
    constexpr int RS = 12;                    // 10-wide window, padded
    extern __shared__ float lds[];
    float* it = lds;                          // [CC][10][RS]
    float* wl = lds + CC * 10 * RS;           // [CC][2][2][9][64] = CC*2304

    int b  = blockIdx.x;
    int tx = b % tilesX, ty = b / tilesX;
    int t  = threadIdx.x;
    int og = t & 7;                           // och group (8 och)
    int q  = t >> 3;                          // 0..31
    int rhalf = q & 7;
    int pxb   = (q >> 3) & 1;                 // out-col parity (wave-uniform)
    int rpar  = q >> 4;                       // out-row parity (wave-uniform)
    int r = 2 * rhalf + rpar;                 // out row in tile
    const int Y0 = ty * 16, X0 = tx * 16;
    const int gy0 = Y0 / 2 - 1;               // global input row of staged row 0
    const int gx0 = X0 / 2 - 1;
    const size_t plane = (size_t)Hin * Win;

    float acc[8][8];
    #pragma unroll
    for (int i = 0; i < 8; ++i)
        #pragma unroll
        for (int j = 0; j < 8; ++j) acc[i][j] = 0.f;

    for (int c0 = 0; c0 < 64; c0 += CC) {
        __syncthreads();
        // stage combined weights (CC*2304 floats) as float4
        {
            const float4* src = (const float4*)(G2 + (size_t)c0 * 2304);
            float4* dst = (float4*)wl;
            for (int i = t; i < CC * 2304 / 4; i += 256) dst[i] = src[i];
        }
        // stage input window (CC*10*RS floats), zero-filled OOB / pad cols
        for (int i = t; i < CC * 10 * RS; i += 256) {
            int cc  = i / (10 * RS);
            int rem = i - cc * (10 * RS);
            int rr  = rem / RS, cl = rem - rr * RS;
            int gi = gy0 + rr, gj = gx0 + cl;
            float v = 0.f;
            if (cl < 10 && (unsigned)gi < (unsigned)Hin && (unsigned)gj < (unsigned)Win) {
                size_t off = (size_t)(c0 + cc) * plane + (size_t)gi * Win + gj;
                v = in[off] + in2[off];
            }
            it[i] = v;
        }
        __syncthreads();
        for (int cc = 0; cc < CC; ++cc) {
            const float* ib = it + cc * 10 * RS;
            const float* wb = wl + cc * 2304 + (rpar * 2 + pxb) * 576;
            #pragma unroll
            for (int ty2 = 0; ty2 < 3; ++ty2) {
                float p[12];
                const float* rowp = ib + (rhalf + ty2) * RS;
                #pragma unroll
                for (int qq = 0; qq < 3; ++qq) {
                    float4 f = *(const float4*)(rowp + qq * 4);
                    p[qq*4+0] = f.x; p[qq*4+1] = f.y; p[qq*4+2] = f.z; p[qq*4+3] = f.w;
                }
                #pragma unroll
                for (int tx2 = 0; tx2 < 3; ++tx2) {
                    const float* wp = wb + (ty2 * 3 + tx2) * 64 + og * 8;
                    float4 wa = *(const float4*)wp;
                    float4 wv = *(const float4*)(wp + 4);
                    float w8[8] = {wa.x, wa.y, wa.z, wa.w, wv.x, wv.y, wv.z, wv.w};
                    #pragma unroll
                    for (int oi = 0; oi < 8; ++oi)
                        #pragma unroll
                        for (int k = 0; k < 8; ++k)
                            acc[oi][k] += w8[oi] * p[k + tx2];
                }
            }
        }
    }

    const int Hout = 2 * Hin, Wout = 2 * Win;
    int y = Y0 + r;
    #pragma unroll
    for (int oi = 0; oi < 8; ++oi) {
        int o = og * 8 + oi;
        float bo = sb[o];
        float* op = out + ((size_t)o * Hout + y) * Wout;
        #pragma unroll
        for (int k = 0; k < 8; ++k) {
            float a = acc[oi][k] + bo;
            op[X0 + 2 * k + pxb] = LRELU(a);
        }
    }
}

// ------- build combined up-weights: G2[c][py][px][ty][tx][o] from W [o][c][3][3] -------
// G2 = (1/16) * sum_{a,b} K[a+dy] K[b+dx] W[a][b], dy=2ty-1-py, dx=2tx-1-px
__global__ void combine_up_w(const float* __restrict__ W, float* __restrict__ G2)
{
    int i = blockIdx.x * 256 + threadIdx.x;
    if (i >= 147456) return;
    int o = i & 63;
    int rest = i >> 6;              // c*36 + m
    int m = rest % 36, c = rest / 36;
    int txk = m % 3, tyk = (m / 3) % 3;
    int px = (m / 9) & 1, py = m / 18;
    int dy = 2 * tyk - 1 - py, dx = 2 * txk - 1 - px;
    const float K[4] = {1.f, 3.f, 3.f, 1.f};
    const float* wp = W + ((size_t)o * 64 + c) * 9;
    float s = 0.f;
    #pragma unroll
    for (int a = 0; a < 3; ++a) {
        int ky = a + dy;
        if ((unsigned)ky >= 4u) continue;
        #pragma unroll
        for (int b2 = 0; b2 < 3; ++b2) {
            int kx = b2 + dx;
            if ((unsigned)kx >= 4u) continue;
            s += K[ky] * K[kx] * wp[a * 3 + b2];
        }
    }
    G2[i] = s * (1.f / 16.f);
}

// ---------------- direct 3x3 conv, shared weights (guide g0 only), o-innermost ----------------
__global__ void conv3x3_guide(const float* __restrict__ in, const float* __restrict__ w,
                              const float* __restrict__ b, float* __restrict__ out,
                              int C, int O, int Hin, int Win, int Hout, int Wout,
                              int stride, int act, int tilesX, int tilesY)
{
    int bid = blockIdx.x;
    int o  = bid % O; bid /= O;
    int tx = bid % tilesX;
    int ty = bid / tilesX;
    extern __shared__ float wls[];
    int nw = C * 9;
    for (int i = threadIdx.x; i < nw; i += blockDim.x) wls[i] = w[o * nw + i];
    __syncthreads();
    int x = tx * 16 + (threadIdx.x & 15);
    int y = ty * 16 + (threadIdx.x >> 4);
    if (x >= Wout || y >= Hout) return;
    float acc = b[o];
    size_t plane = (size_t)Hin * Win;
    int iy0 = y * stride - 1, ix0 = x * stride - 1;
    for (int c = 0; c < C; ++c) {
        const float* ip = in + c * plane;
        const float* wc = wls + c * 9;
        #pragma unroll
        for (int ky = 0; ky < 3; ++ky) {
            int iy = iy0 + ky;
            if ((unsigned)iy >= (unsigned)Hin) continue;
            #pragma unroll
            for (int kx = 0; kx < 3; ++kx) {
                int ix = ix0 + kx;
                if ((unsigned)ix >= (unsigned)Win) continue;
                acc += ip[(size_t)iy * Win + ix] * wc[ky * 3 + kx];
            }
        }
    }
    if (act) acc = LRELU(acc);
    out[((size_t)o * Hout + y) * Wout + x] = acc;
}

// ---------------- direct 3x3 conv, per-sample weights [o][c][k] (f0: C=3, c6: O=3) ----------------
__global__ void conv3x3_mod(const float* __restrict__ in, const float* __restrict__ in2,
                            const float* __restrict__ W, const float* __restrict__ sb,
                            float* __restrict__ out,
                            int C, int O, int Hin, int Win, int Hout, int Wout,
                            int stride, int pad, int act, int tilesX, int tilesY)
{
    int bid = blockIdx.x;
    int o  = bid % O; bid /= O;
    int tx = bid % tilesX;
    int ty = bid / tilesX;
    extern __shared__ float wls[];
    int nw = C * 9;
    const float* wp = W + (size_t)o * nw;
    for (int i = threadIdx.x; i < nw; i += blockDim.x) wls[i] = wp[i];
    __syncthreads();
    int x = tx * 16 + (threadIdx.x & 15);
    int y = ty * 16 + (threadIdx.x >> 4);
    if (x >= Wout || y >= Hout) return;
    float acc = sb[o];
    size_t plane = (size_t)Hin * Win;
    int iy0 = y * stride - pad, ix0 = x * stride - pad;
    for (int c = 0; c < C; ++c) {
        const float* ip  = in + c * plane;
        const float* ip2 = in2 ? in2 + c * plane : nullptr;
        const float* wc  = wls + c * 9;
        #pragma unroll
        for (int ky = 0; ky < 3; ++ky) {
            int iy = iy0 + ky;
            if ((unsigned)iy >= (unsigned)Hin) continue;
            #pragma unroll
            for (int kx = 0; kx < 3; ++kx) {
                int ix = ix0 + kx;
                if ((unsigned)ix >= (unsigned)Win) continue;
                float xv = ip[(size_t)iy * Win + ix];
                if (ip2) xv += ip2[(size_t)iy * Win + ix];
                acc += xv * wc[ky * 3 + kx];
            }
        }
    }
    if (act) acc = LRELU(acc);
    out[((size_t)o * Hout + y) * Wout + x] = acc;
}

// ---------------- 4x4 blur pad=2 (pre-down): out [64, H+1, W+1], /64 ----------------
__global__ void blur_down(const float* __restrict__ in, float* __restrict__ out,
                          int H, int W, int tilesX, int tilesY)
{
    int Ho = H + 1, Wo = W + 1;
    int bid = blockIdx.x;
    int tx = bid % tilesX; bid /= tilesX;
    int ty = bid % tilesY; bid /= tilesY;
    int p  = bid;
    int x = tx * 16 + (threadIdx.x & 15);
    int y = ty * 16 + (threadIdx.x >> 4);
    if (x >= Wo || y >= Ho) return;
    const float k[4] = {1.f, 3.f, 3.f, 1.f};
    const float* ip = in + (size_t)p * H * W;
    float acc = 0.f;
    #pragma unroll
    for (int ky = 0; ky < 4; ++ky) {
        int iy = y - 2 + ky;
        if ((unsigned)iy >= (unsigned)H) continue;
        float row = 0.f;
        #pragma unroll
        for (int kx = 0; kx < 4; ++kx) {
            int ix = x - 2 + kx;
            if ((unsigned)ix >= (unsigned)W) continue;
            row += ip[(size_t)iy * W + ix] * k[kx];
        }
        acc += row * k[ky];
    }
    out[((size_t)p * Ho + y) * Wo + x] = acc * (1.f / 64.f);
}

// ---------------- avg pool to 1x1 (64 planes, one sample) ----------------
__global__ void avgpool_hw(const float* __restrict__ in, float* __restrict__ out, int HW)
{
    int p = blockIdx.x;
    const float* ip = in + (size_t)p * HW;
    float s = 0.f;
    for (int i = threadIdx.x; i < HW; i += blockDim.x) s += ip[i];
    __shared__ float red[256];
    red[threadIdx.x] = s;
    __syncthreads();
    for (int off = 128; off; off >>= 1) {
        if ((int)threadIdx.x < off) red[threadIdx.x] += red[threadIdx.x + off];
        __syncthreads();
    }
    if (threadIdx.x == 0) out[p] = red[0] / (float)HW;
}

// ---------------- style FC (batched) ----------------
__global__ void style_fc(const float* __restrict__ s, const float* __restrict__ W,
                         const float* __restrict__ b, float* __restrict__ out, int outdim)
{
    int n = blockIdx.x;
    int i = threadIdx.x;
    if (i >= outdim) return;
    float acc = b[i];
    const float* sn = s + n * 64;
    const float* wi = W + i * 64;
    for (int f = 0; f < 64; ++f) acc += sn[f] * wi[f];
    out[n * 64 + i] = LRELU(acc);
}

// ------- modulate+demodulate; transpose=1 writes [c][k][o] layout for conv64_gemm -------
__global__ void modulate(const float* __restrict__ w, const float* __restrict__ sw,
                         float* __restrict__ wout, int O, int C, int transpose)
{
    int no = blockIdx.x;
    int o = no % O, n = no / O;
    int nw = C * 9;
    int t = threadIdx.x;
    float v[9];
    int cnt = 0;
    float ss = 0.f;
    for (int idx = t; idx < nw; idx += 64) {
        int c = idx / 9;
        float val = w[o * nw + idx] * sw[n * 64 + c];
        v[cnt++] = val;
        ss += val * val;
    }
    #pragma unroll
    for (int off = 32; off; off >>= 1) ss += __shfl_xor(ss, off);
    float d = rsqrtf(ss + 1e-8f);
    cnt = 0;
    for (int idx = t; idx < nw; idx += 64) {
        float val = v[cnt++] * d;
        if (transpose)
            wout[(size_t)n * nw * O + (size_t)idx * O + o] = val;
        else
            wout[(size_t)no * nw + idx] = val;
    }
}

// ------- guide weight transpose: gt[l][(c*9+k)*64+o] = grw[((l*64+o)*64+c)*9+k] -------
__global__ void guide_transpose(const float* __restrict__ grw, float* __restrict__ gt, int total)
{
    int i = blockIdx.x * 256 + threadIdx.x;
    if (i >= total) return;
    int l = i / 36864, rem = i % 36864;
    int idx = rem / 64, o = rem % 64;
    int c = idx / 9, k = idx % 9;
    gt[i] = grw[(((size_t)l * 64 + o) * 64 + c) * 9 + k];
}

__global__ void fill_sentinel(float* __restrict__ out, int n)
{
    int i = blockIdx.x * 256 + threadIdx.x;
    if (i < n) out[i] = 1.0e9f;
}

extern "C" void kernel_launch(void* const* d_in, const int* in_sizes, int n_in,
                              void* d_out, int out_size, void* d_ws, size_t ws_size,
                              hipStream_t stream)
{
    const float* x     = (const float*)d_in[0];
    const float* ref   = (const float*)d_in[1];
    const float* g0w   = (const float*)d_in[2];
    const float* g0b   = (const float*)d_in[3];
    const float* grw   = (const float*)d_in[4];
    const float* grb   = (const float*)d_in[5];
    const float* c0w   = (const float*)d_in[6];
    const float* c0swW = (const float*)d_in[7];
    const float* c0swb = (const float*)d_in[8];
    const float* c0sbW = (const float*)d_in[9];
    const float* c0sbb = (const float*)d_in[10];
    const float* midw  = (const float*)d_in[11];
    const float* midswW= (const float*)d_in[12];
    const float* midswb= (const float*)d_in[13];
    const float* midsbW= (const float*)d_in[14];
    const float* midsbb= (const float*)d_in[15];
    const float* c6w   = (const float*)d_in[16];
    const float* c6swW = (const float*)d_in[17];
    const float* c6swb = (const float*)d_in[18];
    const float* c6sbW = (const float*)d_in[19];
    const float* c6sbb = (const float*)d_in[20];
    float* out = (float*)d_out;
    float* ws  = (float*)d_ws;

    // -------- per-sample workspace layout (floats) — unchanged, proven to fit --------
    const size_t F0s = 0;                    // f0 [64,256,256]
    const size_t T1s = 4194304ull;           // [64,257,257]-class (blur out / f5 final)
    const size_t T2s = 8421440ull;           // [64,256,256] (f4-G2 scratch / f5up out)
    const size_t D1  = 12615744ull;          // [64,128,128] (f1a / f4up out / f5-G2 scratch)
    const size_t D2  = 13664320ull;          // [64,128,128] f1 final
    const size_t D3  = 14712896ull;          // [64,129,129]-class (f2 blur / f4 final)
    const size_t E1  = 15777920ull;          // [64,64,64]
    const size_t E2  = 16040064ull;
    const size_t E3  = 16302208ull;
    const size_t SV  = 16564352ull;          // s [8,64]
    const size_t STY = 16564864ull;          // 12 x (sw 512 + sb 512)
    const size_t WM  = 16577152ull;          // modulated weights (all samples)
    const size_t GT  = 19553920ull;          // transposed guide weights [4][576][64]
    const size_t TOTAL = 19701376ull;        // ~78.8 MB
    if (ws_size < TOTAL * sizeof(float)) {
        fill_sentinel<<<dim3((out_size + 255) / 256), dim3(256), 0, stream>>>(out, out_size);
        return;
    }

    dim3 blk(256);
    const int LDS1 = 29952;   // conv64_gemm<1>
    const int LDS2 = 28224;   // conv64_gemm<2>
    const int LDSU = 38784;   // upconv64_gemm: (4*120 + 4*2304)*4

    // guide weights -> [c][k][o]
    guide_transpose<<<dim3(147456 / 256), blk, 0, stream>>>(grw, ws + GT, 147456);

    // ==================== guide net (per sample) -> s ====================
    for (int n = 0; n < 8; ++n) {
        const float* refn = ref + (size_t)n * 3 * 65536;
        conv3x3_guide<<<dim3(64 * 16 * 16), blk, 27 * 4, stream>>>(
            refn, g0w, g0b, ws + T1s, 3, 64, 256, 256, 256, 256, 1, 1, 16, 16);
        conv64_gemm<2><<<dim3(8 * 8), blk, LDS2, stream>>>(
            ws + T1s, ws + GT, grb, ws + D1, 256, 256, 128, 128, 1, 1, 8);
        conv64_gemm<1><<<dim3(8 * 8), blk, LDS1, stream>>>(
            ws + D1, ws + GT + 36864, grb + 64, ws + D2, 128, 128, 128, 128, 1, 1, 8);
        conv64_gemm<2><<<dim3(4 * 4), blk, LDS2, stream>>>(
            ws + D2, ws + GT + 73728, grb + 128, ws + E1, 128, 128, 64, 64, 1, 1, 4);
        conv64_gemm<1><<<dim3(4 * 4), blk, LDS1, stream>>>(
            ws + E1, ws + GT + 110592, grb + 192, ws + E2, 64, 64, 64, 64, 1, 0, 4);
        avgpool_hw<<<dim3(64), blk, 0, stream>>>(ws + E2, ws + SV + n * 64, 4096);
    }

    // ==================== styles + modulated weights (batched) ====================
    const float* Wt[12];  const float* swWp[12]; const float* swbp[12];
    const float* sbWp[12]; const float* sbbp[12];
    int Ci[12], Oi[12];
    size_t wmo[12];
    Wt[0] = c0w; swWp[0] = c0swW; swbp[0] = c0swb; sbWp[0] = c0sbW; sbbp[0] = c0sbb;
    Ci[0] = 3; Oi[0] = 64; wmo[0] = WM;
    for (int i = 0; i < 10; ++i) {
        Wt[1 + i]   = midw   + (size_t)i * 36864;
        swWp[1 + i] = midswW + (size_t)i * 4096;
        swbp[1 + i] = midswb + (size_t)i * 64;
        sbWp[1 + i] = midsbW + (size_t)i * 4096;
        sbbp[1 + i] = midsbb + (size_t)i * 64;
        Ci[1 + i] = 64; Oi[1 + i] = 64;
        wmo[1 + i] = WM + 13824ull + (size_t)i * 294912ull;
    }
    Wt[11] = c6w; swWp[11] = c6swW; swbp[11] = c6swb; sbWp[11] = c6sbW; sbbp[11] = c6sbb;
    Ci[11] = 64; Oi[11] = 3; wmo[11] = WM + 13824ull + 2949120ull;

    // transpose flags per CONSUMER:
    //  i=0 (c0 -> conv3x3_mod): 0;  i=11 (c6 -> conv3x3_mod): 0
    //  i=7 (mid6) / i=9 (mid8): consumed by combine_up_w as [o][c][3][3] -> 0
    //  others: conv64_gemm -> 1
    const int trf[12] = {0, 1, 1, 1, 1, 1, 1, 0, 1, 0, 1, 0};

    for (int i = 0; i < 12; ++i) {
        style_fc<<<dim3(8), dim3(64), 0, stream>>>(ws + SV, swWp[i], swbp[i], ws + STY + i * 1024, Ci[i]);
        style_fc<<<dim3(8), dim3(64), 0, stream>>>(ws + SV, sbWp[i], sbbp[i], ws + STY + i * 1024 + 512, Oi[i]);
        modulate<<<dim3(8 * Oi[i]), dim3(64), 0, stream>>>(Wt[i], ws + STY + i * 1024, ws + wmo[i], Oi[i], Ci[i], trf[i]);
    }

    // ==================== main path (per sample) ====================
    for (int n = 0; n < 8; ++n) {
        const float* xn = x + (size_t)n * 3 * 65536;
        float* outn = out + (size_t)n * 3 * 65536;
        #define WN(i)  (ws + wmo[i] + (size_t)n * Oi[i] * Ci[i] * 9)
        #define SBN(i) (ws + STY + (i) * 1024 + 512 + n * 64)
        // f0 = modconv(x, c0)
        conv3x3_mod<<<dim3(64 * 16 * 16), blk, 27 * 4, stream>>>(
            xn, nullptr, WN(0), SBN(0), ws + F0s, 3, 64, 256, 256, 256, 256, 1, 1, 1, 16, 16);
        // f1 down
        blur_down<<<dim3(64 * 17 * 17), blk, 0, stream>>>(ws + F0s, ws + T1s, 256, 256, 17, 17);
        conv64_gemm<2><<<dim3(8 * 8), blk, LDS2, stream>>>(
            ws + T1s, WN(1), SBN(1), ws + D1, 257, 257, 128, 128, 0, 1, 8);
        conv64_gemm<1><<<dim3(8 * 8), blk, LDS1, stream>>>(
            ws + D1, WN(2), SBN(2), ws + D2, 128, 128, 128, 128, 1, 1, 8);
        // f2 down
        blur_down<<<dim3(64 * 9 * 9), blk, 0, stream>>>(ws + D2, ws + D3, 128, 128, 9, 9);
        conv64_gemm<2><<<dim3(4 * 4), blk, LDS2, stream>>>(
            ws + D3, WN(3), SBN(3), ws + E1, 129, 129, 64, 64, 0, 1, 4);
        conv64_gemm<1><<<dim3(4 * 4), blk, LDS1, stream>>>(
            ws + E1, WN(4), SBN(4), ws + E2, 64, 64, 64, 64, 1, 1, 4);
        // f3 x2
        conv64_gemm<1><<<dim3(4 * 4), blk, LDS1, stream>>>(
            ws + E2, WN(5), SBN(5), ws + E3, 64, 64, 64, 64, 1, 1, 4);
        conv64_gemm<1><<<dim3(4 * 4), blk, LDS1, stream>>>(
            ws + E3, WN(6), SBN(6), ws + E1, 64, 64, 64, 64, 1, 1, 4);
        // f4 up (fused tconv+blur+bias+lrelu): G2 -> T2s scratch; upconv(f3+f2) -> D1 (128^2)
        combine_up_w<<<dim3(576), blk, 0, stream>>>(WN(7), ws + T2s);
        upconv64_gemm<<<dim3(8 * 8), blk, LDSU, stream>>>(
            ws + E1, ws + E2, ws + T2s, SBN(7), ws + D1, 64, 64, 8);
        conv64_gemm<1><<<dim3(8 * 8), blk, LDS1, stream>>>(
            ws + D1, WN(8), SBN(8), ws + D3, 128, 128, 128, 128, 1, 1, 8);
        // f5 up: G2 -> D1 scratch (D1 free now); upconv(f4+f1) -> T2s (256^2)
        combine_up_w<<<dim3(576), blk, 0, stream>>>(WN(9), ws + D1);
        upconv64_gemm<<<dim3(16 * 16), blk, LDSU, stream>>>(
            ws + D3, ws + D2, ws + D1, SBN(9), ws + T2s, 128, 128, 16);
        conv64_gemm<1><<<dim3(16 * 16), blk, LDS1, stream>>>(
            ws + T2s, WN(10), SBN(10), ws + T1s, 256, 256, 256, 256, 1, 1, 16);
        // out = modconv(f5+f0, c6, no act)
        conv3x3_mod<<<dim3(3 * 16 * 16), blk, 2304, stream>>>(
            ws + T1s, ws + F0s, WN(11), SBN(11), outn, 64, 3, 256, 256, 256, 256, 1, 1, 0, 16, 16);
        #undef WN
        #undef SBN
    }
}

// Round 6
// 10332.281 us; speedup vs baseline: 3.5877x; 1.7668x over previous
//
#include <hip/hip_runtime.h>

#define LRELU(v) ((v) >= 0.f ? (v) : 0.2f * (v))

// ================= implicit-GEMM 3x3 conv, C=64 -> O=64, sample-batched =================
// in [64,Hin,Win] (+s*inStr); Wt [c][k][o] (+s*wStr); bias[64] (+s*bStr); out (+s*outStr)
// Block: 256 thr -> 16x16 output px x 64 och. Micro-tile: 8 och x 8 px per thread.
template<int S>
__global__ void conv64_gemm(const float* __restrict__ in, const float* __restrict__ Wt,
                            const float* __restrict__ bias, float* __restrict__ out,
                            int Hin, int Win, int Hout, int Wout, int pad, int act, int tilesX,
                            long long inStr, long long wStr, long long bStr, long long outStr)
{
    constexpr int CC  = (S == 1) ? 8 : 4;    // c-chunk
    constexpr int TIN = (S == 1) ? 18 : 33;  // staged input tile dim
    constexpr int RS  = (S == 1) ? 20 : 36;  // padded row stride
    constexpr int NF4 = (S == 1) ? 3 : 5;    // float4 row reads
    constexpr int PW  = NF4 * 4;
    extern __shared__ float lds[];
    float* it = lds;                         // [CC][TIN][RS]
    float* wl = lds + CC * TIN * RS;         // [CC*9*64]

    int s = blockIdx.y;
    in   += (size_t)s * inStr;
    Wt   += (size_t)s * wStr;
    bias += (size_t)s * bStr;
    out  += (size_t)s * outStr;

    int b  = blockIdx.x;
    int tx = b % tilesX, ty = b / tilesX;
    int t  = threadIdx.x;
    int og = t >> 5;
    int pg = t & 31;
    int r  = pg >> 1, ch = pg & 1;

    float acc[8][8];
    #pragma unroll
    for (int i = 0; i < 8; ++i)
        #pragma unroll
        for (int j = 0; j < 8; ++j) acc[i][j] = 0.f;

    const int y0 = ty * 16 * S - pad;
    const int x0 = tx * 16 * S - pad;
    const size_t plane = (size_t)Hin * Win;

    for (int c0 = 0; c0 < 64; c0 += CC) {
        __syncthreads();
        for (int i = t; i < CC * 9 * 64; i += 256) wl[i] = Wt[c0 * 9 * 64 + i];
        for (int i = t; i < CC * TIN * TIN; i += 256) {
            int cc  = i / (TIN * TIN);
            int rem = i - cc * (TIN * TIN);
            int rr  = rem / TIN, cl = rem - rr * TIN;
            int iy = y0 + rr, ix = x0 + cl;
            float v = 0.f;
            if ((unsigned)iy < (unsigned)Hin && (unsigned)ix < (unsigned)Win)
                v = in[(size_t)(c0 + cc) * plane + (size_t)iy * Win + ix];
            it[(cc * TIN + rr) * RS + cl] = v;
        }
        __syncthreads();
        for (int cc = 0; cc < CC; ++cc) {
            const float* base = it + cc * TIN * RS;
            #pragma unroll
            for (int ky = 0; ky < 3; ++ky) {
                float p[PW];
                const float* rowp = base + (r * S + ky) * RS + ch * 8 * S;
                #pragma unroll
                for (int q = 0; q < NF4; ++q) {
                    float4 f = *(const float4*)(rowp + q * 4);
                    p[q*4+0] = f.x; p[q*4+1] = f.y; p[q*4+2] = f.z; p[q*4+3] = f.w;
                }
                #pragma unroll
                for (int kx = 0; kx < 3; ++kx) {
                    const float* wp = wl + ((cc * 9) + ky * 3 + kx) * 64 + og * 8;
                    float4 wa = *(const float4*)wp;
                    float4 wb = *(const float4*)(wp + 4);
                    float w8[8] = {wa.x, wa.y, wa.z, wa.w, wb.x, wb.y, wb.z, wb.w};
                    #pragma unroll
                    for (int oi = 0; oi < 8; ++oi)
                        #pragma unroll
                        for (int j = 0; j < 8; ++j)
                            acc[oi][j] += w8[oi] * p[j * S + kx];
                }
            }
        }
    }

    int y  = ty * 16 + r;
    int xb = tx * 16 + ch * 8;
    #pragma unroll
    for (int oi = 0; oi < 8; ++oi) {
        int o = og * 8 + oi;
        float bo = bias[o];
        float v[8];
        #pragma unroll
        for (int j = 0; j < 8; ++j) {
            float a = acc[oi][j] + bo;
            v[j] = act ? LRELU(a) : a;
        }
        float* op = out + ((size_t)o * Hout + y) * Wout + xb;
        *(float4*)op       = make_float4(v[0], v[1], v[2], v[3]);
        *(float4*)(op + 4) = make_float4(v[4], v[5], v[6], v[7]);
    }
}

// ===== fused up-conv: tconv(s2,3x3)+blur(4x4,x4/64)+bias+lrelu, C=64 -> O=64, batched =====
__global__ void upconv64_gemm(const float* __restrict__ in, const float* __restrict__ in2,
                              const float* __restrict__ G2, const float* __restrict__ sb,
                              float* __restrict__ out, int Hin, int Win, int tilesX,
                              long long bufStr, long long sbStr, long long outStr)
{
    constexpr int CC = 4;
    constexpr int RS = 12;
    extern __shared__ float lds[];
    float* it = lds;                          // [CC][10][RS]
    float* wl = lds + CC * 10 * RS;           // [CC*2304]

    int s = blockIdx.y;
    in  += (size_t)s * bufStr;
    in2 += (size_t)s * bufStr;
    G2  += (size_t)s * bufStr;
    sb  += (size_t)s * sbStr;
    out += (size_t)s * outStr;

    int b  = blockIdx.x;
    int tx = b % tilesX, ty = b / tilesX;
    int t  = threadIdx.x;
    int og = t & 7;
    int q  = t >> 3;
    int rhalf = q & 7;
    int pxb   = (q >> 3) & 1;
    int rpar  = q >> 4;
    int r = 2 * rhalf + rpar;
    const int Y0 = ty * 16, X0 = tx * 16;
    const int gy0 = Y0 / 2 - 1;
    const int gx0 = X0 / 2 - 1;
    const size_t plane = (size_t)Hin * Win;

    float acc[8][8];
    #pragma unroll
    for (int i = 0; i < 8; ++i)
        #pragma unroll
        for (int j = 0; j < 8; ++j) acc[i][j] = 0.f;

    for (int c0 = 0; c0 < 64; c0 += CC) {
        __syncthreads();
        {
            const float4* src = (const float4*)(G2 + (size_t)c0 * 2304);
            float4* dst = (float4*)wl;
            for (int i = t; i < CC * 2304 / 4; i += 256) dst[i] = src[i];
        }
        for (int i = t; i < CC * 10 * RS; i += 256) {
            int cc  = i / (10 * RS);
            int rem = i - cc * (10 * RS);
            int rr  = rem / RS, cl = rem - rr * RS;
            int gi = gy0 + rr, gj = gx0 + cl;
            float v = 0.f;
            if (cl < 10 && (unsigned)gi < (unsigned)Hin && (unsigned)gj < (unsigned)Win) {
                size_t off = (size_t)(c0 + cc) * plane + (size_t)gi * Win + gj;
                v = in[off] + in2[off];
            }
            it[i] = v;
        }
        __syncthreads();
        for (int cc = 0; cc < CC; ++cc) {
            const float* ib = it + cc * 10 * RS;
            const float* wb = wl + cc * 2304 + (rpar * 2 + pxb) * 576;
            #pragma unroll
            for (int ty2 = 0; ty2 < 3; ++ty2) {
                float p[12];
                const float* rowp = ib + (rhalf + ty2) * RS;
                #pragma unroll
                for (int qq = 0; qq < 3; ++qq) {
                    float4 f = *(const float4*)(rowp + qq * 4);
                    p[qq*4+0] = f.x; p[qq*4+1] = f.y; p[qq*4+2] = f.z; p[qq*4+3] = f.w;
                }
                #pragma unroll
                for (int tx2 = 0; tx2 < 3; ++tx2) {
                    const float* wp = wb + (ty2 * 3 + tx2) * 64 + og * 8;
                    float4 wa = *(const float4*)wp;
                    float4 wv = *(const float4*)(wp + 4);
                    float w8[8] = {wa.x, wa.y, wa.z, wa.w, wv.x, wv.y, wv.z, wv.w};
                    #pragma unroll
                    for (int oi = 0; oi < 8; ++oi)
                        #pragma unroll
                        for (int k = 0; k < 8; ++k)
                            acc[oi][k] += w8[oi] * p[k + tx2];
                }
            }
        }
    }

    const int Hout = 2 * Hin, Wout = 2 * Win;
    int y = Y0 + r;
    #pragma unroll
    for (int oi = 0; oi < 8; ++oi) {
        int o = og * 8 + oi;
        float bo = sb[o];
        float* op = out + ((size_t)o * Hout + y) * Wout;
        #pragma unroll
        for (int k = 0; k < 8; ++k) {
            float a = acc[oi][k] + bo;
            op[X0 + 2 * k + pxb] = LRELU(a);
        }
    }
}

// ------- build combined up-weights, batched: G2[c][py][px][ty][tx][o] from W [o][c][3][3] -------
__global__ void combine_up_w(const float* __restrict__ W, float* __restrict__ G2,
                             long long wStr, long long g2Str)
{
    int s = blockIdx.y;
    W  += (size_t)s * wStr;
    G2 += (size_t)s * g2Str;
    int i = blockIdx.x * 256 + threadIdx.x;
    if (i >= 147456) return;
    int o = i & 63;
    int rest = i >> 6;
    int m = rest % 36, c = rest / 36;
    int txk = m % 3, tyk = (m / 3) % 3;
    int px = (m / 9) & 1, py = m / 18;
    int dy = 2 * tyk - 1 - py, dx = 2 * txk - 1 - px;
    const float K[4] = {1.f, 3.f, 3.f, 1.f};
    const float* wp = W + ((size_t)o * 64 + c) * 9;
    float sacc = 0.f;
    #pragma unroll
    for (int a = 0; a < 3; ++a) {
        int ky = a + dy;
        if ((unsigned)ky >= 4u) continue;
        #pragma unroll
        for (int b2 = 0; b2 < 3; ++b2) {
            int kx = b2 + dx;
            if ((unsigned)kx >= 4u) continue;
            sacc += K[ky] * K[kx] * wp[a * 3 + b2];
        }
    }
    G2[i] = sacc * (1.f / 16.f);
}

// ---------------- direct 3x3 conv, shared weights (guide g0), batched, o-innermost ----------------
__global__ void conv3x3_guide(const float* __restrict__ in, const float* __restrict__ w,
                              const float* __restrict__ b, float* __restrict__ out,
                              int C, int O, int Hin, int Win, int Hout, int Wout,
                              int stride, int act, int tilesX,
                              long long inStr, long long outStr)
{
    int s = blockIdx.y;
    in  += (size_t)s * inStr;
    out += (size_t)s * outStr;
    int bid = blockIdx.x;
    int o  = bid % O; bid /= O;
    int tx = bid % tilesX;
    int ty = bid / tilesX;
    extern __shared__ float wls[];
    int nw = C * 9;
    for (int i = threadIdx.x; i < nw; i += blockDim.x) wls[i] = w[o * nw + i];
    __syncthreads();
    int x = tx * 16 + (threadIdx.x & 15);
    int y = ty * 16 + (threadIdx.x >> 4);
    if (x >= Wout || y >= Hout) return;
    float acc = b[o];
    size_t plane = (size_t)Hin * Win;
    int iy0 = y * stride - 1, ix0 = x * stride - 1;
    for (int c = 0; c < C; ++c) {
        const float* ip = in + c * plane;
        const float* wc = wls + c * 9;
        #pragma unroll
        for (int ky = 0; ky < 3; ++ky) {
            int iy = iy0 + ky;
            if ((unsigned)iy >= (unsigned)Hin) continue;
            #pragma unroll
            for (int kx = 0; kx < 3; ++kx) {
                int ix = ix0 + kx;
                if ((unsigned)ix >= (unsigned)Win) continue;
                acc += ip[(size_t)iy * Win + ix] * wc[ky * 3 + kx];
            }
        }
    }
    if (act) acc = LRELU(acc);
    out[((size_t)o * Hout + y) * Wout + x] = acc;
}

// ---------------- direct 3x3 conv, per-sample weights [o][c][k] (f0, c6), batched ----------------
__global__ void conv3x3_mod(const float* __restrict__ in, const float* __restrict__ in2,
                            const float* __restrict__ W, const float* __restrict__ sb,
                            float* __restrict__ out,
                            int C, int O, int Hin, int Win, int Hout, int Wout,
                            int stride, int pad, int act, int tilesX,
                            long long inStr, long long in2Str, long long wStr,
                            long long sbStr, long long outStr)
{
    int s = blockIdx.y;
    in  += (size_t)s * inStr;
    if (in2) in2 += (size_t)s * in2Str;
    W   += (size_t)s * wStr;
    sb  += (size_t)s * sbStr;
    out += (size_t)s * outStr;
    int bid = blockIdx.x;
    int o  = bid % O; bid /= O;
    int tx = bid % tilesX;
    int ty = bid / tilesX;
    extern __shared__ float wls[];
    int nw = C * 9;
    const float* wp = W + (size_t)o * nw;
    for (int i = threadIdx.x; i < nw; i += blockDim.x) wls[i] = wp[i];
    __syncthreads();
    int x = tx * 16 + (threadIdx.x & 15);
    int y = ty * 16 + (threadIdx.x >> 4);
    if (x >= Wout || y >= Hout) return;
    float acc = sb[o];
    size_t plane = (size_t)Hin * Win;
    int iy0 = y * stride - pad, ix0 = x * stride - pad;
    for (int c = 0; c < C; ++c) {
        const float* ip  = in + c * plane;
        const float* ip2 = in2 ? in2 + c * plane : nullptr;
        const float* wc  = wls + c * 9;
        #pragma unroll
        for (int ky = 0; ky < 3; ++ky) {
            int iy = iy0 + ky;
            if ((unsigned)iy >= (unsigned)Hin) continue;
            #pragma unroll
            for (int kx = 0; kx < 3; ++kx) {
                int ix = ix0 + kx;
                if ((unsigned)ix >= (unsigned)Win) continue;
                float xv = ip[(size_t)iy * Win + ix];
                if (ip2) xv += ip2[(size_t)iy * Win + ix];
                acc += xv * wc[ky * 3 + kx];
            }
        }
    }
    if (act) acc = LRELU(acc);
    out[((size_t)o * Hout + y) * Wout + x] = acc;
}

// ---------------- 4x4 blur pad=2 (pre-down), batched: out [64, H+1, W+1], /64 ----------------
__global__ void blur_down(const float* __restrict__ in, float* __restrict__ out,
                          int H, int W, int tilesX, int tilesY,
                          long long inStr, long long outStr)
{
    int s = blockIdx.y;
    in  += (size_t)s * inStr;
    out += (size_t)s * outStr;
    int Ho = H + 1, Wo = W + 1;
    int bid = blockIdx.x;
    int tx = bid % tilesX; bid /= tilesX;
    int ty = bid % tilesY; bid /= tilesY;
    int p  = bid;
    int x = tx * 16 + (threadIdx.x & 15);
    int y = ty * 16 + (threadIdx.x >> 4);
    if (x >= Wo || y >= Ho) return;
    const float k[4] = {1.f, 3.f, 3.f, 1.f};
    const float* ip = in + (size_t)p * H * W;
    float acc = 0.f;
    #pragma unroll
    for (int ky = 0; ky < 4; ++ky) {
        int iy = y - 2 + ky;
        if ((unsigned)iy >= (unsigned)H) continue;
        float row = 0.f;
        #pragma unroll
        for (int kx = 0; kx < 4; ++kx) {
            int ix = x - 2 + kx;
            if ((unsigned)ix >= (unsigned)W) continue;
            row += ip[(size_t)iy * W + ix] * k[kx];
        }
        acc += row * k[ky];
    }
    out[((size_t)p * Ho + y) * Wo + x] = acc * (1.f / 64.f);
}

// ---------------- avg pool to 1x1 (64 planes), batched ----------------
__global__ void avgpool_hw(const float* __restrict__ in, float* __restrict__ out, int HW,
                           long long inStr, long long outStr)
{
    int s = blockIdx.y;
    in  += (size_t)s * inStr;
    out += (size_t)s * outStr;
    int p = blockIdx.x;
    const float* ip = in + (size_t)p * HW;
    float sum = 0.f;
    for (int i = threadIdx.x; i < HW; i += blockDim.x) sum += ip[i];
    __shared__ float red[256];
    red[threadIdx.x] = sum;
    __syncthreads();
    for (int off = 128; off; off >>= 1) {
        if ((int)threadIdx.x < off) red[threadIdx.x] += red[threadIdx.x + off];
        __syncthreads();
    }
    if (threadIdx.x == 0) out[p] = red[0] / (float)HW;
}

// ---------------- style FC (all 8 samples) ----------------
__global__ void style_fc(const float* __restrict__ s, const float* __restrict__ W,
                         const float* __restrict__ b, float* __restrict__ out, int outdim)
{
    int n = blockIdx.x;
    int i = threadIdx.x;
    if (i >= outdim) return;
    float acc = b[i];
    const float* sn = s + n * 64;
    const float* wi = W + i * 64;
    for (int f = 0; f < 64; ++f) acc += sn[f] * wi[f];
    out[n * 64 + i] = LRELU(acc);
}

// ------- modulate+demodulate (all 8 samples); transpose=1 -> [c][k][o] -------
__global__ void modulate(const float* __restrict__ w, const float* __restrict__ sw,
                         float* __restrict__ wout, int O, int C, int transpose)
{
    int no = blockIdx.x;
    int o = no % O, n = no / O;
    int nw = C * 9;
    int t = threadIdx.x;
    float v[9];
    int cnt = 0;
    float ss = 0.f;
    for (int idx = t; idx < nw; idx += 64) {
        int c = idx / 9;
        float val = w[o * nw + idx] * sw[n * 64 + c];
        v[cnt++] = val;
        ss += val * val;
    }
    #pragma unroll
    for (int off = 32; off; off >>= 1) ss += __shfl_xor(ss, off);
    float d = rsqrtf(ss + 1e-8f);
    cnt = 0;
    for (int idx = t; idx < nw; idx += 64) {
        float val = v[cnt++] * d;
        if (transpose)
            wout[(size_t)n * nw * O + (size_t)idx * O + o] = val;
        else
            wout[(size_t)no * nw + idx] = val;
    }
}

// ------- guide weight transpose: gt[l][(c*9+k)*64+o] = grw[((l*64+o)*64+c)*9+k] -------
__global__ void guide_transpose(const float* __restrict__ grw, float* __restrict__ gt, int total)
{
    int i = blockIdx.x * 256 + threadIdx.x;
    if (i >= total) return;
    int l = i / 36864, rem = i % 36864;
    int idx = rem / 64, o = rem % 64;
    int c = idx / 9, k = idx % 9;
    gt[i] = grw[(((size_t)l * 64 + o) * 64 + c) * 9 + k];
}

__global__ void fill_sentinel(float* __restrict__ out, int n)
{
    int i = blockIdx.x * 256 + threadIdx.x;
    if (i < n) out[i] = 1.0e9f;
}

extern "C" void kernel_launch(void* const* d_in, const int* in_sizes, int n_in,
                              void* d_out, int out_size, void* d_ws, size_t ws_size,
                              hipStream_t stream)
{
    const float* x     = (const float*)d_in[0];
    const float* ref   = (const float*)d_in[1];
    const float* g0w   = (const float*)d_in[2];
    const float* g0b   = (const float*)d_in[3];
    const float* grw   = (const float*)d_in[4];
    const float* grb   = (const float*)d_in[5];
    const float* c0w   = (const float*)d_in[6];
    const float* c0swW = (const float*)d_in[7];
    const float* c0swb = (const float*)d_in[8];
    const float* c0sbW = (const float*)d_in[9];
    const float* c0sbb = (const float*)d_in[10];
    const float* midw  = (const float*)d_in[11];
    const float* midswW= (const float*)d_in[12];
    const float* midswb= (const float*)d_in[13];
    const float* midsbW= (const float*)d_in[14];
    const float* midsbb= (const float*)d_in[15];
    const float* c6w   = (const float*)d_in[16];
    const float* c6swW = (const float*)d_in[17];
    const float* c6swb = (const float*)d_in[18];
    const float* c6sbW = (const float*)d_in[19];
    const float* c6sbb = (const float*)d_in[20];
    float* out = (float*)d_out;
    float* ws  = (float*)d_ws;

    // -------- shared region (floats) --------
    const size_t SV  = 0;                 // s [8,64]
    const size_t STY = 512;               // 12 x (sw 512 + sb 512)
    const size_t WM  = 12800;             // modulated weights (all 8 samples)
    const size_t GT  = 2989568;           // transposed guide weights [4][576][64]
    const size_t BUF = 3137024;           // start of per-sample slots

    // -------- per-sample slot offsets (floats, relative to slot base) --------
    const size_t F0 = 0;                  // [64,256,256]
    const size_t SA = 4194304;            // [64,257,257]-class (blur f0 / f5up out)
    const size_t SB = 8421440;            // [64,256,256] (f5 final)
    const size_t D1 = 12615744;           // [64,128,128]
    const size_t D2 = 13664320;           // [64,128,128]
    const size_t D3 = 14712896;           // [64,129,129]-class
    const size_t E1 = 15777920;           // [64,64,64]
    const size_t E2 = 16040064;
    const size_t E3 = 16302208;
    const size_t G2o = 16564352;          // combined up-weights [147456]
    const long long PER = 16711808ll;     // floats per sample

    // adaptive group size: largest G in {8,4,2,1} whose layout fits
    int G = 0;
    const int cand[4] = {8, 4, 2, 1};
    for (int ci = 0; ci < 4; ++ci) {
        size_t need = (BUF + (size_t)cand[ci] * PER) * sizeof(float);
        if (ws_size >= need) { G = cand[ci]; break; }
    }
    if (!G) {
        fill_sentinel<<<dim3((out_size + 255) / 256), dim3(256), 0, stream>>>(out, out_size);
        return;
    }
    const int nGroups = 8 / G;

    dim3 blk(256);
    const int LDS1 = 29952;   // conv64_gemm<1>
    const int LDS2 = 28224;   // conv64_gemm<2>
    const int LDSU = 38784;   // upconv64_gemm

    float* B = ws + BUF;      // per-sample slot base

    // guide weights -> [c][k][o]
    guide_transpose<<<dim3(147456 / 256), blk, 0, stream>>>(grw, ws + GT, 147456);

    // ==================== guide net (grouped, batched) -> s ====================
    for (int gi = 0; gi < nGroups; ++gi) {
        int n0 = gi * G;
        const float* refg = ref + (size_t)n0 * 196608;
        conv3x3_guide<<<dim3(64 * 16 * 16, G), blk, 27 * 4, stream>>>(
            refg, g0w, g0b, B + SA, 3, 64, 256, 256, 256, 256, 1, 1, 16, 196608, PER);
        conv64_gemm<2><<<dim3(8 * 8, G), blk, LDS2, stream>>>(
            B + SA, ws + GT, grb, B + D1, 256, 256, 128, 128, 1, 1, 8, PER, 0, 0, PER);
        conv64_gemm<1><<<dim3(8 * 8, G), blk, LDS1, stream>>>(
            B + D1, ws + GT + 36864, grb + 64, B + D2, 128, 128, 128, 128, 1, 1, 8, PER, 0, 0, PER);
        conv64_gemm<2><<<dim3(4 * 4, G), blk, LDS2, stream>>>(
            B + D2, ws + GT + 73728, grb + 128, B + E1, 128, 128, 64, 64, 1, 1, 4, PER, 0, 0, PER);
        conv64_gemm<1><<<dim3(4 * 4, G), blk, LDS1, stream>>>(
            B + E1, ws + GT + 110592, grb + 192, B + E2, 64, 64, 64, 64, 1, 0, 4, PER, 0, 0, PER);
        avgpool_hw<<<dim3(64, G), blk, 0, stream>>>(B + E2, ws + SV + (size_t)n0 * 64, 4096, PER, 64);
    }

    // ==================== styles + modulated weights (all 8 samples) ====================
    const float* Wt[12];  const float* swWp[12]; const float* swbp[12];
    const float* sbWp[12]; const float* sbbp[12];
    int Ci[12], Oi[12];
    size_t wmo[12];
    Wt[0] = c0w; swWp[0] = c0swW; swbp[0] = c0swb; sbWp[0] = c0sbW; sbbp[0] = c0sbb;
    Ci[0] = 3; Oi[0] = 64; wmo[0] = WM;
    for (int i = 0; i < 10; ++i) {
        Wt[1 + i]   = midw   + (size_t)i * 36864;
        swWp[1 + i] = midswW + (size_t)i * 4096;
        swbp[1 + i] = midswb + (size_t)i * 64;
        sbWp[1 + i] = midsbW + (size_t)i * 4096;
        sbbp[1 + i] = midsbb + (size_t)i * 64;
        Ci[1 + i] = 64; Oi[1 + i] = 64;
        wmo[1 + i] = WM + 13824ull + (size_t)i * 294912ull;
    }
    Wt[11] = c6w; swWp[11] = c6swW; swbp[11] = c6swb; sbWp[11] = c6sbW; sbbp[11] = c6sbb;
    Ci[11] = 64; Oi[11] = 3; wmo[11] = WM + 13824ull + 2949120ull;

    // transpose flags per CONSUMER: conv64_gemm -> 1; conv3x3_mod / combine_up_w -> 0
    const int trf[12] = {0, 1, 1, 1, 1, 1, 1, 0, 1, 0, 1, 0};

    for (int i = 0; i < 12; ++i) {
        style_fc<<<dim3(8), dim3(64), 0, stream>>>(ws + SV, swWp[i], swbp[i], ws + STY + i * 1024, Ci[i]);
        style_fc<<<dim3(8), dim3(64), 0, stream>>>(ws + SV, sbWp[i], sbbp[i], ws + STY + i * 1024 + 512, Oi[i]);
        modulate<<<dim3(8 * Oi[i]), dim3(64), 0, stream>>>(Wt[i], ws + STY + i * 1024, ws + wmo[i], Oi[i], Ci[i], trf[i]);
    }

    // ==================== main path (grouped, batched) ====================
    for (int gi = 0; gi < nGroups; ++gi) {
        int n0 = gi * G;
        const float* xg = x + (size_t)n0 * 196608;
        float* outg = out + (size_t)n0 * 196608;
        #define WN(i)  (ws + wmo[i] + (size_t)n0 * Oi[i] * Ci[i] * 9)
        #define WSTR(i) ((long long)(Oi[i] * Ci[i] * 9))
        #define SBN(i) (ws + STY + (i) * 1024 + 512 + (size_t)n0 * 64)
        // f0 = modconv(x, c0)
        conv3x3_mod<<<dim3(64 * 16 * 16, G), blk, 27 * 4, stream>>>(
            xg, nullptr, WN(0), SBN(0), B + F0, 3, 64, 256, 256, 256, 256, 1, 1, 1, 16,
            196608, 0, WSTR(0), 64, PER);
        // f1 down
        blur_down<<<dim3(64 * 17 * 17, G), blk, 0, stream>>>(B + F0, B + SA, 256, 256, 17, 17, PER, PER);
        conv64_gemm<2><<<dim3(8 * 8, G), blk, LDS2, stream>>>(
            B + SA, WN(1), SBN(1), B + D1, 257, 257, 128, 128, 0, 1, 8, PER, WSTR(1), 64, PER);
        conv64_gemm<1><<<dim3(8 * 8, G), blk, LDS1, stream>>>(
            B + D1, WN(2), SBN(2), B + D2, 128, 128, 128, 128, 1, 1, 8, PER, WSTR(2), 64, PER);
        // f2 down
        blur_down<<<dim3(64 * 9 * 9, G), blk, 0, stream>>>(B + D2, B + D3, 128, 128, 9, 9, PER, PER);
        conv64_gemm<2><<<dim3(4 * 4, G), blk, LDS2, stream>>>(
            B + D3, WN(3), SBN(3), B + E1, 129, 129, 64, 64, 0, 1, 4, PER, WSTR(3), 64, PER);
        conv64_gemm<1><<<dim3(4 * 4, G), blk, LDS1, stream>>>(
            B + E1, WN(4), SBN(4), B + E2, 64, 64, 64, 64, 1, 1, 4, PER, WSTR(4), 64, PER);
        // f3 x2
        conv64_gemm<1><<<dim3(4 * 4, G), blk, LDS1, stream>>>(
            B + E2, WN(5), SBN(5), B + E3, 64, 64, 64, 64, 1, 1, 4, PER, WSTR(5), 64, PER);
        conv64_gemm<1><<<dim3(4 * 4, G), blk, LDS1, stream>>>(
            B + E3, WN(6), SBN(6), B + E1, 64, 64, 64, 64, 1, 1, 4, PER, WSTR(6), 64, PER);
        // f4 up (fused): combine -> G2 slot; upconv(f3+f2) -> D1 (128^2); conv -> D3
        combine_up_w<<<dim3(576, G), blk, 0, stream>>>(WN(7), B + G2o, WSTR(7), PER);
        upconv64_gemm<<<dim3(8 * 8, G), blk, LDSU, stream>>>(
            B + E1, B + E2, B + G2o, SBN(7), B + D1, 64, 64, 8, PER, 64, PER);
        conv64_gemm<1><<<dim3(8 * 8, G), blk, LDS1, stream>>>(
            B + D1, WN(8), SBN(8), B + D3, 128, 128, 128, 128, 1, 1, 8, PER, WSTR(8), 64, PER);
        // f5 up: combine -> G2 slot; upconv(f4+f1) -> SA (256^2); conv -> SB
        combine_up_w<<<dim3(576, G), blk, 0, stream>>>(WN(9), B + G2o, WSTR(9), PER);
        upconv64_gemm<<<dim3(16 * 16, G), blk, LDSU, stream>>>(
            B + D3, B + D2, B + G2o, SBN(9), B + SA, 128, 128, 16, PER, 64, PER);
        conv64_gemm<1><<<dim3(16 * 16, G), blk, LDS1, stream>>>(
            B + SA, WN(10), SBN(10), B + SB, 256, 256, 256, 256, 1, 1, 16, PER, WSTR(10), 64, PER);
        // out = modconv(f5+f0, c6, no act)
        conv3x3_mod<<<dim3(3 * 16 * 16, G), blk, 2304, stream>>>(
            B + SB, B + F0, WN(11), SBN(11), outg, 64, 3, 256, 256, 256, 256, 1, 1, 0, 16,
            PER, PER, WSTR(11), 64, 196608);
        #undef WN
        #undef WSTR
        #undef SBN
    }
}

// Round 7
// 7185.802 us; speedup vs baseline: 5.1587x; 1.4379x over previous
//
#include <hip/hip_runtime.h>

#define LRELU(v) ((v) >= 0.f ? (v) : 0.2f * (v))

// ================= implicit-GEMM 3x3 conv, C=64 -> O=64, sample-batched =================
// in [64,Hin,Win] (+s*inStr); Wt [c][k][o] (+s*wStr); bias[64] (+s*bStr); out (+s*outStr)
// Block: 256 thr -> 16x16 output px x 64 och. Micro-tile: 8 och x 8 px per thread.
template<int S>
__global__ void conv64_gemm(const float* __restrict__ in, const float* __restrict__ Wt,
                            const float* __restrict__ bias, float* __restrict__ out,
                            int Hin, int Win, int Hout, int Wout, int pad, int act, int tilesX,
                            long long inStr, long long wStr, long long bStr, long long outStr)
{
    constexpr int CC  = (S == 1) ? 8 : 4;    // c-chunk
    constexpr int TIN = (S == 1) ? 18 : 33;  // staged input tile dim
    constexpr int RS  = (S == 1) ? 20 : 36;  // padded row stride (multiple of 4)
    constexpr int NF4 = (S == 1) ? 3 : 5;    // float4 row reads (inner loop)
    constexpr int PW  = NF4 * 4;
    extern __shared__ float lds[];
    float* it = lds;                         // [CC][TIN][RS]
    float* wl = lds + CC * TIN * RS;         // [CC*9*64]

    int s = blockIdx.y;
    in   += (size_t)s * inStr;
    Wt   += (size_t)s * wStr;
    bias += (size_t)s * bStr;
    out  += (size_t)s * outStr;

    int b  = blockIdx.x;
    int tx = b % tilesX, ty = b / tilesX;
    int t  = threadIdx.x;
    int og = t >> 5;
    int pg = t & 31;
    int r  = pg >> 1, ch = pg & 1;

    float acc[8][8];
    #pragma unroll
    for (int i = 0; i < 8; ++i)
        #pragma unroll
        for (int j = 0; j < 8; ++j) acc[i][j] = 0.f;

    const int y0 = ty * 16 * S - pad;
    const int x0 = tx * 16 * S - pad;
    const size_t plane = (size_t)Hin * Win;

    for (int c0 = 0; c0 < 64; c0 += CC) {
        __syncthreads();
        // ---- weights: float4 copy ----
        {
            const float4* src = (const float4*)(Wt + c0 * 9 * 64);
            float4* dst = (float4*)wl;
            for (int i = t; i < CC * 9 * 16; i += 256) dst[i] = src[i];
        }
        // ---- input rows: one thread per row, float4 fast path ----
        for (int rowi = t; rowi < CC * TIN; rowi += 256) {
            int cc = rowi / TIN, rr = rowi - cc * TIN;
            int iy = y0 + rr;
            float* dst = it + (size_t)rowi * RS;
            const float* srow = in + (size_t)(c0 + cc) * plane + (size_t)iy * Win + x0;
            if ((unsigned)iy < (unsigned)Hin && x0 >= 0 && x0 + RS <= Win) {
                #pragma unroll
                for (int q = 0; q < RS / 4; ++q)
                    ((float4*)dst)[q] = ((const float4*)srow)[q];
            } else {
                for (int cl = 0; cl < TIN; ++cl) {
                    int ix = x0 + cl;
                    float v = 0.f;
                    if ((unsigned)iy < (unsigned)Hin && (unsigned)ix < (unsigned)Win)
                        v = in[(size_t)(c0 + cc) * plane + (size_t)iy * Win + ix];
                    dst[cl] = v;
                }
            }
        }
        __syncthreads();
        for (int cc = 0; cc < CC; ++cc) {
            const float* base = it + cc * TIN * RS;
            #pragma unroll
            for (int ky = 0; ky < 3; ++ky) {
                float p[PW];
                const float* rowp = base + (r * S + ky) * RS + ch * 8 * S;
                #pragma unroll
                for (int q = 0; q < NF4; ++q) {
                    float4 f = *(const float4*)(rowp + q * 4);
                    p[q*4+0] = f.x; p[q*4+1] = f.y; p[q*4+2] = f.z; p[q*4+3] = f.w;
                }
                #pragma unroll
                for (int kx = 0; kx < 3; ++kx) {
                    const float* wp = wl + ((cc * 9) + ky * 3 + kx) * 64 + og * 8;
                    float4 wa = *(const float4*)wp;
                    float4 wb = *(const float4*)(wp + 4);
                    float w8[8] = {wa.x, wa.y, wa.z, wa.w, wb.x, wb.y, wb.z, wb.w};
                    #pragma unroll
                    for (int oi = 0; oi < 8; ++oi)
                        #pragma unroll
                        for (int j = 0; j < 8; ++j)
                            acc[oi][j] += w8[oi] * p[j * S + kx];
                }
            }
        }
    }

    int y  = ty * 16 + r;
    int xb = tx * 16 + ch * 8;
    #pragma unroll
    for (int oi = 0; oi < 8; ++oi) {
        int o = og * 8 + oi;
        float bo = bias[o];
        float v[8];
        #pragma unroll
        for (int j = 0; j < 8; ++j) {
            float a = acc[oi][j] + bo;
            v[j] = act ? LRELU(a) : a;
        }
        float* op = out + ((size_t)o * Hout + y) * Wout + xb;
        *(float4*)op       = make_float4(v[0], v[1], v[2], v[3]);
        *(float4*)(op + 4) = make_float4(v[4], v[5], v[6], v[7]);
    }
}

// ===== fused up-conv: tconv(s2,3x3)+blur(4x4,x4/64)+bias+lrelu, C=64 -> O=64, batched =====
__global__ void upconv64_gemm(const float* __restrict__ in, const float* __restrict__ in2,
                              const float* __restrict__ G2, const float* __restrict__ sb,
                              float* __restrict__ out, int Hin, int Win, int tilesX,
                              long long bufStr, long long sbStr, long long outStr)
{
    constexpr int CC = 4;
    constexpr int RS = 12;
    extern __shared__ float lds[];
    float* it = lds;                          // [CC][10][RS]
    float* wl = lds + CC * 10 * RS;           // [CC*2304]

    int s = blockIdx.y;
    in  += (size_t)s * bufStr;
    in2 += (size_t)s * bufStr;
    G2  += (size_t)s * bufStr;
    sb  += (size_t)s * sbStr;
    out += (size_t)s * outStr;

    int b  = blockIdx.x;
    int tx = b % tilesX, ty = b / tilesX;
    int t  = threadIdx.x;
    int og = t & 7;
    int q  = t >> 3;
    int rhalf = q & 7;
    int pxb   = (q >> 3) & 1;
    int rpar  = q >> 4;
    int r = 2 * rhalf + rpar;
    const int Y0 = ty * 16, X0 = tx * 16;
    const int gy0 = Y0 / 2 - 1;
    const int gx0 = X0 / 2 - 1;
    const size_t plane = (size_t)Hin * Win;

    float acc[8][8];
    #pragma unroll
    for (int i = 0; i < 8; ++i)
        #pragma unroll
        for (int j = 0; j < 8; ++j) acc[i][j] = 0.f;

    for (int c0 = 0; c0 < 64; c0 += CC) {
        __syncthreads();
        {
            const float4* src = (const float4*)(G2 + (size_t)c0 * 2304);
            float4* dst = (float4*)wl;
            for (int i = t; i < CC * 2304 / 4; i += 256) dst[i] = src[i];
        }
        for (int rowi = t; rowi < CC * 10; rowi += 256) {
            int cc = rowi / 10, rr = rowi - cc * 10;
            int gi = gy0 + rr;
            float* dst = it + (size_t)rowi * RS;
            size_t roff = (size_t)(c0 + cc) * plane + (size_t)gi * Win + gx0;
            if ((unsigned)gi < (unsigned)Hin && gx0 >= 0 && gx0 + RS <= Win) {
                #pragma unroll
                for (int qq = 0; qq < 3; ++qq) {
                    float4 a = ((const float4*)(in  + roff))[qq];
                    float4 bb = ((const float4*)(in2 + roff))[qq];
                    ((float4*)dst)[qq] = make_float4(a.x + bb.x, a.y + bb.y, a.z + bb.z, a.w + bb.w);
                }
            } else {
                for (int cl = 0; cl < RS; ++cl) {
                    int gj = gx0 + cl;
                    float v = 0.f;
                    if (cl < 10 && (unsigned)gi < (unsigned)Hin && (unsigned)gj < (unsigned)Win) {
                        size_t off = (size_t)(c0 + cc) * plane + (size_t)gi * Win + gj;
                        v = in[off] + in2[off];
                    }
                    dst[cl] = v;
                }
            }
        }
        __syncthreads();
        for (int cc = 0; cc < CC; ++cc) {
            const float* ib = it + cc * 10 * RS;
            const float* wb = wl + cc * 2304 + (rpar * 2 + pxb) * 576;
            #pragma unroll
            for (int ty2 = 0; ty2 < 3; ++ty2) {
                float p[12];
                const float* rowp = ib + (rhalf + ty2) * RS;
                #pragma unroll
                for (int qq = 0; qq < 3; ++qq) {
                    float4 f = *(const float4*)(rowp + qq * 4);
                    p[qq*4+0] = f.x; p[qq*4+1] = f.y; p[qq*4+2] = f.z; p[qq*4+3] = f.w;
                }
                #pragma unroll
                for (int tx2 = 0; tx2 < 3; ++tx2) {
                    const float* wp = wb + (ty2 * 3 + tx2) * 64 + og * 8;
                    float4 wa = *(const float4*)wp;
                    float4 wv = *(const float4*)(wp + 4);
                    float w8[8] = {wa.x, wa.y, wa.z, wa.w, wv.x, wv.y, wv.z, wv.w};
                    #pragma unroll
                    for (int oi = 0; oi < 8; ++oi)
                        #pragma unroll
                        for (int k = 0; k < 8; ++k)
                            acc[oi][k] += w8[oi] * p[k + tx2];
                }
            }
        }
    }

    const int Hout = 2 * Hin, Wout = 2 * Win;
    int y = Y0 + r;
    #pragma unroll
    for (int oi = 0; oi < 8; ++oi) {
        int o = og * 8 + oi;
        float bo = sb[o];
        float* op = out + ((size_t)o * Hout + y) * Wout;
        #pragma unroll
        for (int k = 0; k < 8; ++k) {
            float a = acc[oi][k] + bo;
            op[X0 + 2 * k + pxb] = LRELU(a);
        }
    }
}

// ------- build combined up-weights, batched: G2[c][py][px][ty][tx][o] from W [o][c][3][3] -------
__global__ void combine_up_w(const float* __restrict__ W, float* __restrict__ G2,
                             long long wStr, long long g2Str)
{
    int s = blockIdx.y;
    W  += (size_t)s * wStr;
    G2 += (size_t)s * g2Str;
    int i = blockIdx.x * 256 + threadIdx.x;
    if (i >= 147456) return;
    int o = i & 63;
    int rest = i >> 6;
    int m = rest % 36, c = rest / 36;
    int txk = m % 3, tyk = (m / 3) % 3;
    int px = (m / 9) & 1, py = m / 18;
    int dy = 2 * tyk - 1 - py, dx = 2 * txk - 1 - px;
    const float K[4] = {1.f, 3.f, 3.f, 1.f};
    const float* wp = W + ((size_t)o * 64 + c) * 9;
    float sacc = 0.f;
    #pragma unroll
    for (int a = 0; a < 3; ++a) {
        int ky = a + dy;
        if ((unsigned)ky >= 4u) continue;
        #pragma unroll
        for (int b2 = 0; b2 < 3; ++b2) {
            int kx = b2 + dx;
            if ((unsigned)kx >= 4u) continue;
            sacc += K[ky] * K[kx] * wp[a * 3 + b2];
        }
    }
    G2[i] = sacc * (1.f / 16.f);
}

// ---------------- direct 3x3 conv, shared weights (guide g0), batched, o-innermost ----------------
__global__ void conv3x3_guide(const float* __restrict__ in, const float* __restrict__ w,
                              const float* __restrict__ b, float* __restrict__ out,
                              int C, int O, int Hin, int Win, int Hout, int Wout,
                              int stride, int act, int tilesX,
                              long long inStr, long long outStr)
{
    int s = blockIdx.y;
    in  += (size_t)s * inStr;
    out += (size_t)s * outStr;
    int bid = blockIdx.x;
    int o  = bid % O; bid /= O;
    int tx = bid % tilesX;
    int ty = bid / tilesX;
    extern __shared__ float wls[];
    int nw = C * 9;
    for (int i = threadIdx.x; i < nw; i += blockDim.x) wls[i] = w[o * nw + i];
    __syncthreads();
    int x = tx * 16 + (threadIdx.x & 15);
    int y = ty * 16 + (threadIdx.x >> 4);
    if (x >= Wout || y >= Hout) return;
    float acc = b[o];
    size_t plane = (size_t)Hin * Win;
    int iy0 = y * stride - 1, ix0 = x * stride - 1;
    for (int c = 0; c < C; ++c) {
        const float* ip = in + c * plane;
        const float* wc = wls + c * 9;
        #pragma unroll
        for (int ky = 0; ky < 3; ++ky) {
            int iy = iy0 + ky;
            if ((unsigned)iy >= (unsigned)Hin) continue;
            #pragma unroll
            for (int kx = 0; kx < 3; ++kx) {
                int ix = ix0 + kx;
                if ((unsigned)ix >= (unsigned)Win) continue;
                acc += ip[(size_t)iy * Win + ix] * wc[ky * 3 + kx];
            }
        }
    }
    if (act) acc = LRELU(acc);
    out[((size_t)o * Hout + y) * Wout + x] = acc;
}

// ---------------- direct 3x3 conv, per-sample weights [o][c][k] (f0, c6), batched ----------------
__global__ void conv3x3_mod(const float* __restrict__ in, const float* __restrict__ in2,
                            const float* __restrict__ W, const float* __restrict__ sb,
                            float* __restrict__ out,
                            int C, int O, int Hin, int Win, int Hout, int Wout,
                            int stride, int pad, int act, int tilesX,
                            long long inStr, long long in2Str, long long wStr,
                            long long sbStr, long long outStr)
{
    int s = blockIdx.y;
    in  += (size_t)s * inStr;
    if (in2) in2 += (size_t)s * in2Str;
    W   += (size_t)s * wStr;
    sb  += (size_t)s * sbStr;
    out += (size_t)s * outStr;
    int bid = blockIdx.x;
    int o  = bid % O; bid /= O;
    int tx = bid % tilesX;
    int ty = bid / tilesX;
    extern __shared__ float wls[];
    int nw = C * 9;
    const float* wp = W + (size_t)o * nw;
    for (int i = threadIdx.x; i < nw; i += blockDim.x) wls[i] = wp[i];
    __syncthreads();
    int x = tx * 16 + (threadIdx.x & 15);
    int y = ty * 16 + (threadIdx.x >> 4);
    if (x >= Wout || y >= Hout) return;
    float acc = sb[o];
    size_t plane = (size_t)Hin * Win;
    int iy0 = y * stride - pad, ix0 = x * stride - pad;
    for (int c = 0; c < C; ++c) {
        const float* ip  = in + c * plane;
        const float* ip2 = in2 ? in2 + c * plane : nullptr;
        const float* wc  = wls + c * 9;
        #pragma unroll
        for (int ky = 0; ky < 3; ++ky) {
            int iy = iy0 + ky;
            if ((unsigned)iy >= (unsigned)Hin) continue;
            #pragma unroll
            for (int kx = 0; kx < 3; ++kx) {
                int ix = ix0 + kx;
                if ((unsigned)ix >= (unsigned)Win) continue;
                float xv = ip[(size_t)iy * Win + ix];
                if (ip2) xv += ip2[(size_t)iy * Win + ix];
                acc += xv * wc[ky * 3 + kx];
            }
        }
    }
    if (act) acc = LRELU(acc);
    out[((size_t)o * Hout + y) * Wout + x] = acc;
}

// ---------------- 4x4 blur pad=2 (pre-down), batched: out [64, H+1, W+1], /64 ----------------
__global__ void blur_down(const float* __restrict__ in, float* __restrict__ out,
                          int H, int W, int tilesX, int tilesY,
                          long long inStr, long long outStr)
{
    int s = blockIdx.y;
    in  += (size_t)s * inStr;
    out += (size_t)s * outStr;
    int Ho = H + 1, Wo = W + 1;
    int bid = blockIdx.x;
    int tx = bid % tilesX; bid /= tilesX;
    int ty = bid % tilesY; bid /= tilesY;
    int p  = bid;
    int x = tx * 16 + (threadIdx.x & 15);
    int y = ty * 16 + (threadIdx.x >> 4);
    if (x >= Wo || y >= Ho) return;
    const float k[4] = {1.f, 3.f, 3.f, 1.f};
    const float* ip = in + (size_t)p * H * W;
    float acc = 0.f;
    #pragma unroll
    for (int ky = 0; ky < 4; ++ky) {
        int iy = y - 2 + ky;
        if ((unsigned)iy >= (unsigned)H) continue;
        float row = 0.f;
        #pragma unroll
        for (int kx = 0; kx < 4; ++kx) {
            int ix = x - 2 + kx;
            if ((unsigned)ix >= (unsigned)W) continue;
            row += ip[(size_t)iy * W + ix] * k[kx];
        }
        acc += row * k[ky];
    }
    out[((size_t)p * Ho + y) * Wo + x] = acc * (1.f / 64.f);
}

// ---------------- avg pool to 1x1 (64 planes), batched ----------------
__global__ void avgpool_hw(const float* __restrict__ in, float* __restrict__ out, int HW,
                           long long inStr, long long outStr)
{
    int s = blockIdx.y;
    in  += (size_t)s * inStr;
    out += (size_t)s * outStr;
    int p = blockIdx.x;
    const float* ip = in + (size_t)p * HW;
    float sum = 0.f;
    for (int i = threadIdx.x; i < HW; i += blockDim.x) sum += ip[i];
    __shared__ float red[256];
    red[threadIdx.x] = sum;
    __syncthreads();
    for (int off = 128; off; off >>= 1) {
        if ((int)threadIdx.x < off) red[threadIdx.x] += red[threadIdx.x + off];
        __syncthreads();
    }
    if (threadIdx.x == 0) out[p] = red[0] / (float)HW;
}

// ---------------- style FC (all 8 samples) ----------------
__global__ void style_fc(const float* __restrict__ s, const float* __restrict__ W,
                         const float* __restrict__ b, float* __restrict__ out, int outdim)
{
    int n = blockIdx.x;
    int i = threadIdx.x;
    if (i >= outdim) return;
    float acc = b[i];
    const float* sn = s + n * 64;
    const float* wi = W + i * 64;
    for (int f = 0; f < 64; ++f) acc += sn[f] * wi[f];
    out[n * 64 + i] = LRELU(acc);
}

// ------- modulate+demodulate (all 8 samples); transpose=1 -> [c][k][o] -------
__global__ void modulate(const float* __restrict__ w, const float* __restrict__ sw,
                         float* __restrict__ wout, int O, int C, int transpose)
{
    int no = blockIdx.x;
    int o = no % O, n = no / O;
    int nw = C * 9;
    int t = threadIdx.x;
    float v[9];
    int cnt = 0;
    float ss = 0.f;
    for (int idx = t; idx < nw; idx += 64) {
        int c = idx / 9;
        float val = w[o * nw + idx] * sw[n * 64 + c];
        v[cnt++] = val;
        ss += val * val;
    }
    #pragma unroll
    for (int off = 32; off; off >>= 1) ss += __shfl_xor(ss, off);
    float d = rsqrtf(ss + 1e-8f);
    cnt = 0;
    for (int idx = t; idx < nw; idx += 64) {
        float val = v[cnt++] * d;
        if (transpose)
            wout[(size_t)n * nw * O + (size_t)idx * O + o] = val;
        else
            wout[(size_t)no * nw + idx] = val;
    }
}

// ------- guide weight transpose: gt[l][(c*9+k)*64+o] = grw[((l*64+o)*64+c)*9+k] -------
__global__ void guide_transpose(const float* __restrict__ grw, float* __restrict__ gt, int total)
{
    int i = blockIdx.x * 256 + threadIdx.x;
    if (i >= total) return;
    int l = i / 36864, rem = i % 36864;
    int idx = rem / 64, o = rem % 64;
    int c = idx / 9, k = idx % 9;
    gt[i] = grw[(((size_t)l * 64 + o) * 64 + c) * 9 + k];
}

__global__ void fill_sentinel(float* __restrict__ out, int n)
{
    int i = blockIdx.x * 256 + threadIdx.x;
    if (i < n) out[i] = 1.0e9f;
}

extern "C" void kernel_launch(void* const* d_in, const int* in_sizes, int n_in,
                              void* d_out, int out_size, void* d_ws, size_t ws_size,
                              hipStream_t stream)
{
    const float* x     = (const float*)d_in[0];
    const float* ref   = (const float*)d_in[1];
    const float* g0w   = (const float*)d_in[2];
    const float* g0b   = (const float*)d_in[3];
    const float* grw   = (const float*)d_in[4];
    const float* grb   = (const float*)d_in[5];
    const float* c0w   = (const float*)d_in[6];
    const float* c0swW = (const float*)d_in[7];
    const float* c0swb = (const float*)d_in[8];
    const float* c0sbW = (const float*)d_in[9];
    const float* c0sbb = (const float*)d_in[10];
    const float* midw  = (const float*)d_in[11];
    const float* midswW= (const float*)d_in[12];
    const float* midswb= (const float*)d_in[13];
    const float* midsbW= (const float*)d_in[14];
    const float* midsbb= (const float*)d_in[15];
    const float* c6w   = (const float*)d_in[16];
    const float* c6swW = (const float*)d_in[17];
    const float* c6swb = (const float*)d_in[18];
    const float* c6sbW = (const float*)d_in[19];
    const float* c6sbb = (const float*)d_in[20];
    float* out = (float*)d_out;
    float* ws  = (float*)d_ws;

    // -------- shared region (floats) --------
    const size_t SV  = 0;                 // s [8,64]
    const size_t STY = 512;               // 12 x (sw 512 + sb 512)
    const size_t WM  = 12800;             // modulated weights (all 8 samples)
    const size_t GT  = 2989568;           // transposed guide weights [4][576][64]
    const size_t BUF = 3137024;           // start of per-sample slots

    // -------- main-path per-sample slot offsets --------
    const size_t F0 = 0;                  // [64,256,256]
    const size_t SA = 4194304;            // [64,257,257]-class
    const size_t SB = 8421440;            // [64,256,256]
    const size_t D1 = 12615744;           // [64,128,128]
    const size_t D2 = 13664320;           // [64,128,128]
    const size_t D3 = 14712896;           // [64,129,129]-class
    const size_t E1 = 15777920;           // [64,64,64]
    const size_t E2 = 16040064;
    const size_t E3 = 16302208;
    const size_t G2o = 16564352;          // combined up-weights [147456]
    const long long PER = 16711808ll;     // floats per main slot (~66.8 MB)

    // -------- guide-phase per-sample slot offsets (smaller: ~27.3 MB) --------
    const size_t gSA = 0;                 // [64,256,256]
    const size_t gD1 = 4194304;
    const size_t gD2 = 5242880;
    const size_t gE1 = 6291456;
    const size_t gE2 = 6553600;
    const long long GPER = 6815744ll;

    // adaptive group sizes (largest fitting count in {8..1})
    int G = 0, GG = 0;
    for (int g = 8; g >= 1; --g)
        if ((BUF + (size_t)g * PER) * sizeof(float) <= ws_size) { G = g; break; }
    for (int g = 8; g >= 1; --g)
        if ((BUF + (size_t)g * GPER) * sizeof(float) <= ws_size) { GG = g; break; }
    if (!G || !GG) {
        fill_sentinel<<<dim3((out_size + 255) / 256), dim3(256), 0, stream>>>(out, out_size);
        return;
    }

    dim3 blk(256);
    const int LDS1 = 29952;   // conv64_gemm<1>
    const int LDS2 = 28224;   // conv64_gemm<2>
    const int LDSU = 38784;   // upconv64_gemm

    float* B = ws + BUF;      // slot base

    // guide weights -> [c][k][o]
    guide_transpose<<<dim3(147456 / 256), blk, 0, stream>>>(grw, ws + GT, 147456);

    // ==================== guide net (grouped at GG) -> s ====================
    for (int n0 = 0; n0 < 8; ) {
        int g = (8 - n0 < GG) ? (8 - n0) : GG;
        const float* refg = ref + (size_t)n0 * 196608;
        conv3x3_guide<<<dim3(64 * 16 * 16, g), blk, 27 * 4, stream>>>(
            refg, g0w, g0b, B + gSA, 3, 64, 256, 256, 256, 256, 1, 1, 16, 196608, GPER);
        conv64_gemm<2><<<dim3(8 * 8, g), blk, LDS2, stream>>>(
            B + gSA, ws + GT, grb, B + gD1, 256, 256, 128, 128, 1, 1, 8, GPER, 0, 0, GPER);
        conv64_gemm<1><<<dim3(8 * 8, g), blk, LDS1, stream>>>(
            B + gD1, ws + GT + 36864, grb + 64, B + gD2, 128, 128, 128, 128, 1, 1, 8, GPER, 0, 0, GPER);
        conv64_gemm<2><<<dim3(4 * 4, g), blk, LDS2, stream>>>(
            B + gD2, ws + GT + 73728, grb + 128, B + gE1, 128, 128, 64, 64, 1, 1, 4, GPER, 0, 0, GPER);
        conv64_gemm<1><<<dim3(4 * 4, g), blk, LDS1, stream>>>(
            B + gE1, ws + GT + 110592, grb + 192, B + gE2, 64, 64, 64, 64, 1, 0, 4, GPER, 0, 0, GPER);
        avgpool_hw<<<dim3(64, g), blk, 0, stream>>>(B + gE2, ws + SV + (size_t)n0 * 64, 4096, GPER, 64);
        n0 += g;
    }

    // ==================== styles + modulated weights (all 8 samples) ====================
    const float* Wt[12];  const float* swWp[12]; const float* swbp[12];
    const float* sbWp[12]; const float* sbbp[12];
    int Ci[12], Oi[12];
    size_t wmo[12];
    Wt[0] = c0w; swWp[0] = c0swW; swbp[0] = c0swb; sbWp[0] = c0sbW; sbbp[0] = c0sbb;
    Ci[0] = 3; Oi[0] = 64; wmo[0] = WM;
    for (int i = 0; i < 10; ++i) {
        Wt[1 + i]   = midw   + (size_t)i * 36864;
        swWp[1 + i] = midswW + (size_t)i * 4096;
        swbp[1 + i] = midswb + (size_t)i * 64;
        sbWp[1 + i] = midsbW + (size_t)i * 4096;
        sbbp[1 + i] = midsbb + (size_t)i * 64;
        Ci[1 + i] = 64; Oi[1 + i] = 64;
        wmo[1 + i] = WM + 13824ull + (size_t)i * 294912ull;
    }
    Wt[11] = c6w; swWp[11] = c6swW; swbp[11] = c6swb; sbWp[11] = c6sbW; sbbp[11] = c6sbb;
    Ci[11] = 64; Oi[11] = 3; wmo[11] = WM + 13824ull + 2949120ull;

    // transpose flags per CONSUMER: conv64_gemm -> 1; conv3x3_mod / combine_up_w -> 0
    const int trf[12] = {0, 1, 1, 1, 1, 1, 1, 0, 1, 0, 1, 0};

    for (int i = 0; i < 12; ++i) {
        style_fc<<<dim3(8), dim3(64), 0, stream>>>(ws + SV, swWp[i], swbp[i], ws + STY + i * 1024, Ci[i]);
        style_fc<<<dim3(8), dim3(64), 0, stream>>>(ws + SV, sbWp[i], sbbp[i], ws + STY + i * 1024 + 512, Oi[i]);
        modulate<<<dim3(8 * Oi[i]), dim3(64), 0, stream>>>(Wt[i], ws + STY + i * 1024, ws + wmo[i], Oi[i], Ci[i], trf[i]);
    }

    // ==================== main path (grouped at G) ====================
    for (int n0 = 0; n0 < 8; ) {
        int g = (8 - n0 < G) ? (8 - n0) : G;
        const float* xg = x + (size_t)n0 * 196608;
        float* outg = out + (size_t)n0 * 196608;
        #define WN(i)  (ws + wmo[i] + (size_t)n0 * Oi[i] * Ci[i] * 9)
        #define WSTR(i) ((long long)(Oi[i] * Ci[i] * 9))
        #define SBN(i) (ws + STY + (i) * 1024 + 512 + (size_t)n0 * 64)
        // f0 = modconv(x, c0)
        conv3x3_mod<<<dim3(64 * 16 * 16, g), blk, 27 * 4, stream>>>(
            xg, nullptr, WN(0), SBN(0), B + F0, 3, 64, 256, 256, 256, 256, 1, 1, 1, 16,
            196608, 0, WSTR(0), 64, PER);
        // f1 down
        blur_down<<<dim3(64 * 17 * 17, g), blk, 0, stream>>>(B + F0, B + SA, 256, 256, 17, 17, PER, PER);
        conv64_gemm<2><<<dim3(8 * 8, g), blk, LDS2, stream>>>(
            B + SA, WN(1), SBN(1), B + D1, 257, 257, 128, 128, 0, 1, 8, PER, WSTR(1), 64, PER);
        conv64_gemm<1><<<dim3(8 * 8, g), blk, LDS1, stream>>>(
            B + D1, WN(2), SBN(2), B + D2, 128, 128, 128, 128, 1, 1, 8, PER, WSTR(2), 64, PER);
        // f2 down
        blur_down<<<dim3(64 * 9 * 9, g), blk, 0, stream>>>(B + D2, B + D3, 128, 128, 9, 9, PER, PER);
        conv64_gemm<2><<<dim3(4 * 4, g), blk, LDS2, stream>>>(
            B + D3, WN(3), SBN(3), B + E1, 129, 129, 64, 64, 0, 1, 4, PER, WSTR(3), 64, PER);
        conv64_gemm<1><<<dim3(4 * 4, g), blk, LDS1, stream>>>(
            B + E1, WN(4), SBN(4), B + E2, 64, 64, 64, 64, 1, 1, 4, PER, WSTR(4), 64, PER);
        // f3 x2
        conv64_gemm<1><<<dim3(4 * 4, g), blk, LDS1, stream>>>(
            B + E2, WN(5), SBN(5), B + E3, 64, 64, 64, 64, 1, 1, 4, PER, WSTR(5), 64, PER);
        conv64_gemm<1><<<dim3(4 * 4, g), blk, LDS1, stream>>>(
            B + E3, WN(6), SBN(6), B + E1, 64, 64, 64, 64, 1, 1, 4, PER, WSTR(6), 64, PER);
        // f4 up (fused): combine -> G2 slot; upconv(f3+f2) -> D1 (128^2); conv -> D3
        combine_up_w<<<dim3(576, g), blk, 0, stream>>>(WN(7), B + G2o, WSTR(7), PER);
        upconv64_gemm<<<dim3(8 * 8, g), blk, LDSU, stream>>>(
            B + E1, B + E2, B + G2o, SBN(7), B + D1, 64, 64, 8, PER, 64, PER);
        conv64_gemm<1><<<dim3(8 * 8, g), blk, LDS1, stream>>>(
            B + D1, WN(8), SBN(8), B + D3, 128, 128, 128, 128, 1, 1, 8, PER, WSTR(8), 64, PER);
        // f5 up: combine -> G2 slot; upconv(f4+f1) -> SA (256^2); conv -> SB
        combine_up_w<<<dim3(576, g), blk, 0, stream>>>(WN(9), B + G2o, WSTR(9), PER);
        upconv64_gemm<<<dim3(16 * 16, g), blk, LDSU, stream>>>(
            B + D3, B + D2, B + G2o, SBN(9), B + SA, 128, 128, 16, PER, 64, PER);
        conv64_gemm<1><<<dim3(16 * 16, g), blk, LDS1, stream>>>(
            B + SA, WN(10), SBN(10), B + SB, 256, 256, 256, 256, 1, 1, 16, PER, WSTR(10), 64, PER);
        // out = modconv(f5+f0, c6, no act)
        conv3x3_mod<<<dim3(3 * 16 * 16, g), blk, 2304, stream>>>(
            B + SB, B + F0, WN(11), SBN(11), outg, 64, 3, 256, 256, 256, 256, 1, 1, 0, 16,
            PER, PER, WSTR(11), 64, 196608);
        #undef WN
        #undef WSTR
        #undef SBN
        n0 += g;
    }
}

// Round 8
// 5895.450 us; speedup vs baseline: 6.2878x; 1.2189x over previous
//
#include <hip/hip_runtime.h>

#define LRELU(v) ((v) >= 0.f ? (v) : 0.2f * (v))

// ================= implicit-GEMM 3x3 conv, C=64 -> O=64, sample-batched =================
template<int S>
__global__ void conv64_gemm(const float* __restrict__ in, const float* __restrict__ Wt,
                            const float* __restrict__ bias, float* __restrict__ out,
                            int Hin, int Win, int Hout, int Wout, int pad, int act, int tilesX,
                            long long inStr, long long wStr, long long bStr, long long outStr)
{
    constexpr int CC  = (S == 1) ? 8 : 4;
    constexpr int TIN = (S == 1) ? 18 : 33;
    constexpr int RS  = (S == 1) ? 20 : 36;
    constexpr int NF4 = (S == 1) ? 3 : 5;
    constexpr int PW  = NF4 * 4;
    extern __shared__ float lds[];
    float* it = lds;
    float* wl = lds + CC * TIN * RS;

    int s = blockIdx.y;
    in   += (size_t)s * inStr;
    Wt   += (size_t)s * wStr;
    bias += (size_t)s * bStr;
    out  += (size_t)s * outStr;

    int b  = blockIdx.x;
    int tx = b % tilesX, ty = b / tilesX;
    int t  = threadIdx.x;
    int og = t >> 5;
    int pg = t & 31;
    int r  = pg >> 1, ch = pg & 1;

    float acc[8][8];
    #pragma unroll
    for (int i = 0; i < 8; ++i)
        #pragma unroll
        for (int j = 0; j < 8; ++j) acc[i][j] = 0.f;

    const int y0 = ty * 16 * S - pad;
    const int x0 = tx * 16 * S - pad;
    const size_t plane = (size_t)Hin * Win;

    for (int c0 = 0; c0 < 64; c0 += CC) {
        __syncthreads();
        {
            const float4* src = (const float4*)(Wt + c0 * 9 * 64);
            float4* dst = (float4*)wl;
            for (int i = t; i < CC * 9 * 16; i += 256) dst[i] = src[i];
        }
        for (int rowi = t; rowi < CC * TIN; rowi += 256) {
            int cc = rowi / TIN, rr = rowi - cc * TIN;
            int iy = y0 + rr;
            float* dst = it + (size_t)rowi * RS;
            const float* srow = in + (size_t)(c0 + cc) * plane + (size_t)iy * Win + x0;
            if ((unsigned)iy < (unsigned)Hin && x0 >= 0 && x0 + RS <= Win) {
                #pragma unroll
                for (int q = 0; q < RS / 4; ++q)
                    ((float4*)dst)[q] = ((const float4*)srow)[q];
            } else {
                for (int cl = 0; cl < TIN; ++cl) {
                    int ix = x0 + cl;
                    float v = 0.f;
                    if ((unsigned)iy < (unsigned)Hin && (unsigned)ix < (unsigned)Win)
                        v = in[(size_t)(c0 + cc) * plane + (size_t)iy * Win + ix];
                    dst[cl] = v;
                }
            }
        }
        __syncthreads();
        for (int cc = 0; cc < CC; ++cc) {
            const float* base = it + cc * TIN * RS;
            #pragma unroll
            for (int ky = 0; ky < 3; ++ky) {
                float p[PW];
                const float* rowp = base + (r * S + ky) * RS + ch * 8 * S;
                #pragma unroll
                for (int q = 0; q < NF4; ++q) {
                    float4 f = *(const float4*)(rowp + q * 4);
                    p[q*4+0] = f.x; p[q*4+1] = f.y; p[q*4+2] = f.z; p[q*4+3] = f.w;
                }
                #pragma unroll
                for (int kx = 0; kx < 3; ++kx) {
                    const float* wp = wl + ((cc * 9) + ky * 3 + kx) * 64 + og * 8;
                    float4 wa = *(const float4*)wp;
                    float4 wb = *(const float4*)(wp + 4);
                    float w8[8] = {wa.x, wa.y, wa.z, wa.w, wb.x, wb.y, wb.z, wb.w};
                    #pragma unroll
                    for (int oi = 0; oi < 8; ++oi)
                        #pragma unroll
                        for (int j = 0; j < 8; ++j)
                            acc[oi][j] += w8[oi] * p[j * S + kx];
                }
            }
        }
    }

    int y  = ty * 16 + r;
    int xb = tx * 16 + ch * 8;
    #pragma unroll
    for (int oi = 0; oi < 8; ++oi) {
        int o = og * 8 + oi;
        float bo = bias[o];
        float v[8];
        #pragma unroll
        for (int j = 0; j < 8; ++j) {
            float a = acc[oi][j] + bo;
            v[j] = act ? LRELU(a) : a;
        }
        float* op = out + ((size_t)o * Hout + y) * Wout + xb;
        *(float4*)op       = make_float4(v[0], v[1], v[2], v[3]);
        *(float4*)(op + 4) = make_float4(v[4], v[5], v[6], v[7]);
    }
}

// ========== implicit-GEMM 3x3 conv, C=3 -> O=64, stride1 pad1 (g0 guide, f0) ==========
// in [3,H,W]; Wt [27][64] ([c][k][o]); bias[64]; out [64,H,W]; lrelu
__global__ void conv3_gemm(const float* __restrict__ in, const float* __restrict__ Wt,
                           const float* __restrict__ bias, float* __restrict__ out,
                           int H, int W, int tilesX,
                           long long inStr, long long wStr, long long bStr, long long outStr)
{
    constexpr int TIN = 18, RS = 20;
    __shared__ float it[3 * TIN * RS];   // 1080
    __shared__ float wl[27 * 64];        // 1728
    int s = blockIdx.y;
    in   += (size_t)s * inStr;
    Wt   += (size_t)s * wStr;
    bias += (size_t)s * bStr;
    out  += (size_t)s * outStr;

    int b  = blockIdx.x;
    int tx = b % tilesX, ty = b / tilesX;
    int t  = threadIdx.x;
    {
        const float4* src = (const float4*)Wt;
        float4* dst = (float4*)wl;
        for (int i = t; i < 27 * 16; i += 256) dst[i] = src[i];
    }
    const int y0 = ty * 16 - 1, x0 = tx * 16 - 1;
    const size_t plane = (size_t)H * W;
    for (int rowi = t; rowi < 3 * TIN; rowi += 256) {
        int cc = rowi / TIN, rr = rowi - cc * TIN;
        int iy = y0 + rr;
        float* dst = it + (size_t)rowi * RS;
        const float* srow = in + (size_t)cc * plane + (size_t)iy * W + x0;
        if ((unsigned)iy < (unsigned)H && x0 >= 0 && x0 + RS <= W) {
            #pragma unroll
            for (int q = 0; q < RS / 4; ++q)
                ((float4*)dst)[q] = ((const float4*)srow)[q];
        } else {
            for (int cl = 0; cl < TIN; ++cl) {
                int ix = x0 + cl;
                float v = 0.f;
                if ((unsigned)iy < (unsigned)H && (unsigned)ix < (unsigned)W)
                    v = in[(size_t)cc * plane + (size_t)iy * W + ix];
                dst[cl] = v;
            }
        }
    }
    __syncthreads();

    int og = t >> 5, pg = t & 31;
    int r  = pg >> 1, ch = pg & 1;
    float acc[8][8];
    #pragma unroll
    for (int i = 0; i < 8; ++i)
        #pragma unroll
        for (int j = 0; j < 8; ++j) acc[i][j] = 0.f;

    for (int c = 0; c < 3; ++c) {
        const float* base = it + c * TIN * RS;
        #pragma unroll
        for (int ky = 0; ky < 3; ++ky) {
            float p[12];
            const float* rowp = base + (r + ky) * RS + ch * 8;
            #pragma unroll
            for (int q = 0; q < 3; ++q) {
                float4 f = *(const float4*)(rowp + q * 4);
                p[q*4+0] = f.x; p[q*4+1] = f.y; p[q*4+2] = f.z; p[q*4+3] = f.w;
            }
            #pragma unroll
            for (int kx = 0; kx < 3; ++kx) {
                const float* wp = wl + ((c * 9) + ky * 3 + kx) * 64 + og * 8;
                float4 wa = *(const float4*)wp;
                float4 wb = *(const float4*)(wp + 4);
                float w8[8] = {wa.x, wa.y, wa.z, wa.w, wb.x, wb.y, wb.z, wb.w};
                #pragma unroll
                for (int oi = 0; oi < 8; ++oi)
                    #pragma unroll
                    for (int j = 0; j < 8; ++j)
                        acc[oi][j] += w8[oi] * p[j + kx];
            }
        }
    }

    int y  = ty * 16 + r;
    int xb = tx * 16 + ch * 8;
    #pragma unroll
    for (int oi = 0; oi < 8; ++oi) {
        int o = og * 8 + oi;
        float bo = bias[o];
        float v[8];
        #pragma unroll
        for (int j = 0; j < 8; ++j) {
            float a = acc[oi][j] + bo;
            v[j] = LRELU(a);
        }
        float* op = out + ((size_t)o * H + y) * W + xb;
        *(float4*)op       = make_float4(v[0], v[1], v[2], v[3]);
        *(float4*)(op + 4) = make_float4(v[4], v[5], v[6], v[7]);
    }
}

// ========== implicit-GEMM 3x3 conv, C=64 -> O=3, (in1+in2), no act (c6) ==========
// Wt [576][3] ([c][k][o]); sb[3-ish, stride 64 layout]; out [3,H,W]
__global__ void conv64to3_gemm(const float* __restrict__ in, const float* __restrict__ in2,
                               const float* __restrict__ Wt, const float* __restrict__ sb,
                               float* __restrict__ out, int H, int W, int tilesX,
                               long long inStr, long long wStr, long long sbStr, long long outStr)
{
    constexpr int CC = 8, TIN = 18, RS = 20;
    __shared__ float it[CC * TIN * RS];   // 2880
    __shared__ float wl[CC * 9 * 3];      // 216
    int s = blockIdx.y;
    in  += (size_t)s * inStr;
    in2 += (size_t)s * inStr;
    Wt  += (size_t)s * wStr;
    sb  += (size_t)s * sbStr;
    out += (size_t)s * outStr;

    int b  = blockIdx.x;
    int tx = b % tilesX, ty = b / tilesX;
    int t  = threadIdx.x;
    int r  = t >> 4, cl = t & 15;        // output pixel (r, cl) in 16x16 tile
    const int y0 = ty * 16 - 1, x0 = tx * 16 - 1;
    const size_t plane = (size_t)H * W;

    float acc[3] = {0.f, 0.f, 0.f};

    for (int c0 = 0; c0 < 64; c0 += CC) {
        __syncthreads();
        for (int i = t; i < CC * 9 * 3; i += 256) wl[i] = Wt[c0 * 27 + i];
        for (int rowi = t; rowi < CC * TIN; rowi += 256) {
            int cc = rowi / TIN, rr = rowi - cc * TIN;
            int iy = y0 + rr;
            float* dst = it + (size_t)rowi * RS;
            size_t roff = (size_t)(c0 + cc) * plane + (size_t)iy * W + x0;
            if ((unsigned)iy < (unsigned)H && x0 >= 0 && x0 + RS <= W) {
                #pragma unroll
                for (int q = 0; q < RS / 4; ++q) {
                    float4 a = ((const float4*)(in  + roff))[q];
                    float4 bb = ((const float4*)(in2 + roff))[q];
                    ((float4*)dst)[q] = make_float4(a.x + bb.x, a.y + bb.y, a.z + bb.z, a.w + bb.w);
                }
            } else {
                for (int c2 = 0; c2 < TIN; ++c2) {
                    int ix = x0 + c2;
                    float v = 0.f;
                    if ((unsigned)iy < (unsigned)H && (unsigned)ix < (unsigned)W) {
                        size_t off = (size_t)(c0 + cc) * plane + (size_t)iy * W + ix;
                        v = in[off] + in2[off];
                    }
                    dst[c2] = v;
                }
            }
        }
        __syncthreads();
        for (int cc = 0; cc < CC; ++cc) {
            const float* base = it + cc * TIN * RS;
            #pragma unroll
            for (int ky = 0; ky < 3; ++ky) {
                const float* rowp = base + (r + ky) * RS + cl;
                float p0 = rowp[0], p1 = rowp[1], p2 = rowp[2];
                const float* wr = wl + (cc * 9 + ky * 3) * 3;
                #pragma unroll
                for (int o = 0; o < 3; ++o)
                    acc[o] += wr[o] * p0 + wr[3 + o] * p1 + wr[6 + o] * p2;
            }
        }
    }

    int y = ty * 16 + r, x = tx * 16 + cl;
    #pragma unroll
    for (int o = 0; o < 3; ++o)
        out[((size_t)o * H + y) * W + x] = acc[o] + sb[o];
}

// ===== fused up-conv: tconv(s2,3x3)+blur(4x4,x4/64)+bias+lrelu, C=64 -> O=64, batched =====
__global__ void upconv64_gemm(const float* __restrict__ in, const float* __restrict__ in2,
                              const float* __restrict__ G2, const float* __restrict__ sb,
                              float* __restrict__ out, int Hin, int Win, int tilesX,
                              long long bufStr, long long sbStr, long long outStr)
{
    constexpr int CC = 4;
    constexpr int RS = 12;
    extern __shared__ float lds[];
    float* it = lds;
    float* wl = lds + CC * 10 * RS;

    int s = blockIdx.y;
    in  += (size_t)s * bufStr;
    in2 += (size_t)s * bufStr;
    G2  += (size_t)s * bufStr;
    sb  += (size_t)s * sbStr;
    out += (size_t)s * outStr;

    int b  = blockIdx.x;
    int tx = b % tilesX, ty = b / tilesX;
    int t  = threadIdx.x;
    int og = t & 7;
    int q  = t >> 3;
    int rhalf = q & 7;
    int pxb   = (q >> 3) & 1;
    int rpar  = q >> 4;
    int r = 2 * rhalf + rpar;
    const int Y0 = ty * 16, X0 = tx * 16;
    const int gy0 = Y0 / 2 - 1;
    const int gx0 = X0 / 2 - 1;
    const size_t plane = (size_t)Hin * Win;

    float acc[8][8];
    #pragma unroll
    for (int i = 0; i < 8; ++i)
        #pragma unroll
        for (int j = 0; j < 8; ++j) acc[i][j] = 0.f;

    for (int c0 = 0; c0 < 64; c0 += CC) {
        __syncthreads();
        {
            const float4* src = (const float4*)(G2 + (size_t)c0 * 2304);
            float4* dst = (float4*)wl;
            for (int i = t; i < CC * 2304 / 4; i += 256) dst[i] = src[i];
        }
        for (int rowi = t; rowi < CC * 10; rowi += 256) {
            int cc = rowi / 10, rr = rowi - cc * 10;
            int gi = gy0 + rr;
            float* dst = it + (size_t)rowi * RS;
            size_t roff = (size_t)(c0 + cc) * plane + (size_t)gi * Win + gx0;
            if ((unsigned)gi < (unsigned)Hin && gx0 >= 0 && gx0 + RS <= Win) {
                #pragma unroll
                for (int qq = 0; qq < 3; ++qq) {
                    float4 a = ((const float4*)(in  + roff))[qq];
                    float4 bb = ((const float4*)(in2 + roff))[qq];
                    ((float4*)dst)[qq] = make_float4(a.x + bb.x, a.y + bb.y, a.z + bb.z, a.w + bb.w);
                }
            } else {
                for (int cl = 0; cl < RS; ++cl) {
                    int gj = gx0 + cl;
                    float v = 0.f;
                    if (cl < 10 && (unsigned)gi < (unsigned)Hin && (unsigned)gj < (unsigned)Win) {
                        size_t off = (size_t)(c0 + cc) * plane + (size_t)gi * Win + gj;
                        v = in[off] + in2[off];
                    }
                    dst[cl] = v;
                }
            }
        }
        __syncthreads();
        for (int cc = 0; cc < CC; ++cc) {
            const float* ib = it + cc * 10 * RS;
            const float* wb = wl + cc * 2304 + (rpar * 2 + pxb) * 576;
            #pragma unroll
            for (int ty2 = 0; ty2 < 3; ++ty2) {
                float p[12];
                const float* rowp = ib + (rhalf + ty2) * RS;
                #pragma unroll
                for (int qq = 0; qq < 3; ++qq) {
                    float4 f = *(const float4*)(rowp + qq * 4);
                    p[qq*4+0] = f.x; p[qq*4+1] = f.y; p[qq*4+2] = f.z; p[qq*4+3] = f.w;
                }
                #pragma unroll
                for (int tx2 = 0; tx2 < 3; ++tx2) {
                    const float* wp = wb + (ty2 * 3 + tx2) * 64 + og * 8;
                    float4 wa = *(const float4*)wp;
                    float4 wv = *(const float4*)(wp + 4);
                    float w8[8] = {wa.x, wa.y, wa.z, wa.w, wv.x, wv.y, wv.z, wv.w};
                    #pragma unroll
                    for (int oi = 0; oi < 8; ++oi)
                        #pragma unroll
                        for (int k = 0; k < 8; ++k)
                            acc[oi][k] += w8[oi] * p[k + tx2];
                }
            }
        }
    }

    const int Hout = 2 * Hin, Wout = 2 * Win;
    int y = Y0 + r;
    #pragma unroll
    for (int oi = 0; oi < 8; ++oi) {
        int o = og * 8 + oi;
        float bo = sb[o];
        float* op = out + ((size_t)o * Hout + y) * Wout;
        #pragma unroll
        for (int k = 0; k < 8; ++k) {
            float a = acc[oi][k] + bo;
            op[X0 + 2 * k + pxb] = LRELU(a);
        }
    }
}

// ------- build combined up-weights, batched -------
__global__ void combine_up_w(const float* __restrict__ W, float* __restrict__ G2,
                             long long wStr, long long g2Str)
{
    int s = blockIdx.y;
    W  += (size_t)s * wStr;
    G2 += (size_t)s * g2Str;
    int i = blockIdx.x * 256 + threadIdx.x;
    if (i >= 147456) return;
    int o = i & 63;
    int rest = i >> 6;
    int m = rest % 36, c = rest / 36;
    int txk = m % 3, tyk = (m / 3) % 3;
    int px = (m / 9) & 1, py = m / 18;
    int dy = 2 * tyk - 1 - py, dx = 2 * txk - 1 - px;
    const float K[4] = {1.f, 3.f, 3.f, 1.f};
    const float* wp = W + ((size_t)o * 64 + c) * 9;
    float sacc = 0.f;
    #pragma unroll
    for (int a = 0; a < 3; ++a) {
        int ky = a + dy;
        if ((unsigned)ky >= 4u) continue;
        #pragma unroll
        for (int b2 = 0; b2 < 3; ++b2) {
            int kx = b2 + dx;
            if ((unsigned)kx >= 4u) continue;
            sacc += K[ky] * K[kx] * wp[a * 3 + b2];
        }
    }
    G2[i] = sacc * (1.f / 16.f);
}

// ---------------- 4x4 blur pad=2 (pre-down), batched ----------------
__global__ void blur_down(const float* __restrict__ in, float* __restrict__ out,
                          int H, int W, int tilesX, int tilesY,
                          long long inStr, long long outStr)
{
    int s = blockIdx.y;
    in  += (size_t)s * inStr;
    out += (size_t)s * outStr;
    int Ho = H + 1, Wo = W + 1;
    int bid = blockIdx.x;
    int tx = bid % tilesX; bid /= tilesX;
    int ty = bid % tilesY; bid /= tilesY;
    int p  = bid;
    int x = tx * 16 + (threadIdx.x & 15);
    int y = ty * 16 + (threadIdx.x >> 4);
    if (x >= Wo || y >= Ho) return;
    const float k[4] = {1.f, 3.f, 3.f, 1.f};
    const float* ip = in + (size_t)p * H * W;
    float acc = 0.f;
    #pragma unroll
    for (int ky = 0; ky < 4; ++ky) {
        int iy = y - 2 + ky;
        if ((unsigned)iy >= (unsigned)H) continue;
        float row = 0.f;
        #pragma unroll
        for (int kx = 0; kx < 4; ++kx) {
            int ix = x - 2 + kx;
            if ((unsigned)ix >= (unsigned)W) continue;
            row += ip[(size_t)iy * W + ix] * k[kx];
        }
        acc += row * k[ky];
    }
    out[((size_t)p * Ho + y) * Wo + x] = acc * (1.f / 64.f);
}

// ---------------- avg pool to 1x1 (64 planes), batched ----------------
__global__ void avgpool_hw(const float* __restrict__ in, float* __restrict__ out, int HW,
                           long long inStr, long long outStr)
{
    int s = blockIdx.y;
    in  += (size_t)s * inStr;
    out += (size_t)s * outStr;
    int p = blockIdx.x;
    const float* ip = in + (size_t)p * HW;
    float sum = 0.f;
    for (int i = threadIdx.x; i < HW; i += blockDim.x) sum += ip[i];
    __shared__ float red[256];
    red[threadIdx.x] = sum;
    __syncthreads();
    for (int off = 128; off; off >>= 1) {
        if ((int)threadIdx.x < off) red[threadIdx.x] += red[threadIdx.x + off];
        __syncthreads();
    }
    if (threadIdx.x == 0) out[p] = red[0] / (float)HW;
}

// ---------------- style FC (all 8 samples) ----------------
__global__ void style_fc(const float* __restrict__ s, const float* __restrict__ W,
                         const float* __restrict__ b, float* __restrict__ out, int outdim)
{
    int n = blockIdx.x;
    int i = threadIdx.x;
    if (i >= outdim) return;
    float acc = b[i];
    const float* sn = s + n * 64;
    const float* wi = W + i * 64;
    for (int f = 0; f < 64; ++f) acc += sn[f] * wi[f];
    out[n * 64 + i] = LRELU(acc);
}

// ------- modulate+demodulate (all 8 samples); transpose=1 -> [c][k][o] -------
__global__ void modulate(const float* __restrict__ w, const float* __restrict__ sw,
                         float* __restrict__ wout, int O, int C, int transpose)
{
    int no = blockIdx.x;
    int o = no % O, n = no / O;
    int nw = C * 9;
    int t = threadIdx.x;
    float v[9];
    int cnt = 0;
    float ss = 0.f;
    for (int idx = t; idx < nw; idx += 64) {
        int c = idx / 9;
        float val = w[o * nw + idx] * sw[n * 64 + c];
        v[cnt++] = val;
        ss += val * val;
    }
    #pragma unroll
    for (int off = 32; off; off >>= 1) ss += __shfl_xor(ss, off);
    float d = rsqrtf(ss + 1e-8f);
    cnt = 0;
    for (int idx = t; idx < nw; idx += 64) {
        float val = v[cnt++] * d;
        if (transpose)
            wout[(size_t)n * nw * O + (size_t)idx * O + o] = val;
        else
            wout[(size_t)no * nw + idx] = val;
    }
}

// ------- guide weight transpose: gt[l][(c*9+k)*64+o] = grw[((l*64+o)*64+c)*9+k] -------
__global__ void guide_transpose(const float* __restrict__ grw, float* __restrict__ gt, int total)
{
    int i = blockIdx.x * 256 + threadIdx.x;
    if (i >= total) return;
    int l = i / 36864, rem = i % 36864;
    int idx = rem / 64, o = rem % 64;
    int c = idx / 9, k = idx % 9;
    gt[i] = grw[(((size_t)l * 64 + o) * 64 + c) * 9 + k];
}

// ------- g0 weight transpose: gt[(c*9+k)*64+o] = g0w[(o*3+c)*9+k] (1728 elems) -------
__global__ void g0_transpose(const float* __restrict__ g0w, float* __restrict__ gt)
{
    int i = blockIdx.x * 256 + threadIdx.x;
    if (i >= 1728) return;
    int idx = i / 64, o = i % 64;
    int c = idx / 9, k = idx % 9;
    gt[i] = g0w[((size_t)o * 3 + c) * 9 + k];
}

__global__ void fill_sentinel(float* __restrict__ out, int n)
{
    int i = blockIdx.x * 256 + threadIdx.x;
    if (i < n) out[i] = 1.0e9f;
}

extern "C" void kernel_launch(void* const* d_in, const int* in_sizes, int n_in,
                              void* d_out, int out_size, void* d_ws, size_t ws_size,
                              hipStream_t stream)
{
    const float* x     = (const float*)d_in[0];
    const float* ref   = (const float*)d_in[1];
    const float* g0w   = (const float*)d_in[2];
    const float* g0b   = (const float*)d_in[3];
    const float* grw   = (const float*)d_in[4];
    const float* grb   = (const float*)d_in[5];
    const float* c0w   = (const float*)d_in[6];
    const float* c0swW = (const float*)d_in[7];
    const float* c0swb = (const float*)d_in[8];
    const float* c0sbW = (const float*)d_in[9];
    const float* c0sbb = (const float*)d_in[10];
    const float* midw  = (const float*)d_in[11];
    const float* midswW= (const float*)d_in[12];
    const float* midswb= (const float*)d_in[13];
    const float* midsbW= (const float*)d_in[14];
    const float* midsbb= (const float*)d_in[15];
    const float* c6w   = (const float*)d_in[16];
    const float* c6swW = (const float*)d_in[17];
    const float* c6swb = (const float*)d_in[18];
    const float* c6sbW = (const float*)d_in[19];
    const float* c6sbb = (const float*)d_in[20];
    float* out = (float*)d_out;
    float* ws  = (float*)d_ws;

    // -------- shared region (floats) --------
    const size_t SV  = 0;                 // s [8,64]
    const size_t STY = 512;               // 12 x (sw 512 + sb 512)
    const size_t WM  = 12800;             // modulated weights (all 8 samples)
    const size_t GT  = 2989568;           // transposed guide weights [4][576][64]
    const size_t G0T = 3137024;           // transposed g0 weights [27][64]
    const size_t BUF = 3138816;           // start of per-sample slots

    // -------- main-path per-sample slot offsets --------
    const size_t F0 = 0;                  // [64,256,256]
    const size_t SA = 4194304;            // [64,257,257]-class
    const size_t SB = 8421440;            // [64,256,256]
    const size_t D1 = 12615744;           // [64,128,128]
    const size_t D2 = 13664320;           // [64,128,128]
    const size_t D3 = 14712896;           // [64,129,129]-class
    const size_t E1 = 15777920;           // [64,64,64]
    const size_t E2 = 16040064;
    const size_t E3 = 16302208;
    const size_t G2o = 16564352;          // combined up-weights [147456]
    const long long PER = 16711808ll;     // floats per main slot (~66.8 MB)

    // -------- guide-phase per-sample slot offsets (~27.3 MB) --------
    const size_t gSA = 0;                 // [64,256,256]
    const size_t gD1 = 4194304;
    const size_t gD2 = 5242880;
    const size_t gE1 = 6291456;
    const size_t gE2 = 6553600;
    const long long GPER = 6815744ll;

    int G = 0, GG = 0;
    for (int g = 8; g >= 1; --g)
        if ((BUF + (size_t)g * PER) * sizeof(float) <= ws_size) { G = g; break; }
    for (int g = 8; g >= 1; --g)
        if ((BUF + (size_t)g * GPER) * sizeof(float) <= ws_size) { GG = g; break; }
    if (!G || !GG) {
        fill_sentinel<<<dim3((out_size + 255) / 256), dim3(256), 0, stream>>>(out, out_size);
        return;
    }

    dim3 blk(256);
    const int LDS1 = 29952;   // conv64_gemm<1>
    const int LDS2 = 28224;   // conv64_gemm<2>
    const int LDSU = 38784;   // upconv64_gemm

    float* B = ws + BUF;

    guide_transpose<<<dim3(147456 / 256), blk, 0, stream>>>(grw, ws + GT, 147456);
    g0_transpose<<<dim3(7), blk, 0, stream>>>(g0w, ws + G0T);

    // ==================== guide net (grouped at GG) -> s ====================
    for (int n0 = 0; n0 < 8; ) {
        int g = (8 - n0 < GG) ? (8 - n0) : GG;
        const float* refg = ref + (size_t)n0 * 196608;
        conv3_gemm<<<dim3(16 * 16, g), blk, 0, stream>>>(
            refg, ws + G0T, g0b, B + gSA, 256, 256, 16, 196608, 0, 0, GPER);
        conv64_gemm<2><<<dim3(8 * 8, g), blk, LDS2, stream>>>(
            B + gSA, ws + GT, grb, B + gD1, 256, 256, 128, 128, 1, 1, 8, GPER, 0, 0, GPER);
        conv64_gemm<1><<<dim3(8 * 8, g), blk, LDS1, stream>>>(
            B + gD1, ws + GT + 36864, grb + 64, B + gD2, 128, 128, 128, 128, 1, 1, 8, GPER, 0, 0, GPER);
        conv64_gemm<2><<<dim3(4 * 4, g), blk, LDS2, stream>>>(
            B + gD2, ws + GT + 73728, grb + 128, B + gE1, 128, 128, 64, 64, 1, 1, 4, GPER, 0, 0, GPER);
        conv64_gemm<1><<<dim3(4 * 4, g), blk, LDS1, stream>>>(
            B + gE1, ws + GT + 110592, grb + 192, B + gE2, 64, 64, 64, 64, 1, 0, 4, GPER, 0, 0, GPER);
        avgpool_hw<<<dim3(64, g), blk, 0, stream>>>(B + gE2, ws + SV + (size_t)n0 * 64, 4096, GPER, 64);
        n0 += g;
    }

    // ==================== styles + modulated weights (all 8 samples) ====================
    const float* Wt[12];  const float* swWp[12]; const float* swbp[12];
    const float* sbWp[12]; const float* sbbp[12];
    int Ci[12], Oi[12];
    size_t wmo[12];
    Wt[0] = c0w; swWp[0] = c0swW; swbp[0] = c0swb; sbWp[0] = c0sbW; sbbp[0] = c0sbb;
    Ci[0] = 3; Oi[0] = 64; wmo[0] = WM;
    for (int i = 0; i < 10; ++i) {
        Wt[1 + i]   = midw   + (size_t)i * 36864;
        swWp[1 + i] = midswW + (size_t)i * 4096;
        swbp[1 + i] = midswb + (size_t)i * 64;
        sbWp[1 + i] = midsbW + (size_t)i * 4096;
        sbbp[1 + i] = midsbb + (size_t)i * 64;
        Ci[1 + i] = 64; Oi[1 + i] = 64;
        wmo[1 + i] = WM + 13824ull + (size_t)i * 294912ull;
    }
    Wt[11] = c6w; swWp[11] = c6swW; swbp[11] = c6swb; sbWp[11] = c6sbW; sbbp[11] = c6sbb;
    Ci[11] = 64; Oi[11] = 3; wmo[11] = WM + 13824ull + 2949120ull;

    // transpose flags per CONSUMER:
    //  conv3_gemm (i=0), conv64_gemm (mids except 7,9), conv64to3_gemm (i=11) -> [c][k][o] = 1
    //  combine_up_w (i=7, i=9) -> [o][c][k] = 0
    const int trf[12] = {1, 1, 1, 1, 1, 1, 1, 0, 1, 0, 1, 1};

    for (int i = 0; i < 12; ++i) {
        style_fc<<<dim3(8), dim3(64), 0, stream>>>(ws + SV, swWp[i], swbp[i], ws + STY + i * 1024, Ci[i]);
        style_fc<<<dim3(8), dim3(64), 0, stream>>>(ws + SV, sbWp[i], sbbp[i], ws + STY + i * 1024 + 512, Oi[i]);
        modulate<<<dim3(8 * Oi[i]), dim3(64), 0, stream>>>(Wt[i], ws + STY + i * 1024, ws + wmo[i], Oi[i], Ci[i], trf[i]);
    }

    // ==================== main path (grouped at G) ====================
    for (int n0 = 0; n0 < 8; ) {
        int g = (8 - n0 < G) ? (8 - n0) : G;
        const float* xg = x + (size_t)n0 * 196608;
        float* outg = out + (size_t)n0 * 196608;
        #define WN(i)  (ws + wmo[i] + (size_t)n0 * Oi[i] * Ci[i] * 9)
        #define WSTR(i) ((long long)(Oi[i] * Ci[i] * 9))
        #define SBN(i) (ws + STY + (i) * 1024 + 512 + (size_t)n0 * 64)
        // f0 = modconv(x, c0) via conv3_gemm
        conv3_gemm<<<dim3(16 * 16, g), blk, 0, stream>>>(
            xg, WN(0), SBN(0), B + F0, 256, 256, 16, 196608, WSTR(0), 64, PER);
        // f1 down
        blur_down<<<dim3(64 * 17 * 17, g), blk, 0, stream>>>(B + F0, B + SA, 256, 256, 17, 17, PER, PER);
        conv64_gemm<2><<<dim3(8 * 8, g), blk, LDS2, stream>>>(
            B + SA, WN(1), SBN(1), B + D1, 257, 257, 128, 128, 0, 1, 8, PER, WSTR(1), 64, PER);
        conv64_gemm<1><<<dim3(8 * 8, g), blk, LDS1, stream>>>(
            B + D1, WN(2), SBN(2), B + D2, 128, 128, 128, 128, 1, 1, 8, PER, WSTR(2), 64, PER);
        // f2 down
        blur_down<<<dim3(64 * 9 * 9, g), blk, 0, stream>>>(B + D2, B + D3, 128, 128, 9, 9, PER, PER);
        conv64_gemm<2><<<dim3(4 * 4, g), blk, LDS2, stream>>>(
            B + D3, WN(3), SBN(3), B + E1, 129, 129, 64, 64, 0, 1, 4, PER, WSTR(3), 64, PER);
        conv64_gemm<1><<<dim3(4 * 4, g), blk, LDS1, stream>>>(
            B + E1, WN(4), SBN(4), B + E2, 64, 64, 64, 64, 1, 1, 4, PER, WSTR(4), 64, PER);
        // f3 x2
        conv64_gemm<1><<<dim3(4 * 4, g), blk, LDS1, stream>>>(
            B + E2, WN(5), SBN(5), B + E3, 64, 64, 64, 64, 1, 1, 4, PER, WSTR(5), 64, PER);
        conv64_gemm<1><<<dim3(4 * 4, g), blk, LDS1, stream>>>(
            B + E3, WN(6), SBN(6), B + E1, 64, 64, 64, 64, 1, 1, 4, PER, WSTR(6), 64, PER);
        // f4 up (fused)
        combine_up_w<<<dim3(576, g), blk, 0, stream>>>(WN(7), B + G2o, WSTR(7), PER);
        upconv64_gemm<<<dim3(8 * 8, g), blk, LDSU, stream>>>(
            B + E1, B + E2, B + G2o, SBN(7), B + D1, 64, 64, 8, PER, 64, PER);
        conv64_gemm<1><<<dim3(8 * 8, g), blk, LDS1, stream>>>(
            B + D1, WN(8), SBN(8), B + D3, 128, 128, 128, 128, 1, 1, 8, PER, WSTR(8), 64, PER);
        // f5 up
        combine_up_w<<<dim3(576, g), blk, 0, stream>>>(WN(9), B + G2o, WSTR(9), PER);
        upconv64_gemm<<<dim3(16 * 16, g), blk, LDSU, stream>>>(
            B + D3, B + D2, B + G2o, SBN(9), B + SA, 128, 128, 16, PER, 64, PER);
        conv64_gemm<1><<<dim3(16 * 16, g), blk, LDS1, stream>>>(
            B + SA, WN(10), SBN(10), B + SB, 256, 256, 256, 256, 1, 1, 16, PER, WSTR(10), 64, PER);
        // out = modconv(f5+f0, c6, no act) via conv64to3_gemm
        conv64to3_gemm<<<dim3(16 * 16, g), blk, 0, stream>>>(
            B + SB, B + F0, WN(11), SBN(11), outg, 256, 256, 16, PER, WSTR(11), 64, 196608);
        #undef WN
        #undef WSTR
        #undef SBN
        n0 += g;
    }
}

// Round 9
// 5247.040 us; speedup vs baseline: 7.0648x; 1.1236x over previous
//
#include <hip/hip_runtime.h>

#define LRELU(v) ((v) >= 0.f ? (v) : 0.2f * (v))

// ================= implicit-GEMM 3x3 conv, C=64 -> O=64, 16x16 tile =================
template<int S>
__global__ void conv64_gemm(const float* __restrict__ in, const float* __restrict__ Wt,
                            const float* __restrict__ bias, float* __restrict__ out,
                            int Hin, int Win, int Hout, int Wout, int pad, int act, int tilesX,
                            long long inStr, long long wStr, long long bStr, long long outStr)
{
    constexpr int CC  = (S == 1) ? 8 : 4;
    constexpr int TIN = (S == 1) ? 18 : 33;
    constexpr int RS  = (S == 1) ? 20 : 36;
    constexpr int NF4 = (S == 1) ? 3 : 5;
    constexpr int PW  = NF4 * 4;
    extern __shared__ float lds[];
    float* it = lds;
    float* wl = lds + CC * TIN * RS;

    int s = blockIdx.y;
    in   += (size_t)s * inStr;
    Wt   += (size_t)s * wStr;
    bias += (size_t)s * bStr;
    out  += (size_t)s * outStr;

    int b  = blockIdx.x;
    int tx = b % tilesX, ty = b / tilesX;
    int t  = threadIdx.x;
    int og = t >> 5;
    int pg = t & 31;
    int r  = pg >> 1, ch = pg & 1;

    float acc[8][8];
    #pragma unroll
    for (int i = 0; i < 8; ++i)
        #pragma unroll
        for (int j = 0; j < 8; ++j) acc[i][j] = 0.f;

    const int y0 = ty * 16 * S - pad;
    const int x0 = tx * 16 * S - pad;
    const size_t plane = (size_t)Hin * Win;

    for (int c0 = 0; c0 < 64; c0 += CC) {
        __syncthreads();
        {
            const float4* src = (const float4*)(Wt + c0 * 9 * 64);
            float4* dst = (float4*)wl;
            for (int i = t; i < CC * 9 * 16; i += 256) dst[i] = src[i];
        }
        for (int rowi = t; rowi < CC * TIN; rowi += 256) {
            int cc = rowi / TIN, rr = rowi - cc * TIN;
            int iy = y0 + rr;
            float* dst = it + (size_t)rowi * RS;
            const float* srow = in + (size_t)(c0 + cc) * plane + (size_t)iy * Win + x0;
            if ((unsigned)iy < (unsigned)Hin && x0 >= 0 && x0 + RS <= Win) {
                #pragma unroll
                for (int q = 0; q < RS / 4; ++q)
                    ((float4*)dst)[q] = ((const float4*)srow)[q];
            } else {
                for (int cl = 0; cl < TIN; ++cl) {
                    int ix = x0 + cl;
                    float v = 0.f;
                    if ((unsigned)iy < (unsigned)Hin && (unsigned)ix < (unsigned)Win)
                        v = in[(size_t)(c0 + cc) * plane + (size_t)iy * Win + ix];
                    dst[cl] = v;
                }
            }
        }
        __syncthreads();
        for (int cc = 0; cc < CC; ++cc) {
            const float* base = it + cc * TIN * RS;
            #pragma unroll
            for (int ky = 0; ky < 3; ++ky) {
                float p[PW];
                const float* rowp = base + (r * S + ky) * RS + ch * 8 * S;
                #pragma unroll
                for (int q = 0; q < NF4; ++q) {
                    float4 f = *(const float4*)(rowp + q * 4);
                    p[q*4+0] = f.x; p[q*4+1] = f.y; p[q*4+2] = f.z; p[q*4+3] = f.w;
                }
                #pragma unroll
                for (int kx = 0; kx < 3; ++kx) {
                    const float* wp = wl + ((cc * 9) + ky * 3 + kx) * 64 + og * 8;
                    float4 wa = *(const float4*)wp;
                    float4 wb = *(const float4*)(wp + 4);
                    float w8[8] = {wa.x, wa.y, wa.z, wa.w, wb.x, wb.y, wb.z, wb.w};
                    #pragma unroll
                    for (int oi = 0; oi < 8; ++oi)
                        #pragma unroll
                        for (int j = 0; j < 8; ++j)
                            acc[oi][j] += w8[oi] * p[j * S + kx];
                }
            }
        }
    }

    int y  = ty * 16 + r;
    int xb = tx * 16 + ch * 8;
    #pragma unroll
    for (int oi = 0; oi < 8; ++oi) {
        int o = og * 8 + oi;
        float bo = bias[o];
        float v[8];
        #pragma unroll
        for (int j = 0; j < 8; ++j) {
            float a = acc[oi][j] + bo;
            v[j] = act ? LRELU(a) : a;
        }
        float* op = out + ((size_t)o * Hout + y) * Wout + xb;
        *(float4*)op       = make_float4(v[0], v[1], v[2], v[3]);
        *(float4*)(op + 4) = make_float4(v[4], v[5], v[6], v[7]);
    }
}

// ======== implicit-GEMM 3x3 conv, C=64 -> O=64, stride1 pad1, 8x8 tile (small maps) ========
__global__ void conv64_gemm8(const float* __restrict__ in, const float* __restrict__ Wt,
                             const float* __restrict__ bias, float* __restrict__ out,
                             int H, int W, int act, int tilesX,
                             long long inStr, long long wStr, long long bStr, long long outStr)
{
    constexpr int CC = 8, TIN = 10, RS = 12;
    __shared__ float it[CC * TIN * RS];   // 960
    __shared__ float wl[CC * 9 * 64];     // 4608
    int s = blockIdx.y;
    in   += (size_t)s * inStr;
    Wt   += (size_t)s * wStr;
    bias += (size_t)s * bStr;
    out  += (size_t)s * outStr;

    int b  = blockIdx.x;
    int tx = b % tilesX, ty = b / tilesX;
    int t  = threadIdx.x;
    int og = t >> 5, pg = t & 31;
    int r  = pg >> 2, ch = pg & 3;        // row 0..7, col pair 0..3

    float acc[8][2];
    #pragma unroll
    for (int i = 0; i < 8; ++i) { acc[i][0] = 0.f; acc[i][1] = 0.f; }

    const int y0 = ty * 8 - 1, x0 = tx * 8 - 1;
    const size_t plane = (size_t)H * W;

    for (int c0 = 0; c0 < 64; c0 += CC) {
        __syncthreads();
        {
            const float4* src = (const float4*)(Wt + c0 * 9 * 64);
            float4* dst = (float4*)wl;
            for (int i = t; i < CC * 9 * 16; i += 256) dst[i] = src[i];
        }
        for (int rowi = t; rowi < CC * TIN; rowi += 256) {
            int cc = rowi / TIN, rr = rowi - cc * TIN;
            int iy = y0 + rr;
            float* dst = it + rowi * RS;
            const float* srow = in + (size_t)(c0 + cc) * plane + (size_t)iy * W + x0;
            if ((unsigned)iy < (unsigned)H && x0 >= 0 && x0 + RS <= W) {
                #pragma unroll
                for (int q = 0; q < 3; ++q)
                    ((float4*)dst)[q] = ((const float4*)srow)[q];
            } else {
                for (int cl = 0; cl < RS; ++cl) {
                    int ix = x0 + cl;
                    float v = 0.f;
                    if (cl < TIN && (unsigned)iy < (unsigned)H && (unsigned)ix < (unsigned)W)
                        v = in[(size_t)(c0 + cc) * plane + (size_t)iy * W + ix];
                    dst[cl] = v;
                }
            }
        }
        __syncthreads();
        for (int cc = 0; cc < CC; ++cc) {
            const float* base = it + cc * TIN * RS;
            #pragma unroll
            for (int ky = 0; ky < 3; ++ky) {
                const float* rowp = base + (r + ky) * RS + ch * 2;
                float p[4] = {rowp[0], rowp[1], rowp[2], rowp[3]};
                #pragma unroll
                for (int kx = 0; kx < 3; ++kx) {
                    const float* wp = wl + ((cc * 9) + ky * 3 + kx) * 64 + og * 8;
                    float4 wa = *(const float4*)wp;
                    float4 wb = *(const float4*)(wp + 4);
                    float w8[8] = {wa.x, wa.y, wa.z, wa.w, wb.x, wb.y, wb.z, wb.w};
                    #pragma unroll
                    for (int oi = 0; oi < 8; ++oi) {
                        acc[oi][0] += w8[oi] * p[kx];
                        acc[oi][1] += w8[oi] * p[kx + 1];
                    }
                }
            }
        }
    }

    int y = ty * 8 + r, xb = tx * 8 + ch * 2;
    #pragma unroll
    for (int oi = 0; oi < 8; ++oi) {
        int o = og * 8 + oi;
        float bo = bias[o];
        float a0 = acc[oi][0] + bo, a1 = acc[oi][1] + bo;
        if (act) { a0 = LRELU(a0); a1 = LRELU(a1); }
        *(float2*)(out + ((size_t)o * H + y) * W + xb) = make_float2(a0, a1);
    }
}

// ========== implicit-GEMM 3x3 conv, C=3 -> O=64, stride1 pad1 (g0 guide, f0) ==========
__global__ void conv3_gemm(const float* __restrict__ in, const float* __restrict__ Wt,
                           const float* __restrict__ bias, float* __restrict__ out,
                           int H, int W, int tilesX,
                           long long inStr, long long wStr, long long bStr, long long outStr)
{
    constexpr int TIN = 18, RS = 20;
    __shared__ float it[3 * TIN * RS];
    __shared__ float wl[27 * 64];
    int s = blockIdx.y;
    in   += (size_t)s * inStr;
    Wt   += (size_t)s * wStr;
    bias += (size_t)s * bStr;
    out  += (size_t)s * outStr;

    int b  = blockIdx.x;
    int tx = b % tilesX, ty = b / tilesX;
    int t  = threadIdx.x;
    {
        const float4* src = (const float4*)Wt;
        float4* dst = (float4*)wl;
        for (int i = t; i < 27 * 16; i += 256) dst[i] = src[i];
    }
    const int y0 = ty * 16 - 1, x0 = tx * 16 - 1;
    const size_t plane = (size_t)H * W;
    for (int rowi = t; rowi < 3 * TIN; rowi += 256) {
        int cc = rowi / TIN, rr = rowi - cc * TIN;
        int iy = y0 + rr;
        float* dst = it + (size_t)rowi * RS;
        const float* srow = in + (size_t)cc * plane + (size_t)iy * W + x0;
        if ((unsigned)iy < (unsigned)H && x0 >= 0 && x0 + RS <= W) {
            #pragma unroll
            for (int q = 0; q < RS / 4; ++q)
                ((float4*)dst)[q] = ((const float4*)srow)[q];
        } else {
            for (int cl = 0; cl < TIN; ++cl) {
                int ix = x0 + cl;
                float v = 0.f;
                if ((unsigned)iy < (unsigned)H && (unsigned)ix < (unsigned)W)
                    v = in[(size_t)cc * plane + (size_t)iy * W + ix];
                dst[cl] = v;
            }
        }
    }
    __syncthreads();

    int og = t >> 5, pg = t & 31;
    int r  = pg >> 1, ch = pg & 1;
    float acc[8][8];
    #pragma unroll
    for (int i = 0; i < 8; ++i)
        #pragma unroll
        for (int j = 0; j < 8; ++j) acc[i][j] = 0.f;

    for (int c = 0; c < 3; ++c) {
        const float* base = it + c * TIN * RS;
        #pragma unroll
        for (int ky = 0; ky < 3; ++ky) {
            float p[12];
            const float* rowp = base + (r + ky) * RS + ch * 8;
            #pragma unroll
            for (int q = 0; q < 3; ++q) {
                float4 f = *(const float4*)(rowp + q * 4);
                p[q*4+0] = f.x; p[q*4+1] = f.y; p[q*4+2] = f.z; p[q*4+3] = f.w;
            }
            #pragma unroll
            for (int kx = 0; kx < 3; ++kx) {
                const float* wp = wl + ((c * 9) + ky * 3 + kx) * 64 + og * 8;
                float4 wa = *(const float4*)wp;
                float4 wb = *(const float4*)(wp + 4);
                float w8[8] = {wa.x, wa.y, wa.z, wa.w, wb.x, wb.y, wb.z, wb.w};
                #pragma unroll
                for (int oi = 0; oi < 8; ++oi)
                    #pragma unroll
                    for (int j = 0; j < 8; ++j)
                        acc[oi][j] += w8[oi] * p[j + kx];
            }
        }
    }

    int y  = ty * 16 + r;
    int xb = tx * 16 + ch * 8;
    #pragma unroll
    for (int oi = 0; oi < 8; ++oi) {
        int o = og * 8 + oi;
        float bo = bias[o];
        float v[8];
        #pragma unroll
        for (int j = 0; j < 8; ++j) {
            float a = acc[oi][j] + bo;
            v[j] = LRELU(a);
        }
        float* op = out + ((size_t)o * H + y) * W + xb;
        *(float4*)op       = make_float4(v[0], v[1], v[2], v[3]);
        *(float4*)(op + 4) = make_float4(v[4], v[5], v[6], v[7]);
    }
}

// ========== implicit-GEMM 3x3 conv, C=64 -> O=3, (in1+in2), no act (c6) ==========
__global__ void conv64to3_gemm(const float* __restrict__ in, const float* __restrict__ in2,
                               const float* __restrict__ Wt, const float* __restrict__ sb,
                               float* __restrict__ out, int H, int W, int tilesX,
                               long long inStr, long long wStr, long long sbStr, long long outStr)
{
    constexpr int CC = 8, TIN = 18, RS = 20;
    __shared__ float it[CC * TIN * RS];
    __shared__ float wl[CC * 9 * 3];
    int s = blockIdx.y;
    in  += (size_t)s * inStr;
    in2 += (size_t)s * inStr;
    Wt  += (size_t)s * wStr;
    sb  += (size_t)s * sbStr;
    out += (size_t)s * outStr;

    int b  = blockIdx.x;
    int tx = b % tilesX, ty = b / tilesX;
    int t  = threadIdx.x;
    int r  = t >> 4, cl = t & 15;
    const int y0 = ty * 16 - 1, x0 = tx * 16 - 1;
    const size_t plane = (size_t)H * W;

    float acc[3] = {0.f, 0.f, 0.f};

    for (int c0 = 0; c0 < 64; c0 += CC) {
        __syncthreads();
        for (int i = t; i < CC * 9 * 3; i += 256) wl[i] = Wt[c0 * 27 + i];
        for (int rowi = t; rowi < CC * TIN; rowi += 256) {
            int cc = rowi / TIN, rr = rowi - cc * TIN;
            int iy = y0 + rr;
            float* dst = it + (size_t)rowi * RS;
            size_t roff = (size_t)(c0 + cc) * plane + (size_t)iy * W + x0;
            if ((unsigned)iy < (unsigned)H && x0 >= 0 && x0 + RS <= W) {
                #pragma unroll
                for (int q = 0; q < RS / 4; ++q) {
                    float4 a = ((const float4*)(in  + roff))[q];
                    float4 bb = ((const float4*)(in2 + roff))[q];
                    ((float4*)dst)[q] = make_float4(a.x + bb.x, a.y + bb.y, a.z + bb.z, a.w + bb.w);
                }
            } else {
                for (int c2 = 0; c2 < TIN; ++c2) {
                    int ix = x0 + c2;
                    float v = 0.f;
                    if ((unsigned)iy < (unsigned)H && (unsigned)ix < (unsigned)W) {
                        size_t off = (size_t)(c0 + cc) * plane + (size_t)iy * W + ix;
                        v = in[off] + in2[off];
                    }
                    dst[c2] = v;
                }
            }
        }
        __syncthreads();
        for (int cc = 0; cc < CC; ++cc) {
            const float* base = it + cc * TIN * RS;
            #pragma unroll
            for (int ky = 0; ky < 3; ++ky) {
                const float* rowp = base + (r + ky) * RS + cl;
                float p0 = rowp[0], p1 = rowp[1], p2 = rowp[2];
                const float* wr = wl + (cc * 9 + ky * 3) * 3;
                #pragma unroll
                for (int o = 0; o < 3; ++o)
                    acc[o] += wr[o] * p0 + wr[3 + o] * p1 + wr[6 + o] * p2;
            }
        }
    }

    int y = ty * 16 + r, x = tx * 16 + cl;
    #pragma unroll
    for (int o = 0; o < 3; ++o)
        out[((size_t)o * H + y) * W + x] = acc[o] + sb[o];
}

// ===== fused up-conv: tconv(s2,3x3)+blur(4x4,x4/64)+bias+lrelu, coalesced stores =====
// lane map: t = og[0:2] | pxb[3] | rhalf[4:6] | rpar[7]; lane pair t^8 = other parity
__global__ void upconv64_gemm(const float* __restrict__ in, const float* __restrict__ in2,
                              const float* __restrict__ G2, const float* __restrict__ sb,
                              float* __restrict__ out, int Hin, int Win, int tilesX,
                              long long bufStr, long long sbStr, long long outStr)
{
    constexpr int CC = 4;
    constexpr int RS = 12;
    extern __shared__ float lds[];
    float* it = lds;
    float* wl = lds + CC * 10 * RS;

    int s = blockIdx.y;
    in  += (size_t)s * bufStr;
    in2 += (size_t)s * bufStr;
    G2  += (size_t)s * bufStr;
    sb  += (size_t)s * sbStr;
    out += (size_t)s * outStr;

    int b  = blockIdx.x;
    int tx = b % tilesX, ty = b / tilesX;
    int t  = threadIdx.x;
    int og    = t & 7;
    int pxb   = (t >> 3) & 1;
    int rhalf = (t >> 4) & 7;
    int rpar  = t >> 7;
    int r = 2 * rhalf + rpar;
    const int Y0 = ty * 16, X0 = tx * 16;
    const int gy0 = Y0 / 2 - 1;
    const int gx0 = X0 / 2 - 1;
    const size_t plane = (size_t)Hin * Win;

    float acc[8][8];
    #pragma unroll
    for (int i = 0; i < 8; ++i)
        #pragma unroll
        for (int j = 0; j < 8; ++j) acc[i][j] = 0.f;

    for (int c0 = 0; c0 < 64; c0 += CC) {
        __syncthreads();
        {
            const float4* src = (const float4*)(G2 + (size_t)c0 * 2304);
            float4* dst = (float4*)wl;
            for (int i = t; i < CC * 2304 / 4; i += 256) dst[i] = src[i];
        }
        for (int rowi = t; rowi < CC * 10; rowi += 256) {
            int cc = rowi / 10, rr = rowi - cc * 10;
            int gi = gy0 + rr;
            float* dst = it + (size_t)rowi * RS;
            size_t roff = (size_t)(c0 + cc) * plane + (size_t)gi * Win + gx0;
            if ((unsigned)gi < (unsigned)Hin && gx0 >= 0 && gx0 + RS <= Win) {
                #pragma unroll
                for (int qq = 0; qq < 3; ++qq) {
                    float4 a = ((const float4*)(in  + roff))[qq];
                    float4 bb = ((const float4*)(in2 + roff))[qq];
                    ((float4*)dst)[qq] = make_float4(a.x + bb.x, a.y + bb.y, a.z + bb.z, a.w + bb.w);
                }
            } else {
                for (int cl = 0; cl < RS; ++cl) {
                    int gj = gx0 + cl;
                    float v = 0.f;
                    if (cl < 10 && (unsigned)gi < (unsigned)Hin && (unsigned)gj < (unsigned)Win) {
                        size_t off = (size_t)(c0 + cc) * plane + (size_t)gi * Win + gj;
                        v = in[off] + in2[off];
                    }
                    dst[cl] = v;
                }
            }
        }
        __syncthreads();
        for (int cc = 0; cc < CC; ++cc) {
            const float* ib = it + cc * 10 * RS;
            const float* wb = wl + cc * 2304 + (rpar * 2 + pxb) * 576;
            #pragma unroll
            for (int ty2 = 0; ty2 < 3; ++ty2) {
                float p[12];
                const float* rowp = ib + (rhalf + ty2) * RS;
                #pragma unroll
                for (int qq = 0; qq < 3; ++qq) {
                    float4 f = *(const float4*)(rowp + qq * 4);
                    p[qq*4+0] = f.x; p[qq*4+1] = f.y; p[qq*4+2] = f.z; p[qq*4+3] = f.w;
                }
                #pragma unroll
                for (int tx2 = 0; tx2 < 3; ++tx2) {
                    const float* wp = wb + (ty2 * 3 + tx2) * 64 + og * 8;
                    float4 wa = *(const float4*)wp;
                    float4 wv = *(const float4*)(wp + 4);
                    float w8[8] = {wa.x, wa.y, wa.z, wa.w, wv.x, wv.y, wv.z, wv.w};
                    #pragma unroll
                    for (int oi = 0; oi < 8; ++oi)
                        #pragma unroll
                        for (int k = 0; k < 8; ++k)
                            acc[oi][k] += w8[oi] * p[k + tx2];
                }
            }
        }
    }

    const int Hout = 2 * Hin, Wout = 2 * Win;
    int y = Y0 + r;
    #pragma unroll
    for (int oi = 0; oi < 8; ++oi) {
        int o = og * 8 + oi;
        float bo = sb[o];
        float v[8];
        #pragma unroll
        for (int k = 0; k < 8; ++k) {
            float a = acc[oi][k] + bo;
            v[k] = LRELU(a);
        }
        float rcv[4];
        #pragma unroll
        for (int j = 0; j < 4; ++j) {
            float snd = pxb ? v[j] : v[4 + j];
            rcv[j] = __shfl_xor(snd, 8, 64);
        }
        float w0 = pxb ? rcv[0] : v[0];
        float w1 = pxb ? v[4]   : rcv[0];
        float w2 = pxb ? rcv[1] : v[1];
        float w3 = pxb ? v[5]   : rcv[1];
        float w4 = pxb ? rcv[2] : v[2];
        float w5 = pxb ? v[6]   : rcv[2];
        float w6 = pxb ? rcv[3] : v[3];
        float w7 = pxb ? v[7]   : rcv[3];
        float* op = out + ((size_t)o * Hout + y) * Wout + X0 + (pxb ? 8 : 0);
        *(float4*)op       = make_float4(w0, w1, w2, w3);
        *(float4*)(op + 4) = make_float4(w4, w5, w6, w7);
    }
}

// ------- build combined up-weights, batched -------
__global__ void combine_up_w(const float* __restrict__ W, float* __restrict__ G2,
                             long long wStr, long long g2Str)
{
    int s = blockIdx.y;
    W  += (size_t)s * wStr;
    G2 += (size_t)s * g2Str;
    int i = blockIdx.x * 256 + threadIdx.x;
    if (i >= 147456) return;
    int o = i & 63;
    int rest = i >> 6;
    int m = rest % 36, c = rest / 36;
    int txk = m % 3, tyk = (m / 3) % 3;
    int px = (m / 9) & 1, py = m / 18;
    int dy = 2 * tyk - 1 - py, dx = 2 * txk - 1 - px;
    const float K[4] = {1.f, 3.f, 3.f, 1.f};
    const float* wp = W + ((size_t)o * 64 + c) * 9;
    float sacc = 0.f;
    #pragma unroll
    for (int a = 0; a < 3; ++a) {
        int ky = a + dy;
        if ((unsigned)ky >= 4u) continue;
        #pragma unroll
        for (int b2 = 0; b2 < 3; ++b2) {
            int kx = b2 + dx;
            if ((unsigned)kx >= 4u) continue;
            sacc += K[ky] * K[kx] * wp[a * 3 + b2];
        }
    }
    G2[i] = sacc * (1.f / 16.f);
}

// ---------------- 4x4 blur pad=2 (pre-down), batched ----------------
__global__ void blur_down(const float* __restrict__ in, float* __restrict__ out,
                          int H, int W, int tilesX, int tilesY,
                          long long inStr, long long outStr)
{
    int s = blockIdx.y;
    in  += (size_t)s * inStr;
    out += (size_t)s * outStr;
    int Ho = H + 1, Wo = W + 1;
    int bid = blockIdx.x;
    int tx = bid % tilesX; bid /= tilesX;
    int ty = bid % tilesY; bid /= tilesY;
    int p  = bid;
    int x = tx * 16 + (threadIdx.x & 15);
    int y = ty * 16 + (threadIdx.x >> 4);
    if (x >= Wo || y >= Ho) return;
    const float k[4] = {1.f, 3.f, 3.f, 1.f};
    const float* ip = in + (size_t)p * H * W;
    float acc = 0.f;
    #pragma unroll
    for (int ky = 0; ky < 4; ++ky) {
        int iy = y - 2 + ky;
        if ((unsigned)iy >= (unsigned)H) continue;
        float row = 0.f;
        #pragma unroll
        for (int kx = 0; kx < 4; ++kx) {
            int ix = x - 2 + kx;
            if ((unsigned)ix >= (unsigned)W) continue;
            row += ip[(size_t)iy * W + ix] * k[kx];
        }
        acc += row * k[ky];
    }
    out[((size_t)p * Ho + y) * Wo + x] = acc * (1.f / 64.f);
}

// ---------------- avg pool to 1x1 (64 planes), batched ----------------
__global__ void avgpool_hw(const float* __restrict__ in, float* __restrict__ out, int HW,
                           long long inStr, long long outStr)
{
    int s = blockIdx.y;
    in  += (size_t)s * inStr;
    out += (size_t)s * outStr;
    int p = blockIdx.x;
    const float* ip = in + (size_t)p * HW;
    float sum = 0.f;
    for (int i = threadIdx.x; i < HW; i += blockDim.x) sum += ip[i];
    __shared__ float red[256];
    red[threadIdx.x] = sum;
    __syncthreads();
    for (int off = 128; off; off >>= 1) {
        if ((int)threadIdx.x < off) red[threadIdx.x] += red[threadIdx.x + off];
        __syncthreads();
    }
    if (threadIdx.x == 0) out[p] = red[0] / (float)HW;
}

// ---------------- style FC (all 8 samples) ----------------
__global__ void style_fc(const float* __restrict__ s, const float* __restrict__ W,
                         const float* __restrict__ b, float* __restrict__ out, int outdim)
{
    int n = blockIdx.x;
    int i = threadIdx.x;
    if (i >= outdim) return;
    float acc = b[i];
    const float* sn = s + n * 64;
    const float* wi = W + i * 64;
    for (int f = 0; f < 64; ++f) acc += sn[f] * wi[f];
    out[n * 64 + i] = LRELU(acc);
}

// ------- modulate+demodulate (all 8 samples); transpose=1 -> [c][k][o] -------
__global__ void modulate(const float* __restrict__ w, const float* __restrict__ sw,
                         float* __restrict__ wout, int O, int C, int transpose)
{
    int no = blockIdx.x;
    int o = no % O, n = no / O;
    int nw = C * 9;
    int t = threadIdx.x;
    float v[9];
    int cnt = 0;
    float ss = 0.f;
    for (int idx = t; idx < nw; idx += 64) {
        int c = idx / 9;
        float val = w[o * nw + idx] * sw[n * 64 + c];
        v[cnt++] = val;
        ss += val * val;
    }
    #pragma unroll
    for (int off = 32; off; off >>= 1) ss += __shfl_xor(ss, off);
    float d = rsqrtf(ss + 1e-8f);
    cnt = 0;
    for (int idx = t; idx < nw; idx += 64) {
        float val = v[cnt++] * d;
        if (transpose)
            wout[(size_t)n * nw * O + (size_t)idx * O + o] = val;
        else
            wout[(size_t)no * nw + idx] = val;
    }
}

// ------- guide weight transpose -------
__global__ void guide_transpose(const float* __restrict__ grw, float* __restrict__ gt, int total)
{
    int i = blockIdx.x * 256 + threadIdx.x;
    if (i >= total) return;
    int l = i / 36864, rem = i % 36864;
    int idx = rem / 64, o = rem % 64;
    int c = idx / 9, k = idx % 9;
    gt[i] = grw[(((size_t)l * 64 + o) * 64 + c) * 9 + k];
}

// ------- g0 weight transpose -------
__global__ void g0_transpose(const float* __restrict__ g0w, float* __restrict__ gt)
{
    int i = blockIdx.x * 256 + threadIdx.x;
    if (i >= 1728) return;
    int idx = i / 64, o = i % 64;
    int c = idx / 9, k = idx % 9;
    gt[i] = g0w[((size_t)o * 3 + c) * 9 + k];
}

__global__ void fill_sentinel(float* __restrict__ out, int n)
{
    int i = blockIdx.x * 256 + threadIdx.x;
    if (i < n) out[i] = 1.0e9f;
}

extern "C" void kernel_launch(void* const* d_in, const int* in_sizes, int n_in,
                              void* d_out, int out_size, void* d_ws, size_t ws_size,
                              hipStream_t stream)
{
    const float* x     = (const float*)d_in[0];
    const float* ref   = (const float*)d_in[1];
    const float* g0w   = (const float*)d_in[2];
    const float* g0b   = (const float*)d_in[3];
    const float* grw   = (const float*)d_in[4];
    const float* grb   = (const float*)d_in[5];
    const float* c0w   = (const float*)d_in[6];
    const float* c0swW = (const float*)d_in[7];
    const float* c0swb = (const float*)d_in[8];
    const float* c0sbW = (const float*)d_in[9];
    const float* c0sbb = (const float*)d_in[10];
    const float* midw  = (const float*)d_in[11];
    const float* midswW= (const float*)d_in[12];
    const float* midswb= (const float*)d_in[13];
    const float* midsbW= (const float*)d_in[14];
    const float* midsbb= (const float*)d_in[15];
    const float* c6w   = (const float*)d_in[16];
    const float* c6swW = (const float*)d_in[17];
    const float* c6swb = (const float*)d_in[18];
    const float* c6sbW = (const float*)d_in[19];
    const float* c6sbb = (const float*)d_in[20];
    float* out = (float*)d_out;
    float* ws  = (float*)d_ws;

    // -------- shared region (floats) --------
    const size_t SV  = 0;
    const size_t STY = 512;
    const size_t WM  = 12800;
    const size_t GT  = 2989568;
    const size_t G0T = 3137024;
    const size_t BUF = 3138816;

    // -------- main-path per-sample slot offsets --------
    const size_t F0 = 0;
    const size_t SA = 4194304;
    const size_t SB = 8421440;
    const size_t D1 = 12615744;
    const size_t D2 = 13664320;
    const size_t D3 = 14712896;
    const size_t E1 = 15777920;
    const size_t E2 = 16040064;
    const size_t E3 = 16302208;
    const size_t G2o = 16564352;
    const long long PER = 16711808ll;

    // -------- guide-phase per-sample slot offsets --------
    const size_t gSA = 0;
    const size_t gD1 = 4194304;
    const size_t gD2 = 5242880;
    const size_t gE1 = 6291456;
    const size_t gE2 = 6553600;
    const long long GPER = 6815744ll;

    int G = 0, GG = 0;
    for (int g = 8; g >= 1; --g)
        if ((BUF + (size_t)g * PER) * sizeof(float) <= ws_size) { G = g; break; }
    for (int g = 8; g >= 1; --g)
        if ((BUF + (size_t)g * GPER) * sizeof(float) <= ws_size) { GG = g; break; }
    if (!G || !GG) {
        fill_sentinel<<<dim3((out_size + 255) / 256), dim3(256), 0, stream>>>(out, out_size);
        return;
    }

    dim3 blk(256);
    const int LDS1 = 29952;
    const int LDS2 = 28224;
    const int LDSU = 38784;

    float* B = ws + BUF;

    guide_transpose<<<dim3(147456 / 256), blk, 0, stream>>>(grw, ws + GT, 147456);
    g0_transpose<<<dim3(7), blk, 0, stream>>>(g0w, ws + G0T);

    // ==================== guide net ====================
    for (int n0 = 0; n0 < 8; ) {
        int g = (8 - n0 < GG) ? (8 - n0) : GG;
        const float* refg = ref + (size_t)n0 * 196608;
        conv3_gemm<<<dim3(16 * 16, g), blk, 0, stream>>>(
            refg, ws + G0T, g0b, B + gSA, 256, 256, 16, 196608, 0, 0, GPER);
        conv64_gemm<2><<<dim3(8 * 8, g), blk, LDS2, stream>>>(
            B + gSA, ws + GT, grb, B + gD1, 256, 256, 128, 128, 1, 1, 8, GPER, 0, 0, GPER);
        conv64_gemm<1><<<dim3(8 * 8, g), blk, LDS1, stream>>>(
            B + gD1, ws + GT + 36864, grb + 64, B + gD2, 128, 128, 128, 128, 1, 1, 8, GPER, 0, 0, GPER);
        conv64_gemm<2><<<dim3(4 * 4, g), blk, LDS2, stream>>>(
            B + gD2, ws + GT + 73728, grb + 128, B + gE1, 128, 128, 64, 64, 1, 1, 4, GPER, 0, 0, GPER);
        conv64_gemm8<<<dim3(8 * 8, g), blk, 0, stream>>>(
            B + gE1, ws + GT + 110592, grb + 192, B + gE2, 64, 64, 0, 8, GPER, 0, 0, GPER);
        avgpool_hw<<<dim3(64, g), blk, 0, stream>>>(B + gE2, ws + SV + (size_t)n0 * 64, 4096, GPER, 64);
        n0 += g;
    }

    // ==================== styles + modulated weights ====================
    const float* Wt[12];  const float* swWp[12]; const float* swbp[12];
    const float* sbWp[12]; const float* sbbp[12];
    int Ci[12], Oi[12];
    size_t wmo[12];
    Wt[0] = c0w; swWp[0] = c0swW; swbp[0] = c0swb; sbWp[0] = c0sbW; sbbp[0] = c0sbb;
    Ci[0] = 3; Oi[0] = 64; wmo[0] = WM;
    for (int i = 0; i < 10; ++i) {
        Wt[1 + i]   = midw   + (size_t)i * 36864;
        swWp[1 + i] = midswW + (size_t)i * 4096;
        swbp[1 + i] = midswb + (size_t)i * 64;
        sbWp[1 + i] = midsbW + (size_t)i * 4096;
        sbbp[1 + i] = midsbb + (size_t)i * 64;
        Ci[1 + i] = 64; Oi[1 + i] = 64;
        wmo[1 + i] = WM + 13824ull + (size_t)i * 294912ull;
    }
    Wt[11] = c6w; swWp[11] = c6swW; swbp[11] = c6swb; sbWp[11] = c6sbW; sbbp[11] = c6sbb;
    Ci[11] = 64; Oi[11] = 3; wmo[11] = WM + 13824ull + 2949120ull;

    const int trf[12] = {1, 1, 1, 1, 1, 1, 1, 0, 1, 0, 1, 1};

    for (int i = 0; i < 12; ++i) {
        style_fc<<<dim3(8), dim3(64), 0, stream>>>(ws + SV, swWp[i], swbp[i], ws + STY + i * 1024, Ci[i]);
        style_fc<<<dim3(8), dim3(64), 0, stream>>>(ws + SV, sbWp[i], sbbp[i], ws + STY + i * 1024 + 512, Oi[i]);
        modulate<<<dim3(8 * Oi[i]), dim3(64), 0, stream>>>(Wt[i], ws + STY + i * 1024, ws + wmo[i], Oi[i], Ci[i], trf[i]);
    }

    // ==================== main path ====================
    for (int n0 = 0; n0 < 8; ) {
        int g = (8 - n0 < G) ? (8 - n0) : G;
        const float* xg = x + (size_t)n0 * 196608;
        float* outg = out + (size_t)n0 * 196608;
        #define WN(i)  (ws + wmo[i] + (size_t)n0 * Oi[i] * Ci[i] * 9)
        #define WSTR(i) ((long long)(Oi[i] * Ci[i] * 9))
        #define SBN(i) (ws + STY + (i) * 1024 + 512 + (size_t)n0 * 64)
        // f0
        conv3_gemm<<<dim3(16 * 16, g), blk, 0, stream>>>(
            xg, WN(0), SBN(0), B + F0, 256, 256, 16, 196608, WSTR(0), 64, PER);
        // f1 down
        blur_down<<<dim3(64 * 17 * 17, g), blk, 0, stream>>>(B + F0, B + SA, 256, 256, 17, 17, PER, PER);
        conv64_gemm<2><<<dim3(8 * 8, g), blk, LDS2, stream>>>(
            B + SA, WN(1), SBN(1), B + D1, 257, 257, 128, 128, 0, 1, 8, PER, WSTR(1), 64, PER);
        conv64_gemm8<<<dim3(16 * 16, g), blk, 0, stream>>>(
            B + D1, WN(2), SBN(2), B + D2, 128, 128, 1, 16, PER, WSTR(2), 64, PER);
        // f2 down
        blur_down<<<dim3(64 * 9 * 9, g), blk, 0, stream>>>(B + D2, B + D3, 128, 128, 9, 9, PER, PER);
        conv64_gemm<2><<<dim3(4 * 4, g), blk, LDS2, stream>>>(
            B + D3, WN(3), SBN(3), B + E1, 129, 129, 64, 64, 0, 1, 4, PER, WSTR(3), 64, PER);
        conv64_gemm8<<<dim3(8 * 8, g), blk, 0, stream>>>(
            B + E1, WN(4), SBN(4), B + E2, 64, 64, 1, 8, PER, WSTR(4), 64, PER);
        // f3 x2
        conv64_gemm8<<<dim3(8 * 8, g), blk, 0, stream>>>(
            B + E2, WN(5), SBN(5), B + E3, 64, 64, 1, 8, PER, WSTR(5), 64, PER);
        conv64_gemm8<<<dim3(8 * 8, g), blk, 0, stream>>>(
            B + E3, WN(6), SBN(6), B + E1, 64, 64, 1, 8, PER, WSTR(6), 64, PER);
        // f4 up (fused)
        combine_up_w<<<dim3(576, g), blk, 0, stream>>>(WN(7), B + G2o, WSTR(7), PER);
        upconv64_gemm<<<dim3(8 * 8, g), blk, LDSU, stream>>>(
            B + E1, B + E2, B + G2o, SBN(7), B + D1, 64, 64, 8, PER, 64, PER);
        conv64_gemm8<<<dim3(16 * 16, g), blk, 0, stream>>>(
            B + D1, WN(8), SBN(8), B + D3, 128, 128, 1, 16, PER, WSTR(8), 64, PER);
        // f5 up
        combine_up_w<<<dim3(576, g), blk, 0, stream>>>(WN(9), B + G2o, WSTR(9), PER);
        upconv64_gemm<<<dim3(16 * 16, g), blk, LDSU, stream>>>(
            B + D3, B + D2, B + G2o, SBN(9), B + SA, 128, 128, 16, PER, 64, PER);
        conv64_gemm<1><<<dim3(16 * 16, g), blk, LDS1, stream>>>(
            B + SA, WN(10), SBN(10), B + SB, 256, 256, 256, 256, 1, 1, 16, PER, WSTR(10), 64, PER);
        // c6
        conv64to3_gemm<<<dim3(16 * 16, g), blk, 0, stream>>>(
            B + SB, B + F0, WN(11), SBN(11), outg, 256, 256, 16, PER, WSTR(11), 64, 196608);
        #undef WN
        #undef WSTR
        #undef SBN
        n0 += g;
    }
}

// Round 10
// 4600.290 us; speedup vs baseline: 8.0580x; 1.1406x over previous
//
#include <hip/hip_runtime.h>

#define LRELU(v) ((v) >= 0.f ? (v) : 0.2f * (v))

// ================= implicit-GEMM 3x3 conv, C=64 -> O=64, 16x16 tile =================
template<int S>
__global__ void conv64_gemm(const float* __restrict__ in, const float* __restrict__ Wt,
                            const float* __restrict__ bias, float* __restrict__ out,
                            int Hin, int Win, int Hout, int Wout, int pad, int act, int tilesX,
                            long long inStr, long long wStr, long long bStr, long long outStr)
{
    constexpr int CC  = (S == 1) ? 8 : 4;
    constexpr int TIN = (S == 1) ? 18 : 33;
    constexpr int RS  = (S == 1) ? 20 : 36;
    constexpr int NF4 = (S == 1) ? 3 : 5;
    constexpr int PW  = NF4 * 4;
    extern __shared__ float lds[];
    float* it = lds;
    float* wl = lds + CC * TIN * RS;

    int s = blockIdx.y;
    in   += (size_t)s * inStr;
    Wt   += (size_t)s * wStr;
    bias += (size_t)s * bStr;
    out  += (size_t)s * outStr;

    int b  = blockIdx.x;
    int tx = b % tilesX, ty = b / tilesX;
    int t  = threadIdx.x;
    int og = t >> 5;
    int pg = t & 31;
    int r  = pg >> 1, ch = pg & 1;

    float acc[8][8];
    #pragma unroll
    for (int i = 0; i < 8; ++i)
        #pragma unroll
        for (int j = 0; j < 8; ++j) acc[i][j] = 0.f;

    const int y0 = ty * 16 * S - pad;
    const int x0 = tx * 16 * S - pad;
    const size_t plane = (size_t)Hin * Win;

    for (int c0 = 0; c0 < 64; c0 += CC) {
        __syncthreads();
        {
            const float4* src = (const float4*)(Wt + c0 * 9 * 64);
            float4* dst = (float4*)wl;
            for (int i = t; i < CC * 9 * 16; i += 256) dst[i] = src[i];
        }
        for (int rowi = t; rowi < CC * TIN; rowi += 256) {
            int cc = rowi / TIN, rr = rowi - cc * TIN;
            int iy = y0 + rr;
            float* dst = it + (size_t)rowi * RS;
            const float* srow = in + (size_t)(c0 + cc) * plane + (size_t)iy * Win + x0;
            if ((unsigned)iy < (unsigned)Hin && x0 >= 0 && x0 + RS <= Win) {
                #pragma unroll
                for (int q = 0; q < RS / 4; ++q)
                    ((float4*)dst)[q] = ((const float4*)srow)[q];
            } else {
                for (int cl = 0; cl < TIN; ++cl) {
                    int ix = x0 + cl;
                    float v = 0.f;
                    if ((unsigned)iy < (unsigned)Hin && (unsigned)ix < (unsigned)Win)
                        v = in[(size_t)(c0 + cc) * plane + (size_t)iy * Win + ix];
                    dst[cl] = v;
                }
            }
        }
        __syncthreads();
        for (int cc = 0; cc < CC; ++cc) {
            const float* base = it + cc * TIN * RS;
            #pragma unroll
            for (int ky = 0; ky < 3; ++ky) {
                float p[PW];
                const float* rowp = base + (r * S + ky) * RS + ch * 8 * S;
                #pragma unroll
                for (int q = 0; q < NF4; ++q) {
                    float4 f = *(const float4*)(rowp + q * 4);
                    p[q*4+0] = f.x; p[q*4+1] = f.y; p[q*4+2] = f.z; p[q*4+3] = f.w;
                }
                #pragma unroll
                for (int kx = 0; kx < 3; ++kx) {
                    const float* wp = wl + ((cc * 9) + ky * 3 + kx) * 64 + og * 8;
                    float4 wa = *(const float4*)wp;
                    float4 wb = *(const float4*)(wp + 4);
                    float w8[8] = {wa.x, wa.y, wa.z, wa.w, wb.x, wb.y, wb.z, wb.w};
                    #pragma unroll
                    for (int oi = 0; oi < 8; ++oi)
                        #pragma unroll
                        for (int j = 0; j < 8; ++j)
                            acc[oi][j] += w8[oi] * p[j * S + kx];
                }
            }
        }
    }

    int y  = ty * 16 + r;
    int xb = tx * 16 + ch * 8;
    #pragma unroll
    for (int oi = 0; oi < 8; ++oi) {
        int o = og * 8 + oi;
        float bo = bias[o];
        float v[8];
        #pragma unroll
        for (int j = 0; j < 8; ++j) {
            float a = acc[oi][j] + bo;
            v[j] = act ? LRELU(a) : a;
        }
        float* op = out + ((size_t)o * Hout + y) * Wout + xb;
        *(float4*)op       = make_float4(v[0], v[1], v[2], v[3]);
        *(float4*)(op + 4) = make_float4(v[4], v[5], v[6], v[7]);
    }
}

// ======== implicit-GEMM 3x3 conv, C=64 -> O=64, stride1 pad1, 8x8 tile (small maps) ========
__global__ void conv64_gemm8(const float* __restrict__ in, const float* __restrict__ Wt,
                             const float* __restrict__ bias, float* __restrict__ out,
                             int H, int W, int act, int tilesX,
                             long long inStr, long long wStr, long long bStr, long long outStr)
{
    constexpr int CC = 8, TIN = 10, RS = 12;
    __shared__ float it[CC * TIN * RS];
    __shared__ float wl[CC * 9 * 64];
    int s = blockIdx.y;
    in   += (size_t)s * inStr;
    Wt   += (size_t)s * wStr;
    bias += (size_t)s * bStr;
    out  += (size_t)s * outStr;

    int b  = blockIdx.x;
    int tx = b % tilesX, ty = b / tilesX;
    int t  = threadIdx.x;
    int og = t >> 5, pg = t & 31;
    int r  = pg >> 2, ch = pg & 3;

    float acc[8][2];
    #pragma unroll
    for (int i = 0; i < 8; ++i) { acc[i][0] = 0.f; acc[i][1] = 0.f; }

    const int y0 = ty * 8 - 1, x0 = tx * 8 - 1;
    const size_t plane = (size_t)H * W;

    for (int c0 = 0; c0 < 64; c0 += CC) {
        __syncthreads();
        {
            const float4* src = (const float4*)(Wt + c0 * 9 * 64);
            float4* dst = (float4*)wl;
            for (int i = t; i < CC * 9 * 16; i += 256) dst[i] = src[i];
        }
        for (int rowi = t; rowi < CC * TIN; rowi += 256) {
            int cc = rowi / TIN, rr = rowi - cc * TIN;
            int iy = y0 + rr;
            float* dst = it + rowi * RS;
            const float* srow = in + (size_t)(c0 + cc) * plane + (size_t)iy * W + x0;
            if ((unsigned)iy < (unsigned)H && x0 >= 0 && x0 + RS <= W) {
                #pragma unroll
                for (int q = 0; q < 3; ++q)
                    ((float4*)dst)[q] = ((const float4*)srow)[q];
            } else {
                for (int cl = 0; cl < RS; ++cl) {
                    int ix = x0 + cl;
                    float v = 0.f;
                    if (cl < TIN && (unsigned)iy < (unsigned)H && (unsigned)ix < (unsigned)W)
                        v = in[(size_t)(c0 + cc) * plane + (size_t)iy * W + ix];
                    dst[cl] = v;
                }
            }
        }
        __syncthreads();
        for (int cc = 0; cc < CC; ++cc) {
            const float* base = it + cc * TIN * RS;
            #pragma unroll
            for (int ky = 0; ky < 3; ++ky) {
                const float* rowp = base + (r + ky) * RS + ch * 2;
                float p[4] = {rowp[0], rowp[1], rowp[2], rowp[3]};
                #pragma unroll
                for (int kx = 0; kx < 3; ++kx) {
                    const float* wp = wl + ((cc * 9) + ky * 3 + kx) * 64 + og * 8;
                    float4 wa = *(const float4*)wp;
                    float4 wb = *(const float4*)(wp + 4);
                    float w8[8] = {wa.x, wa.y, wa.z, wa.w, wb.x, wb.y, wb.z, wb.w};
                    #pragma unroll
                    for (int oi = 0; oi < 8; ++oi) {
                        acc[oi][0] += w8[oi] * p[kx];
                        acc[oi][1] += w8[oi] * p[kx + 1];
                    }
                }
            }
        }
    }

    int y = ty * 8 + r, xb = tx * 8 + ch * 2;
    #pragma unroll
    for (int oi = 0; oi < 8; ++oi) {
        int o = og * 8 + oi;
        float bo = bias[o];
        float a0 = acc[oi][0] + bo, a1 = acc[oi][1] + bo;
        if (act) { a0 = LRELU(a0); a1 = LRELU(a1); }
        *(float2*)(out + ((size_t)o * H + y) * W + xb) = make_float2(a0, a1);
    }
}

// ========== implicit-GEMM 3x3 conv, C=3 -> O=64, stride1 pad1 (g0 guide, f0) ==========
__global__ void conv3_gemm(const float* __restrict__ in, const float* __restrict__ Wt,
                           const float* __restrict__ bias, float* __restrict__ out,
                           int H, int W, int tilesX,
                           long long inStr, long long wStr, long long bStr, long long outStr)
{
    constexpr int TIN = 18, RS = 20;
    __shared__ float it[3 * TIN * RS];
    __shared__ float wl[27 * 64];
    int s = blockIdx.y;
    in   += (size_t)s * inStr;
    Wt   += (size_t)s * wStr;
    bias += (size_t)s * bStr;
    out  += (size_t)s * outStr;

    int b  = blockIdx.x;
    int tx = b % tilesX, ty = b / tilesX;
    int t  = threadIdx.x;
    {
        const float4* src = (const float4*)Wt;
        float4* dst = (float4*)wl;
        for (int i = t; i < 27 * 16; i += 256) dst[i] = src[i];
    }
    const int y0 = ty * 16 - 1, x0 = tx * 16 - 1;
    const size_t plane = (size_t)H * W;
    for (int rowi = t; rowi < 3 * TIN; rowi += 256) {
        int cc = rowi / TIN, rr = rowi - cc * TIN;
        int iy = y0 + rr;
        float* dst = it + (size_t)rowi * RS;
        const float* srow = in + (size_t)cc * plane + (size_t)iy * W + x0;
        if ((unsigned)iy < (unsigned)H && x0 >= 0 && x0 + RS <= W) {
            #pragma unroll
            for (int q = 0; q < RS / 4; ++q)
                ((float4*)dst)[q] = ((const float4*)srow)[q];
        } else {
            for (int cl = 0; cl < TIN; ++cl) {
                int ix = x0 + cl;
                float v = 0.f;
                if ((unsigned)iy < (unsigned)H && (unsigned)ix < (unsigned)W)
                    v = in[(size_t)cc * plane + (size_t)iy * W + ix];
                dst[cl] = v;
            }
        }
    }
    __syncthreads();

    int og = t >> 5, pg = t & 31;
    int r  = pg >> 1, ch = pg & 1;
    float acc[8][8];
    #pragma unroll
    for (int i = 0; i < 8; ++i)
        #pragma unroll
        for (int j = 0; j < 8; ++j) acc[i][j] = 0.f;

    for (int c = 0; c < 3; ++c) {
        const float* base = it + c * TIN * RS;
        #pragma unroll
        for (int ky = 0; ky < 3; ++ky) {
            float p[12];
            const float* rowp = base + (r + ky) * RS + ch * 8;
            #pragma unroll
            for (int q = 0; q < 3; ++q) {
                float4 f = *(const float4*)(rowp + q * 4);
                p[q*4+0] = f.x; p[q*4+1] = f.y; p[q*4+2] = f.z; p[q*4+3] = f.w;
            }
            #pragma unroll
            for (int kx = 0; kx < 3; ++kx) {
                const float* wp = wl + ((c * 9) + ky * 3 + kx) * 64 + og * 8;
                float4 wa = *(const float4*)wp;
                float4 wb = *(const float4*)(wp + 4);
                float w8[8] = {wa.x, wa.y, wa.z, wa.w, wb.x, wb.y, wb.z, wb.w};
                #pragma unroll
                for (int oi = 0; oi < 8; ++oi)
                    #pragma unroll
                    for (int j = 0; j < 8; ++j)
                        acc[oi][j] += w8[oi] * p[j + kx];
            }
        }
    }

    int y  = ty * 16 + r;
    int xb = tx * 16 + ch * 8;
    #pragma unroll
    for (int oi = 0; oi < 8; ++oi) {
        int o = og * 8 + oi;
        float bo = bias[o];
        float v[8];
        #pragma unroll
        for (int j = 0; j < 8; ++j) {
            float a = acc[oi][j] + bo;
            v[j] = LRELU(a);
        }
        float* op = out + ((size_t)o * H + y) * W + xb;
        *(float4*)op       = make_float4(v[0], v[1], v[2], v[3]);
        *(float4*)(op + 4) = make_float4(v[4], v[5], v[6], v[7]);
    }
}

// ========== implicit-GEMM 3x3 conv, C=64 -> O=3, (in1+in2), no act (c6) ==========
__global__ void conv64to3_gemm(const float* __restrict__ in, const float* __restrict__ in2,
                               const float* __restrict__ Wt, const float* __restrict__ sb,
                               float* __restrict__ out, int H, int W, int tilesX,
                               long long inStr, long long wStr, long long sbStr, long long outStr)
{
    constexpr int CC = 8, TIN = 18, RS = 20;
    __shared__ float it[CC * TIN * RS];
    __shared__ float wl[CC * 9 * 3];
    int s = blockIdx.y;
    in  += (size_t)s * inStr;
    in2 += (size_t)s * inStr;
    Wt  += (size_t)s * wStr;
    sb  += (size_t)s * sbStr;
    out += (size_t)s * outStr;

    int b  = blockIdx.x;
    int tx = b % tilesX, ty = b / tilesX;
    int t  = threadIdx.x;
    int r  = t >> 4, cl = t & 15;
    const int y0 = ty * 16 - 1, x0 = tx * 16 - 1;
    const size_t plane = (size_t)H * W;

    float acc[3] = {0.f, 0.f, 0.f};

    for (int c0 = 0; c0 < 64; c0 += CC) {
        __syncthreads();
        for (int i = t; i < CC * 9 * 3; i += 256) wl[i] = Wt[c0 * 27 + i];
        for (int rowi = t; rowi < CC * TIN; rowi += 256) {
            int cc = rowi / TIN, rr = rowi - cc * TIN;
            int iy = y0 + rr;
            float* dst = it + (size_t)rowi * RS;
            size_t roff = (size_t)(c0 + cc) * plane + (size_t)iy * W + x0;
            if ((unsigned)iy < (unsigned)H && x0 >= 0 && x0 + RS <= W) {
                #pragma unroll
                for (int q = 0; q < RS / 4; ++q) {
                    float4 a = ((const float4*)(in  + roff))[q];
                    float4 bb = ((const float4*)(in2 + roff))[q];
                    ((float4*)dst)[q] = make_float4(a.x + bb.x, a.y + bb.y, a.z + bb.z, a.w + bb.w);
                }
            } else {
                for (int c2 = 0; c2 < TIN; ++c2) {
                    int ix = x0 + c2;
                    float v = 0.f;
                    if ((unsigned)iy < (unsigned)H && (unsigned)ix < (unsigned)W) {
                        size_t off = (size_t)(c0 + cc) * plane + (size_t)iy * W + ix;
                        v = in[off] + in2[off];
                    }
                    dst[c2] = v;
                }
            }
        }
        __syncthreads();
        for (int cc = 0; cc < CC; ++cc) {
            const float* base = it + cc * TIN * RS;
            #pragma unroll
            for (int ky = 0; ky < 3; ++ky) {
                const float* rowp = base + (r + ky) * RS + cl;
                float p0 = rowp[0], p1 = rowp[1], p2 = rowp[2];
                const float* wr = wl + (cc * 9 + ky * 3) * 3;
                #pragma unroll
                for (int o = 0; o < 3; ++o)
                    acc[o] += wr[o] * p0 + wr[3 + o] * p1 + wr[6 + o] * p2;
            }
        }
    }

    int y = ty * 16 + r, x = tx * 16 + cl;
    #pragma unroll
    for (int o = 0; o < 3; ++o)
        out[((size_t)o * H + y) * W + x] = acc[o] + sb[o];
}

// ===== fused up-conv: tconv(s2,3x3)+blur(4x4,x4/64)+bias+lrelu, coalesced + conflict-free =====
// lane map: t = og[0:2] | pxb[3] | rhalf[4:6] | rpar[7]; pair t^8 = other parity.
// G2 global layout [c][tap(9)][parity(4)][o(64)]; LDS parity stride padded to 68 floats.
__global__ void upconv64_gemm(const float* __restrict__ in, const float* __restrict__ in2,
                              const float* __restrict__ G2, const float* __restrict__ sb,
                              float* __restrict__ out, int Hin, int Win, int tilesX,
                              long long bufStr, long long sbStr, long long outStr)
{
    constexpr int CC = 4;
    constexpr int RS = 12;
    constexpr int PSTR = 68;                  // padded parity stride (floats)
    extern __shared__ float lds[];
    float* it = lds;                          // [CC][10][RS] = 480
    float* wl = lds + CC * 10 * RS;           // [CC][9][4][PSTR] = CC*2448

    int s = blockIdx.y;
    in  += (size_t)s * bufStr;
    in2 += (size_t)s * bufStr;
    G2  += (size_t)s * bufStr;
    sb  += (size_t)s * sbStr;
    out += (size_t)s * outStr;

    int b  = blockIdx.x;
    int tx = b % tilesX, ty = b / tilesX;
    int t  = threadIdx.x;
    int og    = t & 7;
    int pxb   = (t >> 3) & 1;
    int rhalf = (t >> 4) & 7;
    int rpar  = t >> 7;
    int r = 2 * rhalf + rpar;
    const int Y0 = ty * 16, X0 = tx * 16;
    const int gy0 = Y0 / 2 - 1;
    const int gx0 = X0 / 2 - 1;
    const size_t plane = (size_t)Hin * Win;

    float acc[8][8];
    #pragma unroll
    for (int i = 0; i < 8; ++i)
        #pragma unroll
        for (int j = 0; j < 8; ++j) acc[i][j] = 0.f;

    for (int c0 = 0; c0 < 64; c0 += CC) {
        __syncthreads();
        {
            // stage [CC][36] rows of 64 floats into stride-68 rows
            const float4* src = (const float4*)(G2 + (size_t)c0 * 2304);
            for (int i = t; i < CC * 36 * 16; i += 256) {
                int row = i >> 4, q = i & 15;
                ((float4*)(wl + row * PSTR))[q] = src[i];
            }
        }
        for (int rowi = t; rowi < CC * 10; rowi += 256) {
            int cc = rowi / 10, rr = rowi - cc * 10;
            int gi = gy0 + rr;
            float* dst = it + (size_t)rowi * RS;
            size_t roff = (size_t)(c0 + cc) * plane + (size_t)gi * Win + gx0;
            if ((unsigned)gi < (unsigned)Hin && gx0 >= 0 && gx0 + RS <= Win) {
                #pragma unroll
                for (int qq = 0; qq < 3; ++qq) {
                    float4 a = ((const float4*)(in  + roff))[qq];
                    float4 bb = ((const float4*)(in2 + roff))[qq];
                    ((float4*)dst)[qq] = make_float4(a.x + bb.x, a.y + bb.y, a.z + bb.z, a.w + bb.w);
                }
            } else {
                for (int cl = 0; cl < RS; ++cl) {
                    int gj = gx0 + cl;
                    float v = 0.f;
                    if (cl < 10 && (unsigned)gi < (unsigned)Hin && (unsigned)gj < (unsigned)Win) {
                        size_t off = (size_t)(c0 + cc) * plane + (size_t)gi * Win + gj;
                        v = in[off] + in2[off];
                    }
                    dst[cl] = v;
                }
            }
        }
        __syncthreads();
        for (int cc = 0; cc < CC; ++cc) {
            const float* ib = it + cc * 10 * RS;
            const float* wcb = wl + cc * (36 * PSTR) + (rpar * 2 + pxb) * PSTR;
            #pragma unroll
            for (int ty2 = 0; ty2 < 3; ++ty2) {
                float p[12];
                const float* rowp = ib + (rhalf + ty2) * RS;
                #pragma unroll
                for (int qq = 0; qq < 3; ++qq) {
                    float4 f = *(const float4*)(rowp + qq * 4);
                    p[qq*4+0] = f.x; p[qq*4+1] = f.y; p[qq*4+2] = f.z; p[qq*4+3] = f.w;
                }
                #pragma unroll
                for (int tx2 = 0; tx2 < 3; ++tx2) {
                    const float* wp = wcb + (ty2 * 3 + tx2) * (4 * PSTR) + og * 8;
                    float4 wa = *(const float4*)wp;
                    float4 wv = *(const float4*)(wp + 4);
                    float w8[8] = {wa.x, wa.y, wa.z, wa.w, wv.x, wv.y, wv.z, wv.w};
                    #pragma unroll
                    for (int oi = 0; oi < 8; ++oi)
                        #pragma unroll
                        for (int k = 0; k < 8; ++k)
                            acc[oi][k] += w8[oi] * p[k + tx2];
                }
            }
        }
    }

    const int Hout = 2 * Hin, Wout = 2 * Win;
    int y = Y0 + r;
    #pragma unroll
    for (int oi = 0; oi < 8; ++oi) {
        int o = og * 8 + oi;
        float bo = sb[o];
        float v[8];
        #pragma unroll
        for (int k = 0; k < 8; ++k) {
            float a = acc[oi][k] + bo;
            v[k] = LRELU(a);
        }
        float rcv[4];
        #pragma unroll
        for (int j = 0; j < 4; ++j) {
            float snd = pxb ? v[j] : v[4 + j];
            rcv[j] = __shfl_xor(snd, 8, 64);
        }
        float w0 = pxb ? rcv[0] : v[0];
        float w1 = pxb ? v[4]   : rcv[0];
        float w2 = pxb ? rcv[1] : v[1];
        float w3 = pxb ? v[5]   : rcv[1];
        float w4 = pxb ? rcv[2] : v[2];
        float w5 = pxb ? v[6]   : rcv[2];
        float w6 = pxb ? rcv[3] : v[3];
        float w7 = pxb ? v[7]   : rcv[3];
        float* op = out + ((size_t)o * Hout + y) * Wout + X0 + (pxb ? 8 : 0);
        *(float4*)op       = make_float4(w0, w1, w2, w3);
        *(float4*)(op + 4) = make_float4(w4, w5, w6, w7);
    }
}

// ------- build combined up-weights, layout [c][tap][parity][o] -------
__global__ void combine_up_w(const float* __restrict__ W, float* __restrict__ G2,
                             long long wStr, long long g2Str)
{
    int s = blockIdx.y;
    W  += (size_t)s * wStr;
    G2 += (size_t)s * g2Str;
    int i = blockIdx.x * 256 + threadIdx.x;
    if (i >= 147456) return;
    int o = i & 63;
    int rest = i >> 6;            // (c*9 + k)*4 + p
    int p4 = rest & 3;
    int k9 = (rest >> 2) % 9;
    int c  = (rest >> 2) / 9;
    int py = p4 >> 1, px = p4 & 1;
    int tyk = k9 / 3, txk = k9 % 3;
    int dy = 2 * tyk - 1 - py, dx = 2 * txk - 1 - px;
    const float K[4] = {1.f, 3.f, 3.f, 1.f};
    const float* wp = W + ((size_t)o * 64 + c) * 9;
    float sacc = 0.f;
    #pragma unroll
    for (int a = 0; a < 3; ++a) {
        int ky = a + dy;
        if ((unsigned)ky >= 4u) continue;
        #pragma unroll
        for (int b2 = 0; b2 < 3; ++b2) {
            int kx = b2 + dx;
            if ((unsigned)kx >= 4u) continue;
            sacc += K[ky] * K[kx] * wp[a * 3 + b2];
        }
    }
    G2[i] = sacc * (1.f / 16.f);
}

// ---------------- 4x4 blur pad=2 (pre-down), batched ----------------
__global__ void blur_down(const float* __restrict__ in, float* __restrict__ out,
                          int H, int W, int tilesX, int tilesY,
                          long long inStr, long long outStr)
{
    int s = blockIdx.y;
    in  += (size_t)s * inStr;
    out += (size_t)s * outStr;
    int Ho = H + 1, Wo = W + 1;
    int bid = blockIdx.x;
    int tx = bid % tilesX; bid /= tilesX;
    int ty = bid % tilesY; bid /= tilesY;
    int p  = bid;
    int x = tx * 16 + (threadIdx.x & 15);
    int y = ty * 16 + (threadIdx.x >> 4);
    if (x >= Wo || y >= Ho) return;
    const float k[4] = {1.f, 3.f, 3.f, 1.f};
    const float* ip = in + (size_t)p * H * W;
    float acc = 0.f;
    #pragma unroll
    for (int ky = 0; ky < 4; ++ky) {
        int iy = y - 2 + ky;
        if ((unsigned)iy >= (unsigned)H) continue;
        float row = 0.f;
        #pragma unroll
        for (int kx = 0; kx < 4; ++kx) {
            int ix = x - 2 + kx;
            if ((unsigned)ix >= (unsigned)W) continue;
            row += ip[(size_t)iy * W + ix] * k[kx];
        }
        acc += row * k[ky];
    }
    out[((size_t)p * Ho + y) * Wo + x] = acc * (1.f / 64.f);
}

// ---------------- avg pool to 1x1 (64 planes), batched ----------------
__global__ void avgpool_hw(const float* __restrict__ in, float* __restrict__ out, int HW,
                           long long inStr, long long outStr)
{
    int s = blockIdx.y;
    in  += (size_t)s * inStr;
    out += (size_t)s * outStr;
    int p = blockIdx.x;
    const float* ip = in + (size_t)p * HW;
    float sum = 0.f;
    for (int i = threadIdx.x; i < HW; i += blockDim.x) sum += ip[i];
    __shared__ float red[256];
    red[threadIdx.x] = sum;
    __syncthreads();
    for (int off = 128; off; off >>= 1) {
        if ((int)threadIdx.x < off) red[threadIdx.x] += red[threadIdx.x + off];
        __syncthreads();
    }
    if (threadIdx.x == 0) out[p] = red[0] / (float)HW;
}

// ---------------- style FC (all 8 samples) ----------------
__global__ void style_fc(const float* __restrict__ s, const float* __restrict__ W,
                         const float* __restrict__ b, float* __restrict__ out, int outdim)
{
    int n = blockIdx.x;
    int i = threadIdx.x;
    if (i >= outdim) return;
    float acc = b[i];
    const float* sn = s + n * 64;
    const float* wi = W + i * 64;
    for (int f = 0; f < 64; ++f) acc += sn[f] * wi[f];
    out[n * 64 + i] = LRELU(acc);
}

// ------- modulate+demodulate (all 8 samples); transpose=1 -> [c][k][o] -------
__global__ void modulate(const float* __restrict__ w, const float* __restrict__ sw,
                         float* __restrict__ wout, int O, int C, int transpose)
{
    int no = blockIdx.x;
    int o = no % O, n = no / O;
    int nw = C * 9;
    int t = threadIdx.x;
    float v[9];
    int cnt = 0;
    float ss = 0.f;
    for (int idx = t; idx < nw; idx += 64) {
        int c = idx / 9;
        float val = w[o * nw + idx] * sw[n * 64 + c];
        v[cnt++] = val;
        ss += val * val;
    }
    #pragma unroll
    for (int off = 32; off; off >>= 1) ss += __shfl_xor(ss, off);
    float d = rsqrtf(ss + 1e-8f);
    cnt = 0;
    for (int idx = t; idx < nw; idx += 64) {
        float val = v[cnt++] * d;
        if (transpose)
            wout[(size_t)n * nw * O + (size_t)idx * O + o] = val;
        else
            wout[(size_t)no * nw + idx] = val;
    }
}

// ------- guide weight transpose -------
__global__ void guide_transpose(const float* __restrict__ grw, float* __restrict__ gt, int total)
{
    int i = blockIdx.x * 256 + threadIdx.x;
    if (i >= total) return;
    int l = i / 36864, rem = i % 36864;
    int idx = rem / 64, o = rem % 64;
    int c = idx / 9, k = idx % 9;
    gt[i] = grw[(((size_t)l * 64 + o) * 64 + c) * 9 + k];
}

// ------- g0 weight transpose -------
__global__ void g0_transpose(const float* __restrict__ g0w, float* __restrict__ gt)
{
    int i = blockIdx.x * 256 + threadIdx.x;
    if (i >= 1728) return;
    int idx = i / 64, o = i % 64;
    int c = idx / 9, k = idx % 9;
    gt[i] = g0w[((size_t)o * 3 + c) * 9 + k];
}

__global__ void fill_sentinel(float* __restrict__ out, int n)
{
    int i = blockIdx.x * 256 + threadIdx.x;
    if (i < n) out[i] = 1.0e9f;
}

extern "C" void kernel_launch(void* const* d_in, const int* in_sizes, int n_in,
                              void* d_out, int out_size, void* d_ws, size_t ws_size,
                              hipStream_t stream)
{
    const float* x     = (const float*)d_in[0];
    const float* ref   = (const float*)d_in[1];
    const float* g0w   = (const float*)d_in[2];
    const float* g0b   = (const float*)d_in[3];
    const float* grw   = (const float*)d_in[4];
    const float* grb   = (const float*)d_in[5];
    const float* c0w   = (const float*)d_in[6];
    const float* c0swW = (const float*)d_in[7];
    const float* c0swb = (const float*)d_in[8];
    const float* c0sbW = (const float*)d_in[9];
    const float* c0sbb = (const float*)d_in[10];
    const float* midw  = (const float*)d_in[11];
    const float* midswW= (const float*)d_in[12];
    const float* midswb= (const float*)d_in[13];
    const float* midsbW= (const float*)d_in[14];
    const float* midsbb= (const float*)d_in[15];
    const float* c6w   = (const float*)d_in[16];
    const float* c6swW = (const float*)d_in[17];
    const float* c6swb = (const float*)d_in[18];
    const float* c6sbW = (const float*)d_in[19];
    const float* c6sbb = (const float*)d_in[20];
    float* out = (float*)d_out;
    float* ws  = (float*)d_ws;

    // -------- shared region (floats) --------
    const size_t SV  = 0;
    const size_t STY = 512;
    const size_t WM  = 12800;
    const size_t GT  = 2989568;
    const size_t G0T = 3137024;
    const size_t BUF = 3138816;

    // -------- main-path per-sample slot offsets (no F0: f0 recomputed at end) --------
    const size_t SA = 0;                  // [64,257,257]-class (blur out / f5up out / f0-recomp)
    const size_t SB = 4227136;            // [64,256,256] (f0 initial / f5 final)
    const size_t D1 = 8421440;            // [64,128,128]
    const size_t D2 = 9470016;            // [64,128,128]
    const size_t D3 = 10518592;           // [64,129,129]-class
    const size_t E1 = 11583616;           // [64,64,64]
    const size_t E2 = 11845760;
    const size_t E3 = 12107904;
    const size_t G2o = 12370048;          // combined up-weights [147456]
    const long long PER = 12517504ll;     // ~50.1 MB per sample

    // -------- guide-phase per-sample slot offsets --------
    const size_t gSA = 0;
    const size_t gD1 = 4194304;
    const size_t gD2 = 5242880;
    const size_t gE1 = 6291456;
    const size_t gE2 = 6553600;
    const long long GPER = 6815744ll;

    int G = 0, GG = 0;
    for (int g = 8; g >= 1; --g)
        if ((BUF + (size_t)g * PER) * sizeof(float) <= ws_size) { G = g; break; }
    for (int g = 8; g >= 1; --g)
        if ((BUF + (size_t)g * GPER) * sizeof(float) <= ws_size) { GG = g; break; }
    if (!G || !GG) {
        fill_sentinel<<<dim3((out_size + 255) / 256), dim3(256), 0, stream>>>(out, out_size);
        return;
    }

    dim3 blk(256);
    const int LDS1 = 29952;
    const int LDS2 = 28224;
    const int LDSU = (4 * 10 * 12 + 4 * 2448) * 4;   // 41088 B

    float* B = ws + BUF;

    guide_transpose<<<dim3(147456 / 256), blk, 0, stream>>>(grw, ws + GT, 147456);
    g0_transpose<<<dim3(7), blk, 0, stream>>>(g0w, ws + G0T);

    // ==================== guide net ====================
    for (int n0 = 0; n0 < 8; ) {
        int g = (8 - n0 < GG) ? (8 - n0) : GG;
        const float* refg = ref + (size_t)n0 * 196608;
        conv3_gemm<<<dim3(16 * 16, g), blk, 0, stream>>>(
            refg, ws + G0T, g0b, B + gSA, 256, 256, 16, 196608, 0, 0, GPER);
        conv64_gemm<2><<<dim3(8 * 8, g), blk, LDS2, stream>>>(
            B + gSA, ws + GT, grb, B + gD1, 256, 256, 128, 128, 1, 1, 8, GPER, 0, 0, GPER);
        conv64_gemm<1><<<dim3(8 * 8, g), blk, LDS1, stream>>>(
            B + gD1, ws + GT + 36864, grb + 64, B + gD2, 128, 128, 128, 128, 1, 1, 8, GPER, 0, 0, GPER);
        conv64_gemm<2><<<dim3(4 * 4, g), blk, LDS2, stream>>>(
            B + gD2, ws + GT + 73728, grb + 128, B + gE1, 128, 128, 64, 64, 1, 1, 4, GPER, 0, 0, GPER);
        conv64_gemm8<<<dim3(8 * 8, g), blk, 0, stream>>>(
            B + gE1, ws + GT + 110592, grb + 192, B + gE2, 64, 64, 0, 8, GPER, 0, 0, GPER);
        avgpool_hw<<<dim3(64, g), blk, 0, stream>>>(B + gE2, ws + SV + (size_t)n0 * 64, 4096, GPER, 64);
        n0 += g;
    }

    // ==================== styles + modulated weights ====================
    const float* Wt[12];  const float* swWp[12]; const float* swbp[12];
    const float* sbWp[12]; const float* sbbp[12];
    int Ci[12], Oi[12];
    size_t wmo[12];
    Wt[0] = c0w; swWp[0] = c0swW; swbp[0] = c0swb; sbWp[0] = c0sbW; sbbp[0] = c0sbb;
    Ci[0] = 3; Oi[0] = 64; wmo[0] = WM;
    for (int i = 0; i < 10; ++i) {
        Wt[1 + i]   = midw   + (size_t)i * 36864;
        swWp[1 + i] = midswW + (size_t)i * 4096;
        swbp[1 + i] = midswb + (size_t)i * 64;
        sbWp[1 + i] = midsbW + (size_t)i * 4096;
        sbbp[1 + i] = midsbb + (size_t)i * 64;
        Ci[1 + i] = 64; Oi[1 + i] = 64;
        wmo[1 + i] = WM + 13824ull + (size_t)i * 294912ull;
    }
    Wt[11] = c6w; swWp[11] = c6swW; swbp[11] = c6swb; sbWp[11] = c6sbW; sbbp[11] = c6sbb;
    Ci[11] = 64; Oi[11] = 3; wmo[11] = WM + 13824ull + 2949120ull;

    const int trf[12] = {1, 1, 1, 1, 1, 1, 1, 0, 1, 0, 1, 1};

    for (int i = 0; i < 12; ++i) {
        style_fc<<<dim3(8), dim3(64), 0, stream>>>(ws + SV, swWp[i], swbp[i], ws + STY + i * 1024, Ci[i]);
        style_fc<<<dim3(8), dim3(64), 0, stream>>>(ws + SV, sbWp[i], sbbp[i], ws + STY + i * 1024 + 512, Oi[i]);
        modulate<<<dim3(8 * Oi[i]), dim3(64), 0, stream>>>(Wt[i], ws + STY + i * 1024, ws + wmo[i], Oi[i], Ci[i], trf[i]);
    }

    // ==================== main path ====================
    for (int n0 = 0; n0 < 8; ) {
        int g = (8 - n0 < G) ? (8 - n0) : G;
        const float* xg = x + (size_t)n0 * 196608;
        float* outg = out + (size_t)n0 * 196608;
        #define WN(i)  (ws + wmo[i] + (size_t)n0 * Oi[i] * Ci[i] * 9)
        #define WSTR(i) ((long long)(Oi[i] * Ci[i] * 9))
        #define SBN(i) (ws + STY + (i) * 1024 + 512 + (size_t)n0 * 64)
        // f0 -> SB
        conv3_gemm<<<dim3(16 * 16, g), blk, 0, stream>>>(
            xg, WN(0), SBN(0), B + SB, 256, 256, 16, 196608, WSTR(0), 64, PER);
        // f1 down: blur(SB) -> SA; conv s2 -> D1; conv -> D2
        blur_down<<<dim3(64 * 17 * 17, g), blk, 0, stream>>>(B + SB, B + SA, 256, 256, 17, 17, PER, PER);
        conv64_gemm<2><<<dim3(8 * 8, g), blk, LDS2, stream>>>(
            B + SA, WN(1), SBN(1), B + D1, 257, 257, 128, 128, 0, 1, 8, PER, WSTR(1), 64, PER);
        conv64_gemm8<<<dim3(16 * 16, g), blk, 0, stream>>>(
            B + D1, WN(2), SBN(2), B + D2, 128, 128, 1, 16, PER, WSTR(2), 64, PER);
        // f2 down
        blur_down<<<dim3(64 * 9 * 9, g), blk, 0, stream>>>(B + D2, B + D3, 128, 128, 9, 9, PER, PER);
        conv64_gemm<2><<<dim3(4 * 4, g), blk, LDS2, stream>>>(
            B + D3, WN(3), SBN(3), B + E1, 129, 129, 64, 64, 0, 1, 4, PER, WSTR(3), 64, PER);
        conv64_gemm8<<<dim3(8 * 8, g), blk, 0, stream>>>(
            B + E1, WN(4), SBN(4), B + E2, 64, 64, 1, 8, PER, WSTR(4), 64, PER);
        // f3 x2
        conv64_gemm8<<<dim3(8 * 8, g), blk, 0, stream>>>(
            B + E2, WN(5), SBN(5), B + E3, 64, 64, 1, 8, PER, WSTR(5), 64, PER);
        conv64_gemm8<<<dim3(8 * 8, g), blk, 0, stream>>>(
            B + E3, WN(6), SBN(6), B + E1, 64, 64, 1, 8, PER, WSTR(6), 64, PER);
        // f4 up (fused): combine -> G2o; upconv(f3+f2) -> D1; conv -> D3
        combine_up_w<<<dim3(576, g), blk, 0, stream>>>(WN(7), B + G2o, WSTR(7), PER);
        upconv64_gemm<<<dim3(8 * 8, g), blk, LDSU, stream>>>(
            B + E1, B + E2, B + G2o, SBN(7), B + D1, 64, 64, 8, PER, 64, PER);
        conv64_gemm8<<<dim3(16 * 16, g), blk, 0, stream>>>(
            B + D1, WN(8), SBN(8), B + D3, 128, 128, 1, 16, PER, WSTR(8), 64, PER);
        // f5 up: combine -> G2o; upconv(f4+f1) -> SA; conv -> SB
        combine_up_w<<<dim3(576, g), blk, 0, stream>>>(WN(9), B + G2o, WSTR(9), PER);
        upconv64_gemm<<<dim3(16 * 16, g), blk, LDSU, stream>>>(
            B + D3, B + D2, B + G2o, SBN(9), B + SA, 128, 128, 16, PER, 64, PER);
        conv64_gemm<1><<<dim3(16 * 16, g), blk, LDS1, stream>>>(
            B + SA, WN(10), SBN(10), B + SB, 256, 256, 256, 256, 1, 1, 16, PER, WSTR(10), 64, PER);
        // recompute f0 -> SA (bit-identical to the original conv3_gemm output)
        conv3_gemm<<<dim3(16 * 16, g), blk, 0, stream>>>(
            xg, WN(0), SBN(0), B + SA, 256, 256, 16, 196608, WSTR(0), 64, PER);
        // c6: conv(f5 + f0) -> out
        conv64to3_gemm<<<dim3(16 * 16, g), blk, 0, stream>>>(
            B + SB, B + SA, WN(11), SBN(11), outg, 256, 256, 16, PER, WSTR(11), 64, 196608);
        #undef WN
        #undef WSTR
        #undef SBN
        n0 += g;
    }
}

// Round 11
// 4302.340 us; speedup vs baseline: 8.6160x; 1.0693x over previous
//
#include <hip/hip_runtime.h>

#define LRELU(v) ((v) >= 0.f ? (v) : 0.2f * (v))

// ================= implicit-GEMM 3x3 conv, C=64 -> O=64, 16x16 tile (stride 1) =================
template<int S>
__global__ void conv64_gemm(const float* __restrict__ in, const float* __restrict__ Wt,
                            const float* __restrict__ bias, float* __restrict__ out,
                            int Hin, int Win, int Hout, int Wout, int pad, int act, int tilesX,
                            long long inStr, long long wStr, long long bStr, long long outStr)
{
    constexpr int CC  = (S == 1) ? 8 : 4;
    constexpr int TIN = (S == 1) ? 18 : 33;
    constexpr int RS  = (S == 1) ? 20 : 36;
    constexpr int NF4 = (S == 1) ? 3 : 5;
    constexpr int PW  = NF4 * 4;
    extern __shared__ float lds[];
    float* it = lds;
    float* wl = lds + CC * TIN * RS;

    int s = blockIdx.y;
    in   += (size_t)s * inStr;
    Wt   += (size_t)s * wStr;
    bias += (size_t)s * bStr;
    out  += (size_t)s * outStr;

    int b  = blockIdx.x;
    int tx = b % tilesX, ty = b / tilesX;
    int t  = threadIdx.x;
    int og = t >> 5;
    int pg = t & 31;
    int r  = pg >> 1, ch = pg & 1;

    float acc[8][8];
    #pragma unroll
    for (int i = 0; i < 8; ++i)
        #pragma unroll
        for (int j = 0; j < 8; ++j) acc[i][j] = 0.f;

    const int y0 = ty * 16 * S - pad;
    const int x0 = tx * 16 * S - pad;
    const size_t plane = (size_t)Hin * Win;

    for (int c0 = 0; c0 < 64; c0 += CC) {
        __syncthreads();
        {
            const float4* src = (const float4*)(Wt + c0 * 9 * 64);
            float4* dst = (float4*)wl;
            for (int i = t; i < CC * 9 * 16; i += 256) dst[i] = src[i];
        }
        for (int rowi = t; rowi < CC * TIN; rowi += 256) {
            int cc = rowi / TIN, rr = rowi - cc * TIN;
            int iy = y0 + rr;
            float* dst = it + (size_t)rowi * RS;
            const float* srow = in + (size_t)(c0 + cc) * plane + (size_t)iy * Win + x0;
            if ((unsigned)iy < (unsigned)Hin && x0 >= 0 && x0 + RS <= Win) {
                #pragma unroll
                for (int q = 0; q < RS / 4; ++q)
                    ((float4*)dst)[q] = ((const float4*)srow)[q];
            } else {
                for (int cl = 0; cl < TIN; ++cl) {
                    int ix = x0 + cl;
                    float v = 0.f;
                    if ((unsigned)iy < (unsigned)Hin && (unsigned)ix < (unsigned)Win)
                        v = in[(size_t)(c0 + cc) * plane + (size_t)iy * Win + ix];
                    dst[cl] = v;
                }
            }
        }
        __syncthreads();
        for (int cc = 0; cc < CC; ++cc) {
            const float* base = it + cc * TIN * RS;
            #pragma unroll
            for (int ky = 0; ky < 3; ++ky) {
                float p[PW];
                const float* rowp = base + (r * S + ky) * RS + ch * 8 * S;
                #pragma unroll
                for (int q = 0; q < NF4; ++q) {
                    float4 f = *(const float4*)(rowp + q * 4);
                    p[q*4+0] = f.x; p[q*4+1] = f.y; p[q*4+2] = f.z; p[q*4+3] = f.w;
                }
                #pragma unroll
                for (int kx = 0; kx < 3; ++kx) {
                    const float* wp = wl + ((cc * 9) + ky * 3 + kx) * 64 + og * 8;
                    float4 wa = *(const float4*)wp;
                    float4 wb = *(const float4*)(wp + 4);
                    float w8[8] = {wa.x, wa.y, wa.z, wa.w, wb.x, wb.y, wb.z, wb.w};
                    #pragma unroll
                    for (int oi = 0; oi < 8; ++oi)
                        #pragma unroll
                        for (int j = 0; j < 8; ++j)
                            acc[oi][j] += w8[oi] * p[j * S + kx];
                }
            }
        }
    }

    int y  = ty * 16 + r;
    int xb = tx * 16 + ch * 8;
    #pragma unroll
    for (int oi = 0; oi < 8; ++oi) {
        int o = og * 8 + oi;
        float bo = bias[o];
        float v[8];
        #pragma unroll
        for (int j = 0; j < 8; ++j) {
            float a = acc[oi][j] + bo;
            v[j] = act ? LRELU(a) : a;
        }
        float* op = out + ((size_t)o * Hout + y) * Wout + xb;
        *(float4*)op       = make_float4(v[0], v[1], v[2], v[3]);
        *(float4*)(op + 4) = make_float4(v[4], v[5], v[6], v[7]);
    }
}

// ======== implicit-GEMM 3x3 conv, C=64 -> O=64, stride1 pad1, 8x8 tile ========
__global__ void conv64_gemm8(const float* __restrict__ in, const float* __restrict__ Wt,
                             const float* __restrict__ bias, float* __restrict__ out,
                             int H, int W, int act, int tilesX,
                             long long inStr, long long wStr, long long bStr, long long outStr)
{
    constexpr int CC = 8, TIN = 10, RS = 12;
    __shared__ float it[CC * TIN * RS];
    __shared__ float wl[CC * 9 * 64];
    int s = blockIdx.y;
    in   += (size_t)s * inStr;
    Wt   += (size_t)s * wStr;
    bias += (size_t)s * bStr;
    out  += (size_t)s * outStr;

    int b  = blockIdx.x;
    int tx = b % tilesX, ty = b / tilesX;
    int t  = threadIdx.x;
    int og = t >> 5, pg = t & 31;
    int r  = pg >> 2, ch = pg & 3;

    float acc[8][2];
    #pragma unroll
    for (int i = 0; i < 8; ++i) { acc[i][0] = 0.f; acc[i][1] = 0.f; }

    const int y0 = ty * 8 - 1, x0 = tx * 8 - 1;
    const size_t plane = (size_t)H * W;

    for (int c0 = 0; c0 < 64; c0 += CC) {
        __syncthreads();
        {
            const float4* src = (const float4*)(Wt + c0 * 9 * 64);
            float4* dst = (float4*)wl;
            for (int i = t; i < CC * 9 * 16; i += 256) dst[i] = src[i];
        }
        for (int rowi = t; rowi < CC * TIN; rowi += 256) {
            int cc = rowi / TIN, rr = rowi - cc * TIN;
            int iy = y0 + rr;
            float* dst = it + rowi * RS;
            const float* srow = in + (size_t)(c0 + cc) * plane + (size_t)iy * W + x0;
            if ((unsigned)iy < (unsigned)H && x0 >= 0 && x0 + RS <= W) {
                #pragma unroll
                for (int q = 0; q < 3; ++q)
                    ((float4*)dst)[q] = ((const float4*)srow)[q];
            } else {
                for (int cl = 0; cl < RS; ++cl) {
                    int ix = x0 + cl;
                    float v = 0.f;
                    if (cl < TIN && (unsigned)iy < (unsigned)H && (unsigned)ix < (unsigned)W)
                        v = in[(size_t)(c0 + cc) * plane + (size_t)iy * W + ix];
                    dst[cl] = v;
                }
            }
        }
        __syncthreads();
        for (int cc = 0; cc < CC; ++cc) {
            const float* base = it + cc * TIN * RS;
            #pragma unroll
            for (int ky = 0; ky < 3; ++ky) {
                const float* rowp = base + (r + ky) * RS + ch * 2;
                float p[4] = {rowp[0], rowp[1], rowp[2], rowp[3]};
                #pragma unroll
                for (int kx = 0; kx < 3; ++kx) {
                    const float* wp = wl + ((cc * 9) + ky * 3 + kx) * 64 + og * 8;
                    float4 wa = *(const float4*)wp;
                    float4 wb = *(const float4*)(wp + 4);
                    float w8[8] = {wa.x, wa.y, wa.z, wa.w, wb.x, wb.y, wb.z, wb.w};
                    #pragma unroll
                    for (int oi = 0; oi < 8; ++oi) {
                        acc[oi][0] += w8[oi] * p[kx];
                        acc[oi][1] += w8[oi] * p[kx + 1];
                    }
                }
            }
        }
    }

    int y = ty * 8 + r, xb = tx * 8 + ch * 2;
    #pragma unroll
    for (int oi = 0; oi < 8; ++oi) {
        int o = og * 8 + oi;
        float bo = bias[o];
        float a0 = acc[oi][0] + bo, a1 = acc[oi][1] + bo;
        if (act) { a0 = LRELU(a0); a1 = LRELU(a1); }
        *(float2*)(out + ((size_t)o * H + y) * W + xb) = make_float2(a0, a1);
    }
}

// ======== implicit-GEMM 3x3 conv, C=64 -> O=64, stride2, 8x8 out tile ========
// out[y][x] reads input rows 2y-pad+ky, cols 2x-pad+kx. Input window 18x18 per tile.
__global__ void conv64s2_gemm8(const float* __restrict__ in, const float* __restrict__ Wt,
                               const float* __restrict__ bias, float* __restrict__ out,
                               int Hin, int Win, int Hout, int Wout, int pad, int act, int tilesX,
                               long long inStr, long long wStr, long long bStr, long long outStr)
{
    constexpr int CC = 8, TIN = 18, RS = 20;
    __shared__ float it[CC * TIN * RS];   // 2880
    __shared__ float wl[CC * 9 * 64];     // 4608
    int s = blockIdx.y;
    in   += (size_t)s * inStr;
    Wt   += (size_t)s * wStr;
    bias += (size_t)s * bStr;
    out  += (size_t)s * outStr;

    int b  = blockIdx.x;
    int tx = b % tilesX, ty = b / tilesX;
    int t  = threadIdx.x;
    int og = t >> 5, pg = t & 31;
    int r  = pg >> 2, ch = pg & 3;        // out row 0..7, col pair 0..3

    float acc[8][2];
    #pragma unroll
    for (int i = 0; i < 8; ++i) { acc[i][0] = 0.f; acc[i][1] = 0.f; }

    const int y0 = ty * 16 - pad, x0 = tx * 16 - pad;
    const size_t plane = (size_t)Hin * Win;

    for (int c0 = 0; c0 < 64; c0 += CC) {
        __syncthreads();
        {
            const float4* src = (const float4*)(Wt + c0 * 9 * 64);
            float4* dst = (float4*)wl;
            for (int i = t; i < CC * 9 * 16; i += 256) dst[i] = src[i];
        }
        for (int rowi = t; rowi < CC * TIN; rowi += 256) {
            int cc = rowi / TIN, rr = rowi - cc * TIN;
            int iy = y0 + rr;
            float* dst = it + rowi * RS;
            const float* srow = in + (size_t)(c0 + cc) * plane + (size_t)iy * Win + x0;
            if ((unsigned)iy < (unsigned)Hin && x0 >= 0 && x0 + RS <= Win) {
                #pragma unroll
                for (int q = 0; q < RS / 4; ++q)
                    ((float4*)dst)[q] = ((const float4*)srow)[q];
            } else {
                for (int cl = 0; cl < RS; ++cl) {
                    int ix = x0 + cl;
                    float v = 0.f;
                    if (cl < TIN && (unsigned)iy < (unsigned)Hin && (unsigned)ix < (unsigned)Win)
                        v = in[(size_t)(c0 + cc) * plane + (size_t)iy * Win + ix];
                    dst[cl] = v;
                }
            }
        }
        __syncthreads();
        for (int cc = 0; cc < CC; ++cc) {
            const float* base = it + cc * TIN * RS;
            #pragma unroll
            for (int ky = 0; ky < 3; ++ky) {
                const float* rowp = base + (2 * r + ky) * RS + ch * 4;
                float4 f0 = *(const float4*)rowp;
                float4 f1 = *(const float4*)(rowp + 4);
                float p[8] = {f0.x, f0.y, f0.z, f0.w, f1.x, f1.y, f1.z, f1.w};
                #pragma unroll
                for (int kx = 0; kx < 3; ++kx) {
                    const float* wp = wl + ((cc * 9) + ky * 3 + kx) * 64 + og * 8;
                    float4 wa = *(const float4*)wp;
                    float4 wb = *(const float4*)(wp + 4);
                    float w8[8] = {wa.x, wa.y, wa.z, wa.w, wb.x, wb.y, wb.z, wb.w};
                    #pragma unroll
                    for (int oi = 0; oi < 8; ++oi) {
                        acc[oi][0] += w8[oi] * p[kx];
                        acc[oi][1] += w8[oi] * p[kx + 2];
                    }
                }
            }
        }
    }

    int y = ty * 8 + r, xb = tx * 8 + ch * 2;
    #pragma unroll
    for (int oi = 0; oi < 8; ++oi) {
        int o = og * 8 + oi;
        float bo = bias[o];
        float a0 = acc[oi][0] + bo, a1 = acc[oi][1] + bo;
        if (act) { a0 = LRELU(a0); a1 = LRELU(a1); }
        *(float2*)(out + ((size_t)o * Hout + y) * Wout + xb) = make_float2(a0, a1);
    }
}

// ========== implicit-GEMM 3x3 conv, C=3 -> O=64, stride1 pad1 (g0 guide, f0) ==========
__global__ void conv3_gemm(const float* __restrict__ in, const float* __restrict__ Wt,
                           const float* __restrict__ bias, float* __restrict__ out,
                           int H, int W, int tilesX,
                           long long inStr, long long wStr, long long bStr, long long outStr)
{
    constexpr int TIN = 18, RS = 20;
    __shared__ float it[3 * TIN * RS];
    __shared__ float wl[27 * 64];
    int s = blockIdx.y;
    in   += (size_t)s * inStr;
    Wt   += (size_t)s * wStr;
    bias += (size_t)s * bStr;
    out  += (size_t)s * outStr;

    int b  = blockIdx.x;
    int tx = b % tilesX, ty = b / tilesX;
    int t  = threadIdx.x;
    {
        const float4* src = (const float4*)Wt;
        float4* dst = (float4*)wl;
        for (int i = t; i < 27 * 16; i += 256) dst[i] = src[i];
    }
    const int y0 = ty * 16 - 1, x0 = tx * 16 - 1;
    const size_t plane = (size_t)H * W;
    for (int rowi = t; rowi < 3 * TIN; rowi += 256) {
        int cc = rowi / TIN, rr = rowi - cc * TIN;
        int iy = y0 + rr;
        float* dst = it + (size_t)rowi * RS;
        const float* srow = in + (size_t)cc * plane + (size_t)iy * W + x0;
        if ((unsigned)iy < (unsigned)H && x0 >= 0 && x0 + RS <= W) {
            #pragma unroll
            for (int q = 0; q < RS / 4; ++q)
                ((float4*)dst)[q] = ((const float4*)srow)[q];
        } else {
            for (int cl = 0; cl < TIN; ++cl) {
                int ix = x0 + cl;
                float v = 0.f;
                if ((unsigned)iy < (unsigned)H && (unsigned)ix < (unsigned)W)
                    v = in[(size_t)cc * plane + (size_t)iy * W + ix];
                dst[cl] = v;
            }
        }
    }
    __syncthreads();

    int og = t >> 5, pg = t & 31;
    int r  = pg >> 1, ch = pg & 1;
    float acc[8][8];
    #pragma unroll
    for (int i = 0; i < 8; ++i)
        #pragma unroll
        for (int j = 0; j < 8; ++j) acc[i][j] = 0.f;

    for (int c = 0; c < 3; ++c) {
        const float* base = it + c * TIN * RS;
        #pragma unroll
        for (int ky = 0; ky < 3; ++ky) {
            float p[12];
            const float* rowp = base + (r + ky) * RS + ch * 8;
            #pragma unroll
            for (int q = 0; q < 3; ++q) {
                float4 f = *(const float4*)(rowp + q * 4);
                p[q*4+0] = f.x; p[q*4+1] = f.y; p[q*4+2] = f.z; p[q*4+3] = f.w;
            }
            #pragma unroll
            for (int kx = 0; kx < 3; ++kx) {
                const float* wp = wl + ((c * 9) + ky * 3 + kx) * 64 + og * 8;
                float4 wa = *(const float4*)wp;
                float4 wb = *(const float4*)(wp + 4);
                float w8[8] = {wa.x, wa.y, wa.z, wa.w, wb.x, wb.y, wb.z, wb.w};
                #pragma unroll
                for (int oi = 0; oi < 8; ++oi)
                    #pragma unroll
                    for (int j = 0; j < 8; ++j)
                        acc[oi][j] += w8[oi] * p[j + kx];
            }
        }
    }

    int y  = ty * 16 + r;
    int xb = tx * 16 + ch * 8;
    #pragma unroll
    for (int oi = 0; oi < 8; ++oi) {
        int o = og * 8 + oi;
        float bo = bias[o];
        float v[8];
        #pragma unroll
        for (int j = 0; j < 8; ++j) {
            float a = acc[oi][j] + bo;
            v[j] = LRELU(a);
        }
        float* op = out + ((size_t)o * H + y) * W + xb;
        *(float4*)op       = make_float4(v[0], v[1], v[2], v[3]);
        *(float4*)(op + 4) = make_float4(v[4], v[5], v[6], v[7]);
    }
}

// ========== implicit-GEMM 3x3 conv, C=64 -> O=3, (in1+in2), no act (c6) ==========
__global__ void conv64to3_gemm(const float* __restrict__ in, const float* __restrict__ in2,
                               const float* __restrict__ Wt, const float* __restrict__ sb,
                               float* __restrict__ out, int H, int W, int tilesX,
                               long long inStr, long long wStr, long long sbStr, long long outStr)
{
    constexpr int CC = 8, TIN = 18, RS = 20;
    __shared__ float it[CC * TIN * RS];
    __shared__ float wl[CC * 9 * 3];
    int s = blockIdx.y;
    in  += (size_t)s * inStr;
    in2 += (size_t)s * inStr;
    Wt  += (size_t)s * wStr;
    sb  += (size_t)s * sbStr;
    out += (size_t)s * outStr;

    int b  = blockIdx.x;
    int tx = b % tilesX, ty = b / tilesX;
    int t  = threadIdx.x;
    int r  = t >> 4, cl = t & 15;
    const int y0 = ty * 16 - 1, x0 = tx * 16 - 1;
    const size_t plane = (size_t)H * W;

    float acc[3] = {0.f, 0.f, 0.f};

    for (int c0 = 0; c0 < 64; c0 += CC) {
        __syncthreads();
        for (int i = t; i < CC * 9 * 3; i += 256) wl[i] = Wt[c0 * 27 + i];
        for (int rowi = t; rowi < CC * TIN; rowi += 256) {
            int cc = rowi / TIN, rr = rowi - cc * TIN;
            int iy = y0 + rr;
            float* dst = it + (size_t)rowi * RS;
            size_t roff = (size_t)(c0 + cc) * plane + (size_t)iy * W + x0;
            if ((unsigned)iy < (unsigned)H && x0 >= 0 && x0 + RS <= W) {
                #pragma unroll
                for (int q = 0; q < RS / 4; ++q) {
                    float4 a = ((const float4*)(in  + roff))[q];
                    float4 bb = ((const float4*)(in2 + roff))[q];
                    ((float4*)dst)[q] = make_float4(a.x + bb.x, a.y + bb.y, a.z + bb.z, a.w + bb.w);
                }
            } else {
                for (int c2 = 0; c2 < TIN; ++c2) {
                    int ix = x0 + c2;
                    float v = 0.f;
                    if ((unsigned)iy < (unsigned)H && (unsigned)ix < (unsigned)W) {
                        size_t off = (size_t)(c0 + cc) * plane + (size_t)iy * W + ix;
                        v = in[off] + in2[off];
                    }
                    dst[c2] = v;
                }
            }
        }
        __syncthreads();
        for (int cc = 0; cc < CC; ++cc) {
            const float* base = it + cc * TIN * RS;
            #pragma unroll
            for (int ky = 0; ky < 3; ++ky) {
                const float* rowp = base + (r + ky) * RS + cl;
                float p0 = rowp[0], p1 = rowp[1], p2 = rowp[2];
                const float* wr = wl + (cc * 9 + ky * 3) * 3;
                #pragma unroll
                for (int o = 0; o < 3; ++o)
                    acc[o] += wr[o] * p0 + wr[3 + o] * p1 + wr[6 + o] * p2;
            }
        }
    }

    int y = ty * 16 + r, x = tx * 16 + cl;
    #pragma unroll
    for (int o = 0; o < 3; ++o)
        out[((size_t)o * H + y) * W + x] = acc[o] + sb[o];
}

// ===== fused up-conv: tconv(s2,3x3)+blur(4x4,x4/64)+bias+lrelu, 32x8 out tile =====
// lane map: t = og[0:2] | pxb[3] | xh[4] | r[5:7]; pair t^8 = other x-parity.
// Per (o,row) the block writes 32 consecutive floats = one full 128B line.
__global__ void upconv64_gemm(const float* __restrict__ in, const float* __restrict__ in2,
                              const float* __restrict__ G2, const float* __restrict__ sb,
                              float* __restrict__ out, int Hin, int Win, int tilesX,
                              long long bufStr, long long sbStr, long long outStr)
{
    constexpr int CC = 4;
    constexpr int RS = 20;                    // 18-col window, padded
    constexpr int PSTR = 68;                  // padded parity stride (floats)
    extern __shared__ float lds[];
    float* it = lds;                          // [CC][6][RS] = 480
    float* wl = lds + CC * 6 * RS;            // [CC][9][4][PSTR] = CC*2448

    int s = blockIdx.y;
    in  += (size_t)s * bufStr;
    in2 += (size_t)s * bufStr;
    G2  += (size_t)s * bufStr;
    sb  += (size_t)s * sbStr;
    out += (size_t)s * outStr;

    int b  = blockIdx.x;
    int tx = b % tilesX, ty = b / tilesX;
    int t  = threadIdx.x;
    int og  = t & 7;
    int pxb = (t >> 3) & 1;
    int xh  = (t >> 4) & 1;
    int r   = t >> 5;                         // out row 0..7
    int rhalf = r >> 1, rpar = r & 1;
    const int Y0 = ty * 8, X0 = tx * 32;
    const int gy0 = Y0 / 2 - 1;
    const int gx0 = X0 / 2 - 1;
    const size_t plane = (size_t)Hin * Win;

    float acc[8][8];
    #pragma unroll
    for (int i = 0; i < 8; ++i)
        #pragma unroll
        for (int j = 0; j < 8; ++j) acc[i][j] = 0.f;

    for (int c0 = 0; c0 < 64; c0 += CC) {
        __syncthreads();
        {
            // stage [CC][36] rows of 64 floats into stride-68 rows
            const float4* src = (const float4*)(G2 + (size_t)c0 * 2304);
            for (int i = t; i < CC * 36 * 16; i += 256) {
                int row = i >> 4, q = i & 15;
                ((float4*)(wl + row * PSTR))[q] = src[i];
            }
        }
        for (int rowi = t; rowi < CC * 6; rowi += 256) {
            int cc = rowi / 6, rr = rowi - cc * 6;
            int gi = gy0 + rr;
            float* dst = it + (size_t)rowi * RS;
            size_t roff = (size_t)(c0 + cc) * plane + (size_t)gi * Win + gx0;
            if ((unsigned)gi < (unsigned)Hin && gx0 >= 0 && gx0 + RS <= Win) {
                #pragma unroll
                for (int qq = 0; qq < 5; ++qq) {
                    float4 a = ((const float4*)(in  + roff))[qq];
                    float4 bb = ((const float4*)(in2 + roff))[qq];
                    ((float4*)dst)[qq] = make_float4(a.x + bb.x, a.y + bb.y, a.z + bb.z, a.w + bb.w);
                }
            } else {
                for (int cl = 0; cl < RS; ++cl) {
                    int gj = gx0 + cl;
                    float v = 0.f;
                    if (cl < 18 && (unsigned)gi < (unsigned)Hin && (unsigned)gj < (unsigned)Win) {
                        size_t off = (size_t)(c0 + cc) * plane + (size_t)gi * Win + gj;
                        v = in[off] + in2[off];
                    }
                    dst[cl] = v;
                }
            }
        }
        __syncthreads();
        for (int cc = 0; cc < CC; ++cc) {
            const float* ib = it + cc * 6 * RS;
            const float* wcb = wl + cc * (36 * PSTR) + (rpar * 2 + pxb) * PSTR;
            #pragma unroll
            for (int ty2 = 0; ty2 < 3; ++ty2) {
                float p[12];
                const float* rowp = ib + (rhalf + ty2) * RS + xh * 8;
                #pragma unroll
                for (int qq = 0; qq < 3; ++qq) {
                    float4 f = *(const float4*)(rowp + qq * 4);
                    p[qq*4+0] = f.x; p[qq*4+1] = f.y; p[qq*4+2] = f.z; p[qq*4+3] = f.w;
                }
                #pragma unroll
                for (int tx2 = 0; tx2 < 3; ++tx2) {
                    const float* wp = wcb + (ty2 * 3 + tx2) * (4 * PSTR) + og * 8;
                    float4 wa = *(const float4*)wp;
                    float4 wv = *(const float4*)(wp + 4);
                    float w8[8] = {wa.x, wa.y, wa.z, wa.w, wv.x, wv.y, wv.z, wv.w};
                    #pragma unroll
                    for (int oi = 0; oi < 8; ++oi)
                        #pragma unroll
                        for (int k = 0; k < 8; ++k)
                            acc[oi][k] += w8[oi] * p[k + tx2];
                }
            }
        }
    }

    const int Hout = 2 * Hin, Wout = 2 * Win;
    int y = Y0 + r;
    #pragma unroll
    for (int oi = 0; oi < 8; ++oi) {
        int o = og * 8 + oi;
        float bo = sb[o];
        float v[8];
        #pragma unroll
        for (int k = 0; k < 8; ++k) {
            float a = acc[oi][k] + bo;
            v[k] = LRELU(a);
        }
        float rcv[4];
        #pragma unroll
        for (int j = 0; j < 4; ++j) {
            float snd = pxb ? v[j] : v[4 + j];
            rcv[j] = __shfl_xor(snd, 8, 64);
        }
        float w0 = pxb ? rcv[0] : v[0];
        float w1 = pxb ? v[4]   : rcv[0];
        float w2 = pxb ? rcv[1] : v[1];
        float w3 = pxb ? v[5]   : rcv[1];
        float w4 = pxb ? rcv[2] : v[2];
        float w5 = pxb ? v[6]   : rcv[2];
        float w6 = pxb ? rcv[3] : v[3];
        float w7 = pxb ? v[7]   : rcv[3];
        float* op = out + ((size_t)o * Hout + y) * Wout + X0 + xh * 16 + (pxb ? 8 : 0);
        *(float4*)op       = make_float4(w0, w1, w2, w3);
        *(float4*)(op + 4) = make_float4(w4, w5, w6, w7);
    }
}

// ------- build combined up-weights, layout [c][tap][parity][o] -------
__global__ void combine_up_w(const float* __restrict__ W, float* __restrict__ G2,
                             long long wStr, long long g2Str)
{
    int s = blockIdx.y;
    W  += (size_t)s * wStr;
    G2 += (size_t)s * g2Str;
    int i = blockIdx.x * 256 + threadIdx.x;
    if (i >= 147456) return;
    int o = i & 63;
    int rest = i >> 6;            // (c*9 + k)*4 + p
    int p4 = rest & 3;
    int k9 = (rest >> 2) % 9;
    int c  = (rest >> 2) / 9;
    int py = p4 >> 1, px = p4 & 1;
    int tyk = k9 / 3, txk = k9 % 3;
    int dy = 2 * tyk - 1 - py, dx = 2 * txk - 1 - px;
    const float K[4] = {1.f, 3.f, 3.f, 1.f};
    const float* wp = W + ((size_t)o * 64 + c) * 9;
    float sacc = 0.f;
    #pragma unroll
    for (int a = 0; a < 3; ++a) {
        int ky = a + dy;
        if ((unsigned)ky >= 4u) continue;
        #pragma unroll
        for (int b2 = 0; b2 < 3; ++b2) {
            int kx = b2 + dx;
            if ((unsigned)kx >= 4u) continue;
            sacc += K[ky] * K[kx] * wp[a * 3 + b2];
        }
    }
    G2[i] = sacc * (1.f / 16.f);
}

// ---------------- 4x4 blur pad=2 (pre-down), batched ----------------
__global__ void blur_down(const float* __restrict__ in, float* __restrict__ out,
                          int H, int W, int tilesX, int tilesY,
                          long long inStr, long long outStr)
{
    int s = blockIdx.y;
    in  += (size_t)s * inStr;
    out += (size_t)s * outStr;
    int Ho = H + 1, Wo = W + 1;
    int bid = blockIdx.x;
    int tx = bid % tilesX; bid /= tilesX;
    int ty = bid % tilesY; bid /= tilesY;
    int p  = bid;
    int x = tx * 16 + (threadIdx.x & 15);
    int y = ty * 16 + (threadIdx.x >> 4);
    if (x >= Wo || y >= Ho) return;
    const float k[4] = {1.f, 3.f, 3.f, 1.f};
    const float* ip = in + (size_t)p * H * W;
    float acc = 0.f;
    #pragma unroll
    for (int ky = 0; ky < 4; ++ky) {
        int iy = y - 2 + ky;
        if ((unsigned)iy >= (unsigned)H) continue;
        float row = 0.f;
        #pragma unroll
        for (int kx = 0; kx < 4; ++kx) {
            int ix = x - 2 + kx;
            if ((unsigned)ix >= (unsigned)W) continue;
            row += ip[(size_t)iy * W + ix] * k[kx];
        }
        acc += row * k[ky];
    }
    out[((size_t)p * Ho + y) * Wo + x] = acc * (1.f / 64.f);
}

// ---------------- avg pool to 1x1 (64 planes), batched ----------------
__global__ void avgpool_hw(const float* __restrict__ in, float* __restrict__ out, int HW,
                           long long inStr, long long outStr)
{
    int s = blockIdx.y;
    in  += (size_t)s * inStr;
    out += (size_t)s * outStr;
    int p = blockIdx.x;
    const float* ip = in + (size_t)p * HW;
    float sum = 0.f;
    for (int i = threadIdx.x; i < HW; i += blockDim.x) sum += ip[i];
    __shared__ float red[256];
    red[threadIdx.x] = sum;
    __syncthreads();
    for (int off = 128; off; off >>= 1) {
        if ((int)threadIdx.x < off) red[threadIdx.x] += red[threadIdx.x + off];
        __syncthreads();
    }
    if (threadIdx.x == 0) out[p] = red[0] / (float)HW;
}

// ---------------- style FC (all 8 samples) ----------------
__global__ void style_fc(const float* __restrict__ s, const float* __restrict__ W,
                         const float* __restrict__ b, float* __restrict__ out, int outdim)
{
    int n = blockIdx.x;
    int i = threadIdx.x;
    if (i >= outdim) return;
    float acc = b[i];
    const float* sn = s + n * 64;
    const float* wi = W + i * 64;
    for (int f = 0; f < 64; ++f) acc += sn[f] * wi[f];
    out[n * 64 + i] = LRELU(acc);
}

// ------- modulate+demodulate (all 8 samples); transpose=1 -> [c][k][o] -------
__global__ void modulate(const float* __restrict__ w, const float* __restrict__ sw,
                         float* __restrict__ wout, int O, int C, int transpose)
{
    int no = blockIdx.x;
    int o = no % O, n = no / O;
    int nw = C * 9;
    int t = threadIdx.x;
    float v[9];
    int cnt = 0;
    float ss = 0.f;
    for (int idx = t; idx < nw; idx += 64) {
        int c = idx / 9;
        float val = w[o * nw + idx] * sw[n * 64 + c];
        v[cnt++] = val;
        ss += val * val;
    }
    #pragma unroll
    for (int off = 32; off; off >>= 1) ss += __shfl_xor(ss, off);
    float d = rsqrtf(ss + 1e-8f);
    cnt = 0;
    for (int idx = t; idx < nw; idx += 64) {
        float val = v[cnt++] * d;
        if (transpose)
            wout[(size_t)n * nw * O + (size_t)idx * O + o] = val;
        else
            wout[(size_t)no * nw + idx] = val;
    }
}

// ------- guide weight transpose -------
__global__ void guide_transpose(const float* __restrict__ grw, float* __restrict__ gt, int total)
{
    int i = blockIdx.x * 256 + threadIdx.x;
    if (i >= total) return;
    int l = i / 36864, rem = i % 36864;
    int idx = rem / 64, o = rem % 64;
    int c = idx / 9, k = idx % 9;
    gt[i] = grw[(((size_t)l * 64 + o) * 64 + c) * 9 + k];
}

// ------- g0 weight transpose -------
__global__ void g0_transpose(const float* __restrict__ g0w, float* __restrict__ gt)
{
    int i = blockIdx.x * 256 + threadIdx.x;
    if (i >= 1728) return;
    int idx = i / 64, o = i % 64;
    int c = idx / 9, k = idx % 9;
    gt[i] = g0w[((size_t)o * 3 + c) * 9 + k];
}

__global__ void fill_sentinel(float* __restrict__ out, int n)
{
    int i = blockIdx.x * 256 + threadIdx.x;
    if (i < n) out[i] = 1.0e9f;
}

extern "C" void kernel_launch(void* const* d_in, const int* in_sizes, int n_in,
                              void* d_out, int out_size, void* d_ws, size_t ws_size,
                              hipStream_t stream)
{
    const float* x     = (const float*)d_in[0];
    const float* ref   = (const float*)d_in[1];
    const float* g0w   = (const float*)d_in[2];
    const float* g0b   = (const float*)d_in[3];
    const float* grw   = (const float*)d_in[4];
    const float* grb   = (const float*)d_in[5];
    const float* c0w   = (const float*)d_in[6];
    const float* c0swW = (const float*)d_in[7];
    const float* c0swb = (const float*)d_in[8];
    const float* c0sbW = (const float*)d_in[9];
    const float* c0sbb = (const float*)d_in[10];
    const float* midw  = (const float*)d_in[11];
    const float* midswW= (const float*)d_in[12];
    const float* midswb= (const float*)d_in[13];
    const float* midsbW= (const float*)d_in[14];
    const float* midsbb= (const float*)d_in[15];
    const float* c6w   = (const float*)d_in[16];
    const float* c6swW = (const float*)d_in[17];
    const float* c6swb = (const float*)d_in[18];
    const float* c6sbW = (const float*)d_in[19];
    const float* c6sbb = (const float*)d_in[20];
    float* out = (float*)d_out;
    float* ws  = (float*)d_ws;

    // -------- shared region (floats) --------
    const size_t SV  = 0;
    const size_t STY = 512;
    const size_t WM  = 12800;
    const size_t GT  = 2989568;
    const size_t G0T = 3137024;
    const size_t BUF = 3138816;

    // -------- main-path per-sample slot offsets --------
    const size_t SA = 0;                  // [64,257,257]-class
    const size_t SB = 4227136;            // [64,256,256]
    const size_t D1 = 8421440;            // [64,128,128]
    const size_t D2 = 9470016;            // [64,128,128]
    const size_t D3 = 10518592;           // [64,129,129]-class
    const size_t E1 = 11583616;           // [64,64,64]
    const size_t E2 = 11845760;
    const size_t E3 = 12107904;
    const size_t G2o = 12370048;          // combined up-weights [147456]
    const long long PER = 12517504ll;     // ~50.1 MB per sample

    // -------- guide-phase per-sample slot offsets --------
    const size_t gSA = 0;
    const size_t gD1 = 4194304;
    const size_t gD2 = 5242880;
    const size_t gE1 = 6291456;
    const size_t gE2 = 6553600;
    const long long GPER = 6815744ll;

    int G = 0, GG = 0;
    for (int g = 8; g >= 1; --g)
        if ((BUF + (size_t)g * PER) * sizeof(float) <= ws_size) { G = g; break; }
    for (int g = 8; g >= 1; --g)
        if ((BUF + (size_t)g * GPER) * sizeof(float) <= ws_size) { GG = g; break; }
    if (!G || !GG) {
        fill_sentinel<<<dim3((out_size + 255) / 256), dim3(256), 0, stream>>>(out, out_size);
        return;
    }

    dim3 blk(256);
    const int LDS1 = 29952;
    const int LDSU = (4 * 6 * 20 + 4 * 2448) * 4;   // 41088 B

    float* B = ws + BUF;

    guide_transpose<<<dim3(147456 / 256), blk, 0, stream>>>(grw, ws + GT, 147456);
    g0_transpose<<<dim3(7), blk, 0, stream>>>(g0w, ws + G0T);

    // ==================== guide net ====================
    for (int n0 = 0; n0 < 8; ) {
        int g = (8 - n0 < GG) ? (8 - n0) : GG;
        const float* refg = ref + (size_t)n0 * 196608;
        conv3_gemm<<<dim3(16 * 16, g), blk, 0, stream>>>(
            refg, ws + G0T, g0b, B + gSA, 256, 256, 16, 196608, 0, 0, GPER);
        conv64s2_gemm8<<<dim3(16 * 16, g), blk, 0, stream>>>(
            B + gSA, ws + GT, grb, B + gD1, 256, 256, 128, 128, 1, 1, 16, GPER, 0, 0, GPER);
        conv64_gemm8<<<dim3(16 * 16, g), blk, 0, stream>>>(
            B + gD1, ws + GT + 36864, grb + 64, B + gD2, 128, 128, 1, 16, GPER, 0, 0, GPER);
        conv64s2_gemm8<<<dim3(8 * 8, g), blk, 0, stream>>>(
            B + gD2, ws + GT + 73728, grb + 128, B + gE1, 128, 128, 64, 64, 1, 1, 8, GPER, 0, 0, GPER);
        conv64_gemm8<<<dim3(8 * 8, g), blk, 0, stream>>>(
            B + gE1, ws + GT + 110592, grb + 192, B + gE2, 64, 64, 0, 8, GPER, 0, 0, GPER);
        avgpool_hw<<<dim3(64, g), blk, 0, stream>>>(B + gE2, ws + SV + (size_t)n0 * 64, 4096, GPER, 64);
        n0 += g;
    }

    // ==================== styles + modulated weights ====================
    const float* Wt[12];  const float* swWp[12]; const float* swbp[12];
    const float* sbWp[12]; const float* sbbp[12];
    int Ci[12], Oi[12];
    size_t wmo[12];
    Wt[0] = c0w; swWp[0] = c0swW; swbp[0] = c0swb; sbWp[0] = c0sbW; sbbp[0] = c0sbb;
    Ci[0] = 3; Oi[0] = 64; wmo[0] = WM;
    for (int i = 0; i < 10; ++i) {
        Wt[1 + i]   = midw   + (size_t)i * 36864;
        swWp[1 + i] = midswW + (size_t)i * 4096;
        swbp[1 + i] = midswb + (size_t)i * 64;
        sbWp[1 + i] = midsbW + (size_t)i * 4096;
        sbbp[1 + i] = midsbb + (size_t)i * 64;
        Ci[1 + i] = 64; Oi[1 + i] = 64;
        wmo[1 + i] = WM + 13824ull + (size_t)i * 294912ull;
    }
    Wt[11] = c6w; swWp[11] = c6swW; swbp[11] = c6swb; sbWp[11] = c6sbW; sbbp[11] = c6sbb;
    Ci[11] = 64; Oi[11] = 3; wmo[11] = WM + 13824ull + 2949120ull;

    const int trf[12] = {1, 1, 1, 1, 1, 1, 1, 0, 1, 0, 1, 1};

    for (int i = 0; i < 12; ++i) {
        style_fc<<<dim3(8), dim3(64), 0, stream>>>(ws + SV, swWp[i], swbp[i], ws + STY + i * 1024, Ci[i]);
        style_fc<<<dim3(8), dim3(64), 0, stream>>>(ws + SV, sbWp[i], sbbp[i], ws + STY + i * 1024 + 512, Oi[i]);
        modulate<<<dim3(8 * Oi[i]), dim3(64), 0, stream>>>(Wt[i], ws + STY + i * 1024, ws + wmo[i], Oi[i], Ci[i], trf[i]);
    }

    // ==================== main path ====================
    for (int n0 = 0; n0 < 8; ) {
        int g = (8 - n0 < G) ? (8 - n0) : G;
        const float* xg = x + (size_t)n0 * 196608;
        float* outg = out + (size_t)n0 * 196608;
        #define WN(i)  (ws + wmo[i] + (size_t)n0 * Oi[i] * Ci[i] * 9)
        #define WSTR(i) ((long long)(Oi[i] * Ci[i] * 9))
        #define SBN(i) (ws + STY + (i) * 1024 + 512 + (size_t)n0 * 64)
        // f0 -> SB
        conv3_gemm<<<dim3(16 * 16, g), blk, 0, stream>>>(
            xg, WN(0), SBN(0), B + SB, 256, 256, 16, 196608, WSTR(0), 64, PER);
        // f1 down: blur(SB) -> SA; conv s2 -> D1; conv -> D2
        blur_down<<<dim3(64 * 17 * 17, g), blk, 0, stream>>>(B + SB, B + SA, 256, 256, 17, 17, PER, PER);
        conv64s2_gemm8<<<dim3(16 * 16, g), blk, 0, stream>>>(
            B + SA, WN(1), SBN(1), B + D1, 257, 257, 128, 128, 0, 1, 16, PER, WSTR(1), 64, PER);
        conv64_gemm8<<<dim3(16 * 16, g), blk, 0, stream>>>(
            B + D1, WN(2), SBN(2), B + D2, 128, 128, 1, 16, PER, WSTR(2), 64, PER);
        // f2 down
        blur_down<<<dim3(64 * 9 * 9, g), blk, 0, stream>>>(B + D2, B + D3, 128, 128, 9, 9, PER, PER);
        conv64s2_gemm8<<<dim3(8 * 8, g), blk, 0, stream>>>(
            B + D3, WN(3), SBN(3), B + E1, 129, 129, 64, 64, 0, 1, 8, PER, WSTR(3), 64, PER);
        conv64_gemm8<<<dim3(8 * 8, g), blk, 0, stream>>>(
            B + E1, WN(4), SBN(4), B + E2, 64, 64, 1, 8, PER, WSTR(4), 64, PER);
        // f3 x2
        conv64_gemm8<<<dim3(8 * 8, g), blk, 0, stream>>>(
            B + E2, WN(5), SBN(5), B + E3, 64, 64, 1, 8, PER, WSTR(5), 64, PER);
        conv64_gemm8<<<dim3(8 * 8, g), blk, 0, stream>>>(
            B + E3, WN(6), SBN(6), B + E1, 64, 64, 1, 8, PER, WSTR(6), 64, PER);
        // f4 up (fused): combine -> G2o; upconv(f3+f2) -> D1 (128^2, tiles 4x16); conv -> D3
        combine_up_w<<<dim3(576, g), blk, 0, stream>>>(WN(7), B + G2o, WSTR(7), PER);
        upconv64_gemm<<<dim3(4 * 16, g), blk, LDSU, stream>>>(
            B + E1, B + E2, B + G2o, SBN(7), B + D1, 64, 64, 4, PER, 64, PER);
        conv64_gemm8<<<dim3(16 * 16, g), blk, 0, stream>>>(
            B + D1, WN(8), SBN(8), B + D3, 128, 128, 1, 16, PER, WSTR(8), 64, PER);
        // f5 up: combine -> G2o; upconv(f4+f1) -> SA (256^2, tiles 8x32); conv -> SB
        combine_up_w<<<dim3(576, g), blk, 0, stream>>>(WN(9), B + G2o, WSTR(9), PER);
        upconv64_gemm<<<dim3(8 * 32, g), blk, LDSU, stream>>>(
            B + D3, B + D2, B + G2o, SBN(9), B + SA, 128, 128, 8, PER, 64, PER);
        conv64_gemm<1><<<dim3(16 * 16, g), blk, LDS1, stream>>>(
            B + SA, WN(10), SBN(10), B + SB, 256, 256, 256, 256, 1, 1, 16, PER, WSTR(10), 64, PER);
        // recompute f0 -> SA
        conv3_gemm<<<dim3(16 * 16, g), blk, 0, stream>>>(
            xg, WN(0), SBN(0), B + SA, 256, 256, 16, 196608, WSTR(0), 64, PER);
        // c6: conv(f5 + f0) -> out
        conv64to3_gemm<<<dim3(16 * 16, g), blk, 0, stream>>>(
            B + SB, B + SA, WN(11), SBN(11), outg, 256, 256, 16, PER, WSTR(11), 64, 196608);
        #undef WN
        #undef WSTR
        #undef SBN
        n0 += g;
    }
}

// Round 12
// 3945.235 us; speedup vs baseline: 9.3959x; 1.0905x over previous
//
#include <hip/hip_runtime.h>

#define LRELU(v) ((v) >= 0.f ? (v) : 0.2f * (v))

// ================= implicit-GEMM 3x3 conv, C=64 -> O=64, 16x16 tile (stride 1) =================
template<int S>
__global__ void conv64_gemm(const float* __restrict__ in, const float* __restrict__ Wt,
                            const float* __restrict__ bias, float* __restrict__ out,
                            int Hin, int Win, int Hout, int Wout, int pad, int act, int tilesX,
                            long long inStr, long long wStr, long long bStr, long long outStr)
{
    constexpr int CC  = (S == 1) ? 8 : 4;
    constexpr int TIN = (S == 1) ? 18 : 33;
    constexpr int RS  = (S == 1) ? 20 : 36;
    constexpr int NF4 = (S == 1) ? 3 : 5;
    constexpr int PW  = NF4 * 4;
    extern __shared__ float lds[];
    float* it = lds;
    float* wl = lds + CC * TIN * RS;

    int s = blockIdx.y;
    in   += (size_t)s * inStr;
    Wt   += (size_t)s * wStr;
    bias += (size_t)s * bStr;
    out  += (size_t)s * outStr;

    int b  = blockIdx.x;
    int tx = b % tilesX, ty = b / tilesX;
    int t  = threadIdx.x;
    int og = t >> 5;
    int pg = t & 31;
    int r  = pg >> 1, ch = pg & 1;

    float acc[8][8];
    #pragma unroll
    for (int i = 0; i < 8; ++i)
        #pragma unroll
        for (int j = 0; j < 8; ++j) acc[i][j] = 0.f;

    const int y0 = ty * 16 * S - pad;
    const int x0 = tx * 16 * S - pad;
    const size_t plane = (size_t)Hin * Win;

    for (int c0 = 0; c0 < 64; c0 += CC) {
        __syncthreads();
        {
            const float4* src = (const float4*)(Wt + c0 * 9 * 64);
            float4* dst = (float4*)wl;
            for (int i = t; i < CC * 9 * 16; i += 256) dst[i] = src[i];
        }
        for (int rowi = t; rowi < CC * TIN; rowi += 256) {
            int cc = rowi / TIN, rr = rowi - cc * TIN;
            int iy = y0 + rr;
            float* dst = it + (size_t)rowi * RS;
            const float* srow = in + (size_t)(c0 + cc) * plane + (size_t)iy * Win + x0;
            if ((unsigned)iy < (unsigned)Hin && x0 >= 0 && x0 + RS <= Win) {
                #pragma unroll
                for (int q = 0; q < RS / 4; ++q)
                    ((float4*)dst)[q] = ((const float4*)srow)[q];
            } else {
                for (int cl = 0; cl < TIN; ++cl) {
                    int ix = x0 + cl;
                    float v = 0.f;
                    if ((unsigned)iy < (unsigned)Hin && (unsigned)ix < (unsigned)Win)
                        v = in[(size_t)(c0 + cc) * plane + (size_t)iy * Win + ix];
                    dst[cl] = v;
                }
            }
        }
        __syncthreads();
        for (int cc = 0; cc < CC; ++cc) {
            const float* base = it + cc * TIN * RS;
            #pragma unroll
            for (int ky = 0; ky < 3; ++ky) {
                float p[PW];
                const float* rowp = base + (r * S + ky) * RS + ch * 8 * S;
                #pragma unroll
                for (int q = 0; q < NF4; ++q) {
                    float4 f = *(const float4*)(rowp + q * 4);
                    p[q*4+0] = f.x; p[q*4+1] = f.y; p[q*4+2] = f.z; p[q*4+3] = f.w;
                }
                #pragma unroll
                for (int kx = 0; kx < 3; ++kx) {
                    const float* wp = wl + ((cc * 9) + ky * 3 + kx) * 64 + og * 8;
                    float4 wa = *(const float4*)wp;
                    float4 wb = *(const float4*)(wp + 4);
                    float w8[8] = {wa.x, wa.y, wa.z, wa.w, wb.x, wb.y, wb.z, wb.w};
                    #pragma unroll
                    for (int oi = 0; oi < 8; ++oi)
                        #pragma unroll
                        for (int j = 0; j < 8; ++j)
                            acc[oi][j] += w8[oi] * p[j * S + kx];
                }
            }
        }
    }

    int y  = ty * 16 + r;
    int xb = tx * 16 + ch * 8;
    #pragma unroll
    for (int oi = 0; oi < 8; ++oi) {
        int o = og * 8 + oi;
        float bo = bias[o];
        float v[8];
        #pragma unroll
        for (int j = 0; j < 8; ++j) {
            float a = acc[oi][j] + bo;
            v[j] = act ? LRELU(a) : a;
        }
        float* op = out + ((size_t)o * Hout + y) * Wout + xb;
        *(float4*)op       = make_float4(v[0], v[1], v[2], v[3]);
        *(float4*)(op + 4) = make_float4(v[4], v[5], v[6], v[7]);
    }
}

// ======== implicit-GEMM 3x3 conv, C=64 -> O=64, stride1 pad1, 8x8 tile ========
__global__ void conv64_gemm8(const float* __restrict__ in, const float* __restrict__ Wt,
                             const float* __restrict__ bias, float* __restrict__ out,
                             int H, int W, int act, int tilesX,
                             long long inStr, long long wStr, long long bStr, long long outStr)
{
    constexpr int CC = 8, TIN = 10, RS = 12;
    __shared__ float it[CC * TIN * RS];
    __shared__ float wl[CC * 9 * 64];
    int s = blockIdx.y;
    in   += (size_t)s * inStr;
    Wt   += (size_t)s * wStr;
    bias += (size_t)s * bStr;
    out  += (size_t)s * outStr;

    int b  = blockIdx.x;
    int tx = b % tilesX, ty = b / tilesX;
    int t  = threadIdx.x;
    int og = t >> 5, pg = t & 31;
    int r  = pg >> 2, ch = pg & 3;

    float acc[8][2];
    #pragma unroll
    for (int i = 0; i < 8; ++i) { acc[i][0] = 0.f; acc[i][1] = 0.f; }

    const int y0 = ty * 8 - 1, x0 = tx * 8 - 1;
    const size_t plane = (size_t)H * W;

    for (int c0 = 0; c0 < 64; c0 += CC) {
        __syncthreads();
        {
            const float4* src = (const float4*)(Wt + c0 * 9 * 64);
            float4* dst = (float4*)wl;
            for (int i = t; i < CC * 9 * 16; i += 256) dst[i] = src[i];
        }
        for (int rowi = t; rowi < CC * TIN; rowi += 256) {
            int cc = rowi / TIN, rr = rowi - cc * TIN;
            int iy = y0 + rr;
            float* dst = it + rowi * RS;
            const float* srow = in + (size_t)(c0 + cc) * plane + (size_t)iy * W + x0;
            if ((unsigned)iy < (unsigned)H && x0 >= 0 && x0 + RS <= W) {
                #pragma unroll
                for (int q = 0; q < 3; ++q)
                    ((float4*)dst)[q] = ((const float4*)srow)[q];
            } else {
                for (int cl = 0; cl < RS; ++cl) {
                    int ix = x0 + cl;
                    float v = 0.f;
                    if (cl < TIN && (unsigned)iy < (unsigned)H && (unsigned)ix < (unsigned)W)
                        v = in[(size_t)(c0 + cc) * plane + (size_t)iy * W + ix];
                    dst[cl] = v;
                }
            }
        }
        __syncthreads();
        for (int cc = 0; cc < CC; ++cc) {
            const float* base = it + cc * TIN * RS;
            #pragma unroll
            for (int ky = 0; ky < 3; ++ky) {
                const float* rowp = base + (r + ky) * RS + ch * 2;
                float p[4] = {rowp[0], rowp[1], rowp[2], rowp[3]};
                #pragma unroll
                for (int kx = 0; kx < 3; ++kx) {
                    const float* wp = wl + ((cc * 9) + ky * 3 + kx) * 64 + og * 8;
                    float4 wa = *(const float4*)wp;
                    float4 wb = *(const float4*)(wp + 4);
                    float w8[8] = {wa.x, wa.y, wa.z, wa.w, wb.x, wb.y, wb.z, wb.w};
                    #pragma unroll
                    for (int oi = 0; oi < 8; ++oi) {
                        acc[oi][0] += w8[oi] * p[kx];
                        acc[oi][1] += w8[oi] * p[kx + 1];
                    }
                }
            }
        }
    }

    int y = ty * 8 + r, xb = tx * 8 + ch * 2;
    #pragma unroll
    for (int oi = 0; oi < 8; ++oi) {
        int o = og * 8 + oi;
        float bo = bias[o];
        float a0 = acc[oi][0] + bo, a1 = acc[oi][1] + bo;
        if (act) { a0 = LRELU(a0); a1 = LRELU(a1); }
        *(float2*)(out + ((size_t)o * H + y) * W + xb) = make_float2(a0, a1);
    }
}

// ======== implicit-GEMM 3x3 conv, C=64 -> O=64, stride2, 8x8 out tile ========
__global__ void conv64s2_gemm8(const float* __restrict__ in, const float* __restrict__ Wt,
                               const float* __restrict__ bias, float* __restrict__ out,
                               int Hin, int Win, int Hout, int Wout, int pad, int act, int tilesX,
                               long long inStr, long long wStr, long long bStr, long long outStr)
{
    constexpr int CC = 8, TIN = 18, RS = 20;
    __shared__ float it[CC * TIN * RS];   // 2880
    __shared__ float wl[CC * 9 * 64];     // 4608
    int s = blockIdx.y;
    in   += (size_t)s * inStr;
    Wt   += (size_t)s * wStr;
    bias += (size_t)s * bStr;
    out  += (size_t)s * outStr;

    int b  = blockIdx.x;
    int tx = b % tilesX, ty = b / tilesX;
    int t  = threadIdx.x;
    int og = t >> 5, pg = t & 31;
    int r  = pg >> 2, ch = pg & 3;        // out row 0..7, col pair 0..3

    float acc[8][2];
    #pragma unroll
    for (int i = 0; i < 8; ++i) { acc[i][0] = 0.f; acc[i][1] = 0.f; }

    const int y0 = ty * 16 - pad, x0 = tx * 16 - pad;
    const size_t plane = (size_t)Hin * Win;

    for (int c0 = 0; c0 < 64; c0 += CC) {
        __syncthreads();
        {
            const float4* src = (const float4*)(Wt + c0 * 9 * 64);
            float4* dst = (float4*)wl;
            for (int i = t; i < CC * 9 * 16; i += 256) dst[i] = src[i];
        }
        for (int rowi = t; rowi < CC * TIN; rowi += 256) {
            int cc = rowi / TIN, rr = rowi - cc * TIN;
            int iy = y0 + rr;
            float* dst = it + rowi * RS;
            const float* srow = in + (size_t)(c0 + cc) * plane + (size_t)iy * Win + x0;
            if ((unsigned)iy < (unsigned)Hin && x0 >= 0 && x0 + RS <= Win) {
                #pragma unroll
                for (int q = 0; q < RS / 4; ++q)
                    ((float4*)dst)[q] = ((const float4*)srow)[q];
            } else {
                for (int cl = 0; cl < RS; ++cl) {
                    int ix = x0 + cl;
                    float v = 0.f;
                    if (cl < TIN && (unsigned)iy < (unsigned)Hin && (unsigned)ix < (unsigned)Win)
                        v = in[(size_t)(c0 + cc) * plane + (size_t)iy * Win + ix];
                    dst[cl] = v;
                }
            }
        }
        __syncthreads();
        for (int cc = 0; cc < CC; ++cc) {
            const float* base = it + cc * TIN * RS;
            #pragma unroll
            for (int ky = 0; ky < 3; ++ky) {
                const float* rowp = base + (2 * r + ky) * RS + ch * 4;
                float4 f0 = *(const float4*)rowp;
                float4 f1 = *(const float4*)(rowp + 4);
                float p[8] = {f0.x, f0.y, f0.z, f0.w, f1.x, f1.y, f1.z, f1.w};
                #pragma unroll
                for (int kx = 0; kx < 3; ++kx) {
                    const float* wp = wl + ((cc * 9) + ky * 3 + kx) * 64 + og * 8;
                    float4 wa = *(const float4*)wp;
                    float4 wb = *(const float4*)(wp + 4);
                    float w8[8] = {wa.x, wa.y, wa.z, wa.w, wb.x, wb.y, wb.z, wb.w};
                    #pragma unroll
                    for (int oi = 0; oi < 8; ++oi) {
                        acc[oi][0] += w8[oi] * p[kx];
                        acc[oi][1] += w8[oi] * p[kx + 2];
                    }
                }
            }
        }
    }

    int y = ty * 8 + r, xb = tx * 8 + ch * 2;
    #pragma unroll
    for (int oi = 0; oi < 8; ++oi) {
        int o = og * 8 + oi;
        float bo = bias[o];
        float a0 = acc[oi][0] + bo, a1 = acc[oi][1] + bo;
        if (act) { a0 = LRELU(a0); a1 = LRELU(a1); }
        *(float2*)(out + ((size_t)o * Hout + y) * Wout + xb) = make_float2(a0, a1);
    }
}

// ========== implicit-GEMM 3x3 conv, C=3 -> O=64, stride1 pad1 (g0 guide, f0) ==========
__global__ void conv3_gemm(const float* __restrict__ in, const float* __restrict__ Wt,
                           const float* __restrict__ bias, float* __restrict__ out,
                           int H, int W, int tilesX,
                           long long inStr, long long wStr, long long bStr, long long outStr)
{
    constexpr int TIN = 18, RS = 20;
    __shared__ float it[3 * TIN * RS];
    __shared__ float wl[27 * 64];
    int s = blockIdx.y;
    in   += (size_t)s * inStr;
    Wt   += (size_t)s * wStr;
    bias += (size_t)s * bStr;
    out  += (size_t)s * outStr;

    int b  = blockIdx.x;
    int tx = b % tilesX, ty = b / tilesX;
    int t  = threadIdx.x;
    {
        const float4* src = (const float4*)Wt;
        float4* dst = (float4*)wl;
        for (int i = t; i < 27 * 16; i += 256) dst[i] = src[i];
    }
    const int y0 = ty * 16 - 1, x0 = tx * 16 - 1;
    const size_t plane = (size_t)H * W;
    for (int rowi = t; rowi < 3 * TIN; rowi += 256) {
        int cc = rowi / TIN, rr = rowi - cc * TIN;
        int iy = y0 + rr;
        float* dst = it + (size_t)rowi * RS;
        const float* srow = in + (size_t)cc * plane + (size_t)iy * W + x0;
        if ((unsigned)iy < (unsigned)H && x0 >= 0 && x0 + RS <= W) {
            #pragma unroll
            for (int q = 0; q < RS / 4; ++q)
                ((float4*)dst)[q] = ((const float4*)srow)[q];
        } else {
            for (int cl = 0; cl < TIN; ++cl) {
                int ix = x0 + cl;
                float v = 0.f;
                if ((unsigned)iy < (unsigned)H && (unsigned)ix < (unsigned)W)
                    v = in[(size_t)cc * plane + (size_t)iy * W + ix];
                dst[cl] = v;
            }
        }
    }
    __syncthreads();

    int og = t >> 5, pg = t & 31;
    int r  = pg >> 1, ch = pg & 1;
    float acc[8][8];
    #pragma unroll
    for (int i = 0; i < 8; ++i)
        #pragma unroll
        for (int j = 0; j < 8; ++j) acc[i][j] = 0.f;

    for (int c = 0; c < 3; ++c) {
        const float* base = it + c * TIN * RS;
        #pragma unroll
        for (int ky = 0; ky < 3; ++ky) {
            float p[12];
            const float* rowp = base + (r + ky) * RS + ch * 8;
            #pragma unroll
            for (int q = 0; q < 3; ++q) {
                float4 f = *(const float4*)(rowp + q * 4);
                p[q*4+0] = f.x; p[q*4+1] = f.y; p[q*4+2] = f.z; p[q*4+3] = f.w;
            }
            #pragma unroll
            for (int kx = 0; kx < 3; ++kx) {
                const float* wp = wl + ((c * 9) + ky * 3 + kx) * 64 + og * 8;
                float4 wa = *(const float4*)wp;
                float4 wb = *(const float4*)(wp + 4);
                float w8[8] = {wa.x, wa.y, wa.z, wa.w, wb.x, wb.y, wb.z, wb.w};
                #pragma unroll
                for (int oi = 0; oi < 8; ++oi)
                    #pragma unroll
                    for (int j = 0; j < 8; ++j)
                        acc[oi][j] += w8[oi] * p[j + kx];
            }
        }
    }

    int y  = ty * 16 + r;
    int xb = tx * 16 + ch * 8;
    #pragma unroll
    for (int oi = 0; oi < 8; ++oi) {
        int o = og * 8 + oi;
        float bo = bias[o];
        float v[8];
        #pragma unroll
        for (int j = 0; j < 8; ++j) {
            float a = acc[oi][j] + bo;
            v[j] = LRELU(a);
        }
        float* op = out + ((size_t)o * H + y) * W + xb;
        *(float4*)op       = make_float4(v[0], v[1], v[2], v[3]);
        *(float4*)(op + 4) = make_float4(v[4], v[5], v[6], v[7]);
    }
}

// ========== implicit-GEMM 3x3 conv, C=64 -> O=3, (in1+in2), no act (c6) ==========
__global__ void conv64to3_gemm(const float* __restrict__ in, const float* __restrict__ in2,
                               const float* __restrict__ Wt, const float* __restrict__ sb,
                               float* __restrict__ out, int H, int W, int tilesX,
                               long long inStr, long long wStr, long long sbStr, long long outStr)
{
    constexpr int CC = 8, TIN = 18, RS = 20;
    __shared__ float it[CC * TIN * RS];
    __shared__ float wl[CC * 9 * 3];
    int s = blockIdx.y;
    in  += (size_t)s * inStr;
    in2 += (size_t)s * inStr;
    Wt  += (size_t)s * wStr;
    sb  += (size_t)s * sbStr;
    out += (size_t)s * outStr;

    int b  = blockIdx.x;
    int tx = b % tilesX, ty = b / tilesX;
    int t  = threadIdx.x;
    int r  = t >> 4, cl = t & 15;
    const int y0 = ty * 16 - 1, x0 = tx * 16 - 1;
    const size_t plane = (size_t)H * W;

    float acc[3] = {0.f, 0.f, 0.f};

    for (int c0 = 0; c0 < 64; c0 += CC) {
        __syncthreads();
        for (int i = t; i < CC * 9 * 3; i += 256) wl[i] = Wt[c0 * 27 + i];
        for (int rowi = t; rowi < CC * TIN; rowi += 256) {
            int cc = rowi / TIN, rr = rowi - cc * TIN;
            int iy = y0 + rr;
            float* dst = it + (size_t)rowi * RS;
            size_t roff = (size_t)(c0 + cc) * plane + (size_t)iy * W + x0;
            if ((unsigned)iy < (unsigned)H && x0 >= 0 && x0 + RS <= W) {
                #pragma unroll
                for (int q = 0; q < RS / 4; ++q) {
                    float4 a = ((const float4*)(in  + roff))[q];
                    float4 bb = ((const float4*)(in2 + roff))[q];
                    ((float4*)dst)[q] = make_float4(a.x + bb.x, a.y + bb.y, a.z + bb.z, a.w + bb.w);
                }
            } else {
                for (int c2 = 0; c2 < TIN; ++c2) {
                    int ix = x0 + c2;
                    float v = 0.f;
                    if ((unsigned)iy < (unsigned)H && (unsigned)ix < (unsigned)W) {
                        size_t off = (size_t)(c0 + cc) * plane + (size_t)iy * W + ix;
                        v = in[off] + in2[off];
                    }
                    dst[c2] = v;
                }
            }
        }
        __syncthreads();
        for (int cc = 0; cc < CC; ++cc) {
            const float* base = it + cc * TIN * RS;
            #pragma unroll
            for (int ky = 0; ky < 3; ++ky) {
                const float* rowp = base + (r + ky) * RS + cl;
                float p0 = rowp[0], p1 = rowp[1], p2 = rowp[2];
                const float* wr = wl + (cc * 9 + ky * 3) * 3;
                #pragma unroll
                for (int o = 0; o < 3; ++o)
                    acc[o] += wr[o] * p0 + wr[3 + o] * p1 + wr[6 + o] * p2;
            }
        }
    }

    int y = ty * 16 + r, x = tx * 16 + cl;
    #pragma unroll
    for (int o = 0; o < 3; ++o)
        out[((size_t)o * H + y) * W + x] = acc[o] + sb[o];
}

// ===== fused up-conv: tconv(s2,3x3)+blur(4x4,x4/64)+bias+lrelu, 32x8 tile, LDS-staged stores =====
// lane map: t = og[0:2] | pxb[3] | xh[4] | r[5:7].
// Output staged in LDS [r*8+og][33] then written cooperatively: lane t stores float4 at
// linear offset 4t -> 8 consecutive lanes = one full 128B line per instruction.
__global__ void upconv64_gemm(const float* __restrict__ in, const float* __restrict__ in2,
                              const float* __restrict__ G2, const float* __restrict__ sb,
                              float* __restrict__ out, int Hin, int Win, int tilesX,
                              long long bufStr, long long sbStr, long long outStr)
{
    constexpr int CC = 4;
    constexpr int RS = 20;                    // 18-col window, padded
    constexpr int PSTR = 68;                  // padded parity stride (floats)
    extern __shared__ float lds[];
    float* it  = lds;                         // [CC][6][RS] = 480
    float* wl  = lds + CC * 6 * RS;           // [CC][9][4][PSTR] = CC*2448
    float* ost = wl + CC * 2448;              // [64][33] = 2112

    int s = blockIdx.y;
    in  += (size_t)s * bufStr;
    in2 += (size_t)s * bufStr;
    G2  += (size_t)s * bufStr;
    sb  += (size_t)s * sbStr;
    out += (size_t)s * outStr;

    int b  = blockIdx.x;
    int tx = b % tilesX, ty = b / tilesX;
    int t  = threadIdx.x;
    int og  = t & 7;
    int pxb = (t >> 3) & 1;
    int xh  = (t >> 4) & 1;
    int r   = t >> 5;                         // out row 0..7
    int rhalf = r >> 1, rpar = r & 1;
    const int Y0 = ty * 8, X0 = tx * 32;
    const int gy0 = Y0 / 2 - 1;
    const int gx0 = X0 / 2 - 1;
    const size_t plane = (size_t)Hin * Win;

    float acc[8][8];
    #pragma unroll
    for (int i = 0; i < 8; ++i)
        #pragma unroll
        for (int j = 0; j < 8; ++j) acc[i][j] = 0.f;

    for (int c0 = 0; c0 < 64; c0 += CC) {
        __syncthreads();
        {
            const float4* src = (const float4*)(G2 + (size_t)c0 * 2304);
            for (int i = t; i < CC * 36 * 16; i += 256) {
                int row = i >> 4, q = i & 15;
                ((float4*)(wl + row * PSTR))[q] = src[i];
            }
        }
        for (int rowi = t; rowi < CC * 6; rowi += 256) {
            int cc = rowi / 6, rr = rowi - cc * 6;
            int gi = gy0 + rr;
            float* dst = it + (size_t)rowi * RS;
            size_t roff = (size_t)(c0 + cc) * plane + (size_t)gi * Win + gx0;
            if ((unsigned)gi < (unsigned)Hin && gx0 >= 0 && gx0 + RS <= Win) {
                #pragma unroll
                for (int qq = 0; qq < 5; ++qq) {
                    float4 a = ((const float4*)(in  + roff))[qq];
                    float4 bb = ((const float4*)(in2 + roff))[qq];
                    ((float4*)dst)[qq] = make_float4(a.x + bb.x, a.y + bb.y, a.z + bb.z, a.w + bb.w);
                }
            } else {
                for (int cl = 0; cl < RS; ++cl) {
                    int gj = gx0 + cl;
                    float v = 0.f;
                    if (cl < 18 && (unsigned)gi < (unsigned)Hin && (unsigned)gj < (unsigned)Win) {
                        size_t off = (size_t)(c0 + cc) * plane + (size_t)gi * Win + gj;
                        v = in[off] + in2[off];
                    }
                    dst[cl] = v;
                }
            }
        }
        __syncthreads();
        for (int cc = 0; cc < CC; ++cc) {
            const float* ib = it + cc * 6 * RS;
            const float* wcb = wl + cc * (36 * PSTR) + (rpar * 2 + pxb) * PSTR;
            #pragma unroll
            for (int ty2 = 0; ty2 < 3; ++ty2) {
                float p[12];
                const float* rowp = ib + (rhalf + ty2) * RS + xh * 8;
                #pragma unroll
                for (int qq = 0; qq < 3; ++qq) {
                    float4 f = *(const float4*)(rowp + qq * 4);
                    p[qq*4+0] = f.x; p[qq*4+1] = f.y; p[qq*4+2] = f.z; p[qq*4+3] = f.w;
                }
                #pragma unroll
                for (int tx2 = 0; tx2 < 3; ++tx2) {
                    const float* wp = wcb + (ty2 * 3 + tx2) * (4 * PSTR) + og * 8;
                    float4 wa = *(const float4*)wp;
                    float4 wv = *(const float4*)(wp + 4);
                    float w8[8] = {wa.x, wa.y, wa.z, wa.w, wv.x, wv.y, wv.z, wv.w};
                    #pragma unroll
                    for (int oi = 0; oi < 8; ++oi)
                        #pragma unroll
                        for (int k = 0; k < 8; ++k)
                            acc[oi][k] += w8[oi] * p[k + tx2];
                }
            }
        }
    }

    const int Hout = 2 * Hin, Wout = 2 * Win;
    const int obase = (r * 8 + og) * 33 + xh * 16 + pxb;
    #pragma unroll
    for (int oi = 0; oi < 8; ++oi) {
        int o = og * 8 + oi;
        float bo = sb[o];
        __syncthreads();                       // previous oi's readers done
        #pragma unroll
        for (int k = 0; k < 8; ++k) {
            float a = acc[oi][k] + bo;
            ost[obase + 2 * k] = LRELU(a);
        }
        __syncthreads();
        // cooperative coalesced write: 512 float4s over [og8][r8][x4 8]
        #pragma unroll
        for (int p2 = 0; p2 < 2; ++p2) {
            int j4 = p2 * 256 + t;
            int ogr = j4 >> 6;
            int rr  = (j4 >> 3) & 7;
            int x4  = j4 & 7;
            const float* sp = ost + (rr * 8 + ogr) * 33 + x4 * 4;
            float4 f = make_float4(sp[0], sp[1], sp[2], sp[3]);
            int oo = ogr * 8 + oi;
            *(float4*)(out + ((size_t)oo * Hout + Y0 + rr) * Wout + X0 + x4 * 4) = f;
        }
    }
}

// ------- build combined up-weights, layout [c][tap][parity][o] -------
__global__ void combine_up_w(const float* __restrict__ W, float* __restrict__ G2,
                             long long wStr, long long g2Str)
{
    int s = blockIdx.y;
    W  += (size_t)s * wStr;
    G2 += (size_t)s * g2Str;
    int i = blockIdx.x * 256 + threadIdx.x;
    if (i >= 147456) return;
    int o = i & 63;
    int rest = i >> 6;            // (c*9 + k)*4 + p
    int p4 = rest & 3;
    int k9 = (rest >> 2) % 9;
    int c  = (rest >> 2) / 9;
    int py = p4 >> 1, px = p4 & 1;
    int tyk = k9 / 3, txk = k9 % 3;
    int dy = 2 * tyk - 1 - py, dx = 2 * txk - 1 - px;
    const float K[4] = {1.f, 3.f, 3.f, 1.f};
    const float* wp = W + ((size_t)o * 64 + c) * 9;
    float sacc = 0.f;
    #pragma unroll
    for (int a = 0; a < 3; ++a) {
        int ky = a + dy;
        if ((unsigned)ky >= 4u) continue;
        #pragma unroll
        for (int b2 = 0; b2 < 3; ++b2) {
            int kx = b2 + dx;
            if ((unsigned)kx >= 4u) continue;
            sacc += K[ky] * K[kx] * wp[a * 3 + b2];
        }
    }
    G2[i] = sacc * (1.f / 16.f);
}

// ---------------- 4x4 blur pad=2 (pre-down), batched ----------------
__global__ void blur_down(const float* __restrict__ in, float* __restrict__ out,
                          int H, int W, int tilesX, int tilesY,
                          long long inStr, long long outStr)
{
    int s = blockIdx.y;
    in  += (size_t)s * inStr;
    out += (size_t)s * outStr;
    int Ho = H + 1, Wo = W + 1;
    int bid = blockIdx.x;
    int tx = bid % tilesX; bid /= tilesX;
    int ty = bid % tilesY; bid /= tilesY;
    int p  = bid;
    int x = tx * 16 + (threadIdx.x & 15);
    int y = ty * 16 + (threadIdx.x >> 4);
    if (x >= Wo || y >= Ho) return;
    const float k[4] = {1.f, 3.f, 3.f, 1.f};
    const float* ip = in + (size_t)p * H * W;
    float acc = 0.f;
    #pragma unroll
    for (int ky = 0; ky < 4; ++ky) {
        int iy = y - 2 + ky;
        if ((unsigned)iy >= (unsigned)H) continue;
        float row = 0.f;
        #pragma unroll
        for (int kx = 0; kx < 4; ++kx) {
            int ix = x - 2 + kx;
            if ((unsigned)ix >= (unsigned)W) continue;
            row += ip[(size_t)iy * W + ix] * k[kx];
        }
        acc += row * k[ky];
    }
    out[((size_t)p * Ho + y) * Wo + x] = acc * (1.f / 64.f);
}

// ---------------- avg pool to 1x1 (64 planes), batched ----------------
__global__ void avgpool_hw(const float* __restrict__ in, float* __restrict__ out, int HW,
                           long long inStr, long long outStr)
{
    int s = blockIdx.y;
    in  += (size_t)s * inStr;
    out += (size_t)s * outStr;
    int p = blockIdx.x;
    const float* ip = in + (size_t)p * HW;
    float sum = 0.f;
    for (int i = threadIdx.x; i < HW; i += blockDim.x) sum += ip[i];
    __shared__ float red[256];
    red[threadIdx.x] = sum;
    __syncthreads();
    for (int off = 128; off; off >>= 1) {
        if ((int)threadIdx.x < off) red[threadIdx.x] += red[threadIdx.x + off];
        __syncthreads();
    }
    if (threadIdx.x == 0) out[p] = red[0] / (float)HW;
}

// ---------------- style FC (all 8 samples) ----------------
__global__ void style_fc(const float* __restrict__ s, const float* __restrict__ W,
                         const float* __restrict__ b, float* __restrict__ out, int outdim)
{
    int n = blockIdx.x;
    int i = threadIdx.x;
    if (i >= outdim) return;
    float acc = b[i];
    const float* sn = s + n * 64;
    const float* wi = W + i * 64;
    for (int f = 0; f < 64; ++f) acc += sn[f] * wi[f];
    out[n * 64 + i] = LRELU(acc);
}

// ------- modulate+demodulate (all 8 samples); transpose=1 -> [c][k][o] -------
__global__ void modulate(const float* __restrict__ w, const float* __restrict__ sw,
                         float* __restrict__ wout, int O, int C, int transpose)
{
    int no = blockIdx.x;
    int o = no % O, n = no / O;
    int nw = C * 9;
    int t = threadIdx.x;
    float v[9];
    int cnt = 0;
    float ss = 0.f;
    for (int idx = t; idx < nw; idx += 64) {
        int c = idx / 9;
        float val = w[o * nw + idx] * sw[n * 64 + c];
        v[cnt++] = val;
        ss += val * val;
    }
    #pragma unroll
    for (int off = 32; off; off >>= 1) ss += __shfl_xor(ss, off);
    float d = rsqrtf(ss + 1e-8f);
    cnt = 0;
    for (int idx = t; idx < nw; idx += 64) {
        float val = v[cnt++] * d;
        if (transpose)
            wout[(size_t)n * nw * O + (size_t)idx * O + o] = val;
        else
            wout[(size_t)no * nw + idx] = val;
    }
}

// ------- guide weight transpose -------
__global__ void guide_transpose(const float* __restrict__ grw, float* __restrict__ gt, int total)
{
    int i = blockIdx.x * 256 + threadIdx.x;
    if (i >= total) return;
    int l = i / 36864, rem = i % 36864;
    int idx = rem / 64, o = rem % 64;
    int c = idx / 9, k = idx % 9;
    gt[i] = grw[(((size_t)l * 64 + o) * 64 + c) * 9 + k];
}

// ------- g0 weight transpose -------
__global__ void g0_transpose(const float* __restrict__ g0w, float* __restrict__ gt)
{
    int i = blockIdx.x * 256 + threadIdx.x;
    if (i >= 1728) return;
    int idx = i / 64, o = i % 64;
    int c = idx / 9, k = idx % 9;
    gt[i] = g0w[((size_t)o * 3 + c) * 9 + k];
}

__global__ void fill_sentinel(float* __restrict__ out, int n)
{
    int i = blockIdx.x * 256 + threadIdx.x;
    if (i < n) out[i] = 1.0e9f;
}

extern "C" void kernel_launch(void* const* d_in, const int* in_sizes, int n_in,
                              void* d_out, int out_size, void* d_ws, size_t ws_size,
                              hipStream_t stream)
{
    const float* x     = (const float*)d_in[0];
    const float* ref   = (const float*)d_in[1];
    const float* g0w   = (const float*)d_in[2];
    const float* g0b   = (const float*)d_in[3];
    const float* grw   = (const float*)d_in[4];
    const float* grb   = (const float*)d_in[5];
    const float* c0w   = (const float*)d_in[6];
    const float* c0swW = (const float*)d_in[7];
    const float* c0swb = (const float*)d_in[8];
    const float* c0sbW = (const float*)d_in[9];
    const float* c0sbb = (const float*)d_in[10];
    const float* midw  = (const float*)d_in[11];
    const float* midswW= (const float*)d_in[12];
    const float* midswb= (const float*)d_in[13];
    const float* midsbW= (const float*)d_in[14];
    const float* midsbb= (const float*)d_in[15];
    const float* c6w   = (const float*)d_in[16];
    const float* c6swW = (const float*)d_in[17];
    const float* c6swb = (const float*)d_in[18];
    const float* c6sbW = (const float*)d_in[19];
    const float* c6sbb = (const float*)d_in[20];
    float* out = (float*)d_out;
    float* ws  = (float*)d_ws;

    // -------- shared region (floats) --------
    const size_t SV  = 0;
    const size_t STY = 512;
    const size_t WM  = 12800;
    const size_t GT  = 2989568;
    const size_t G0T = 3137024;
    const size_t BUF = 3138816;

    // -------- main-path per-sample slot offsets --------
    const size_t SA = 0;                  // [64,257,257]-class
    const size_t SB = 4227136;            // [64,256,256]
    const size_t D1 = 8421440;            // [64,128,128]
    const size_t D2 = 9470016;            // [64,128,128]
    const size_t D3 = 10518592;           // [64,129,129]-class
    const size_t E1 = 11583616;           // [64,64,64]
    const size_t E2 = 11845760;
    const size_t E3 = 12107904;
    const size_t G2o = 12370048;          // combined up-weights [147456]
    const long long PER = 12517504ll;     // ~50.1 MB per sample

    // -------- guide-phase per-sample slot offsets --------
    const size_t gSA = 0;
    const size_t gD1 = 4194304;
    const size_t gD2 = 5242880;
    const size_t gE1 = 6291456;
    const size_t gE2 = 6553600;
    const long long GPER = 6815744ll;

    int G = 0, GG = 0;
    for (int g = 8; g >= 1; --g)
        if ((BUF + (size_t)g * PER) * sizeof(float) <= ws_size) { G = g; break; }
    for (int g = 8; g >= 1; --g)
        if ((BUF + (size_t)g * GPER) * sizeof(float) <= ws_size) { GG = g; break; }
    if (!G || !GG) {
        fill_sentinel<<<dim3((out_size + 255) / 256), dim3(256), 0, stream>>>(out, out_size);
        return;
    }

    dim3 blk(256);
    const int LDS1 = 29952;
    const int LDSU = (4 * 6 * 20 + 4 * 2448 + 2112) * 4;   // 49536 B

    float* B = ws + BUF;

    guide_transpose<<<dim3(147456 / 256), blk, 0, stream>>>(grw, ws + GT, 147456);
    g0_transpose<<<dim3(7), blk, 0, stream>>>(g0w, ws + G0T);

    // ==================== guide net ====================
    for (int n0 = 0; n0 < 8; ) {
        int g = (8 - n0 < GG) ? (8 - n0) : GG;
        const float* refg = ref + (size_t)n0 * 196608;
        conv3_gemm<<<dim3(16 * 16, g), blk, 0, stream>>>(
            refg, ws + G0T, g0b, B + gSA, 256, 256, 16, 196608, 0, 0, GPER);
        conv64s2_gemm8<<<dim3(16 * 16, g), blk, 0, stream>>>(
            B + gSA, ws + GT, grb, B + gD1, 256, 256, 128, 128, 1, 1, 16, GPER, 0, 0, GPER);
        conv64_gemm8<<<dim3(16 * 16, g), blk, 0, stream>>>(
            B + gD1, ws + GT + 36864, grb + 64, B + gD2, 128, 128, 1, 16, GPER, 0, 0, GPER);
        conv64s2_gemm8<<<dim3(8 * 8, g), blk, 0, stream>>>(
            B + gD2, ws + GT + 73728, grb + 128, B + gE1, 128, 128, 64, 64, 1, 1, 8, GPER, 0, 0, GPER);
        conv64_gemm8<<<dim3(8 * 8, g), blk, 0, stream>>>(
            B + gE1, ws + GT + 110592, grb + 192, B + gE2, 64, 64, 0, 8, GPER, 0, 0, GPER);
        avgpool_hw<<<dim3(64, g), blk, 0, stream>>>(B + gE2, ws + SV + (size_t)n0 * 64, 4096, GPER, 64);
        n0 += g;
    }

    // ==================== styles + modulated weights ====================
    const float* Wt[12];  const float* swWp[12]; const float* swbp[12];
    const float* sbWp[12]; const float* sbbp[12];
    int Ci[12], Oi[12];
    size_t wmo[12];
    Wt[0] = c0w; swWp[0] = c0swW; swbp[0] = c0swb; sbWp[0] = c0sbW; sbbp[0] = c0sbb;
    Ci[0] = 3; Oi[0] = 64; wmo[0] = WM;
    for (int i = 0; i < 10; ++i) {
        Wt[1 + i]   = midw   + (size_t)i * 36864;
        swWp[1 + i] = midswW + (size_t)i * 4096;
        swbp[1 + i] = midswb + (size_t)i * 64;
        sbWp[1 + i] = midsbW + (size_t)i * 4096;
        sbbp[1 + i] = midsbb + (size_t)i * 64;
        Ci[1 + i] = 64; Oi[1 + i] = 64;
        wmo[1 + i] = WM + 13824ull + (size_t)i * 294912ull;
    }
    Wt[11] = c6w; swWp[11] = c6swW; swbp[11] = c6swb; sbWp[11] = c6sbW; sbbp[11] = c6sbb;
    Ci[11] = 64; Oi[11] = 3; wmo[11] = WM + 13824ull + 2949120ull;

    const int trf[12] = {1, 1, 1, 1, 1, 1, 1, 0, 1, 0, 1, 1};

    for (int i = 0; i < 12; ++i) {
        style_fc<<<dim3(8), dim3(64), 0, stream>>>(ws + SV, swWp[i], swbp[i], ws + STY + i * 1024, Ci[i]);
        style_fc<<<dim3(8), dim3(64), 0, stream>>>(ws + SV, sbWp[i], sbbp[i], ws + STY + i * 1024 + 512, Oi[i]);
        modulate<<<dim3(8 * Oi[i]), dim3(64), 0, stream>>>(Wt[i], ws + STY + i * 1024, ws + wmo[i], Oi[i], Ci[i], trf[i]);
    }

    // ==================== main path ====================
    for (int n0 = 0; n0 < 8; ) {
        int g = (8 - n0 < G) ? (8 - n0) : G;
        const float* xg = x + (size_t)n0 * 196608;
        float* outg = out + (size_t)n0 * 196608;
        #define WN(i)  (ws + wmo[i] + (size_t)n0 * Oi[i] * Ci[i] * 9)
        #define WSTR(i) ((long long)(Oi[i] * Ci[i] * 9))
        #define SBN(i) (ws + STY + (i) * 1024 + 512 + (size_t)n0 * 64)
        // f0 -> SB
        conv3_gemm<<<dim3(16 * 16, g), blk, 0, stream>>>(
            xg, WN(0), SBN(0), B + SB, 256, 256, 16, 196608, WSTR(0), 64, PER);
        // f1 down: blur(SB) -> SA; conv s2 -> D1; conv -> D2
        blur_down<<<dim3(64 * 17 * 17, g), blk, 0, stream>>>(B + SB, B + SA, 256, 256, 17, 17, PER, PER);
        conv64s2_gemm8<<<dim3(16 * 16, g), blk, 0, stream>>>(
            B + SA, WN(1), SBN(1), B + D1, 257, 257, 128, 128, 0, 1, 16, PER, WSTR(1), 64, PER);
        conv64_gemm8<<<dim3(16 * 16, g), blk, 0, stream>>>(
            B + D1, WN(2), SBN(2), B + D2, 128, 128, 1, 16, PER, WSTR(2), 64, PER);
        // f2 down
        blur_down<<<dim3(64 * 9 * 9, g), blk, 0, stream>>>(B + D2, B + D3, 128, 128, 9, 9, PER, PER);
        conv64s2_gemm8<<<dim3(8 * 8, g), blk, 0, stream>>>(
            B + D3, WN(3), SBN(3), B + E1, 129, 129, 64, 64, 0, 1, 8, PER, WSTR(3), 64, PER);
        conv64_gemm8<<<dim3(8 * 8, g), blk, 0, stream>>>(
            B + E1, WN(4), SBN(4), B + E2, 64, 64, 1, 8, PER, WSTR(4), 64, PER);
        // f3 x2
        conv64_gemm8<<<dim3(8 * 8, g), blk, 0, stream>>>(
            B + E2, WN(5), SBN(5), B + E3, 64, 64, 1, 8, PER, WSTR(5), 64, PER);
        conv64_gemm8<<<dim3(8 * 8, g), blk, 0, stream>>>(
            B + E3, WN(6), SBN(6), B + E1, 64, 64, 1, 8, PER, WSTR(6), 64, PER);
        // f4 up (fused): combine -> G2o; upconv(f3+f2) -> D1 (128^2, tiles 4x16); conv -> D3
        combine_up_w<<<dim3(576, g), blk, 0, stream>>>(WN(7), B + G2o, WSTR(7), PER);
        upconv64_gemm<<<dim3(4 * 16, g), blk, LDSU, stream>>>(
            B + E1, B + E2, B + G2o, SBN(7), B + D1, 64, 64, 4, PER, 64, PER);
        conv64_gemm8<<<dim3(16 * 16, g), blk, 0, stream>>>(
            B + D1, WN(8), SBN(8), B + D3, 128, 128, 1, 16, PER, WSTR(8), 64, PER);
        // f5 up: combine -> G2o; upconv(f4+f1) -> SA (256^2, tiles 8x32); conv -> SB
        combine_up_w<<<dim3(576, g), blk, 0, stream>>>(WN(9), B + G2o, WSTR(9), PER);
        upconv64_gemm<<<dim3(8 * 32, g), blk, LDSU, stream>>>(
            B + D3, B + D2, B + G2o, SBN(9), B + SA, 128, 128, 8, PER, 64, PER);
        conv64_gemm<1><<<dim3(16 * 16, g), blk, LDS1, stream>>>(
            B + SA, WN(10), SBN(10), B + SB, 256, 256, 256, 256, 1, 1, 16, PER, WSTR(10), 64, PER);
        // recompute f0 -> SA
        conv3_gemm<<<dim3(16 * 16, g), blk, 0, stream>>>(
            xg, WN(0), SBN(0), B + SA, 256, 256, 16, 196608, WSTR(0), 64, PER);
        // c6: conv(f5 + f0) -> out
        conv64to3_gemm<<<dim3(16 * 16, g), blk, 0, stream>>>(
            B + SB, B + SA, WN(11), SBN(11), outg, 256, 256, 16, PER, WSTR(11), 64, 196608);
        #undef WN
        #undef WSTR
        #undef SBN
        n0 += g;
    }
}